// Round 5
// baseline (996.011 us; speedup 1.0000x reference)
//
#include <hip/hip_runtime.h>
#include <hip/hip_bf16.h>
#include <math.h>

#define L_SEQ 1024
#define BATCH 4
#define DMODEL 768
#define NH 8
#define DH 96
#define DFF 2048
#define U_TOP 35
#define NROWS (L_SEQ * BATCH)
#define NBH (BATCH * NH)
#define IDX_CNT (L_SEQ * U_TOP)   // 35840

// ---------------- Threefry-2x32 (exact JAX reproduction) ----------------
__device__ inline unsigned rotl32(unsigned v, int d) { return (v << d) | (v >> (32 - d)); }

__device__ inline void tf2x32(unsigned k0, unsigned k1, unsigned x0, unsigned x1,
                              unsigned& o0, unsigned& o1) {
  unsigned ks0 = k0, ks1 = k1, ks2 = k0 ^ k1 ^ 0x1BD11BDAu;
  x0 += ks0; x1 += ks1;
#define TFR(r) { x0 += x1; x1 = rotl32(x1, r); x1 ^= x0; }
  TFR(13) TFR(15) TFR(26) TFR(6)
  x0 += ks1; x1 += ks2 + 1u;
  TFR(17) TFR(29) TFR(16) TFR(24)
  x0 += ks2; x1 += ks0 + 2u;
  TFR(13) TFR(15) TFR(26) TFR(6)
  x0 += ks0; x1 += ks1 + 3u;
  TFR(17) TFR(29) TFR(16) TFR(24)
  x0 += ks1; x1 += ks2 + 4u;
  TFR(13) TFR(15) TFR(26) TFR(6)
  x0 += ks2; x1 += ks0 + 5u;
#undef TFR
  o0 = x0; o1 = x1;
}

// idx = randint(key(42), (1024,35), 0, 1024), jax_threefry_partitionable=True:
//   k1,k2 = split(key)        (foldlike: child i = BOTH words of E(key,(0,i)))
//   lower_bits[j] = w0 ^ w1 of E(k2, (0,j))   (partitionable random_bits)
//   span=1024 (pow2) -> multiplier=0 -> idx[j] = lower_bits[j] & 1023
__global__ void gen_idx(int* __restrict__ idx) {
  int j = blockIdx.x * 256 + threadIdx.x;
  if (j >= IDX_CNT) return;
  unsigned k2a, k2b;
  tf2x32(0u, 42u, 0u, 1u, k2a, k2b);      // k2 = split(key)[1]
  unsigned o0, o1;
  tf2x32(k2a, k2b, 0u, (unsigned)j, o0, o1);
  idx[j] = (int)((o0 ^ o1) & 1023u);
}

// ---------------- M[b,h,l] = max_s qk - mean_s qk over 35 sampled keys ----------------
__global__ __launch_bounds__(64) void sample_scores(
    const float* __restrict__ target, const float* __restrict__ source,
    const int* __restrict__ idx, float* __restrict__ M) {
  int blk = blockIdx.x;            // bh*1024 + l
  int l = blk & (L_SEQ - 1);
  int bh = blk >> 10;
  int h = bh & (NH - 1), b = bh >> 3;
  int lane = threadIdx.x;
  const float* q = target + ((size_t)l * BATCH + b) * DMODEL + h * DH;
  float val = 0.f;
  bool active = lane < U_TOP;
  if (active) {
    int kl = idx[l * U_TOP + lane];
    const float* kr = source + ((size_t)kl * BATCH + b) * DMODEL + h * DH;
    float s = 0.f;
#pragma unroll 8
    for (int d = 0; d < DH; ++d) s += q[d] * kr[d];
    val = s;
  }
  float vmax = active ? val : -INFINITY;
  float vsum = active ? val : 0.f;
#pragma unroll
  for (int off = 32; off; off >>= 1) {
    vmax = fmaxf(vmax, __shfl_xor(vmax, off, 64));
    vsum += __shfl_xor(vsum, off, 64);
  }
  if (lane == 0) M[(size_t)bh * L_SEQ + l] = vmax - vsum * (1.f / U_TOP);
}

// ---------------- top-35 per (b,h), ties -> lowest index; build sel map ----------------
__global__ __launch_bounds__(256) void topk_sel(const float* __restrict__ M,
                                                int* __restrict__ top, int* __restrict__ sel) {
  int bh = blockIdx.x;
  __shared__ float vals[L_SEQ];
  __shared__ float rv[256];
  __shared__ int ri[256];
  int tid = threadIdx.x;
  for (int i = tid; i < L_SEQ; i += 256) {
    vals[i] = M[(size_t)bh * L_SEQ + i];
    sel[(size_t)bh * L_SEQ + i] = -1;
  }
  __syncthreads();
  for (int it = 0; it < U_TOP; ++it) {
    float bv = -INFINITY; int bi = 0x7FFFFFFF;
    for (int i = tid; i < L_SEQ; i += 256) {
      float v = vals[i];
      if (v > bv || (v == bv && i < bi)) { bv = v; bi = i; }
    }
    rv[tid] = bv; ri[tid] = bi;
    __syncthreads();
    for (int s = 128; s; s >>= 1) {
      if (tid < s) {
        float ov = rv[tid + s]; int oi = ri[tid + s];
        if (ov > rv[tid] || (ov == rv[tid] && oi < ri[tid])) { rv[tid] = ov; ri[tid] = oi; }
      }
      __syncthreads();
    }
    if (tid == 0) {
      int bidx = ri[0];
      top[bh * U_TOP + it] = bidx;
      sel[(size_t)bh * L_SEQ + bidx] = it;
      vals[bidx] = -INFINITY;
    }
    __syncthreads();
  }
}

// ---------------- V.mean over L (V = K = source) ----------------
__global__ __launch_bounds__(768) void vmean_kernel(const float* __restrict__ source,
                                                    float* __restrict__ vmean) {
  int b = blockIdx.x;
  int d = threadIdx.x;
  float s = 0.f;
  for (int l = 0; l < L_SEQ; ++l) s += source[((size_t)l * BATCH + b) * DMODEL + d];
  vmean[b * DMODEL + d] = s * (1.f / L_SEQ);
}

// ---------------- full attention for the 35 selected queries per (b,h) ----------------
__global__ __launch_bounds__(256) void attn_sel(
    const float* __restrict__ target, const float* __restrict__ source,
    const int* __restrict__ top, float* __restrict__ upd) {
  int blk = blockIdx.x;            // bh*35 + u
  int u = blk % U_TOP;
  int bh = blk / U_TOP;
  int h = bh & (NH - 1), b = bh >> 3;
  __shared__ float q[DH];
  __shared__ float sc[L_SEQ];
  __shared__ float red[256];
  int tid = threadIdx.x;
  int qpos = top[bh * U_TOP + u];
  if (tid < DH) q[tid] = target[((size_t)qpos * BATCH + b) * DMODEL + h * DH + tid];
  __syncthreads();
  const float scale = 1.0f / sqrtf((float)DH);
  for (int l = tid; l < L_SEQ; l += 256) {
    const float* kr = source + ((size_t)l * BATCH + b) * DMODEL + h * DH;
    float s = 0.f;
#pragma unroll 8
    for (int d = 0; d < DH; ++d) s += q[d] * kr[d];
    sc[l] = s * scale;
  }
  __syncthreads();
  float m = -INFINITY;
  for (int l = tid; l < L_SEQ; l += 256) m = fmaxf(m, sc[l]);
  red[tid] = m; __syncthreads();
  for (int s = 128; s; s >>= 1) { if (tid < s) red[tid] = fmaxf(red[tid], red[tid + s]); __syncthreads(); }
  m = red[0];
  __syncthreads();
  float sum = 0.f;
  for (int l = tid; l < L_SEQ; l += 256) { float p = expf(sc[l] - m); sc[l] = p; sum += p; }
  red[tid] = sum; __syncthreads();
  for (int s = 128; s; s >>= 1) { if (tid < s) red[tid] += red[tid + s]; __syncthreads(); }
  float inv = 1.f / red[0];
  __syncthreads();
  if (tid < DH) {
    float acc = 0.f;
    for (int l = 0; l < L_SEQ; ++l) acc += sc[l] * source[((size_t)l * BATCH + b) * DMODEL + h * DH + tid];
    upd[(size_t)blk * DH + tid] = acc * inv;
  }
}

// ---------------- attended + residual + LN1 -> normed1 ----------------
__global__ __launch_bounds__(256) void fuse_ln1(
    const float* __restrict__ target, const float* __restrict__ upd,
    const int* __restrict__ sel, const float* __restrict__ vmean,
    const float* __restrict__ g, const float* __restrict__ bb,
    float* __restrict__ normed1) {
  int r = blockIdx.x;              // r = l*BATCH + b
  int l = r >> 2, b = r & 3;
  __shared__ float x[DMODEL];
  __shared__ float red[256];
  int tid = threadIdx.x;
  for (int d = tid; d < DMODEL; d += 256) {
    int h = d / DH;
    int s = sel[((size_t)(b * NH + h)) * L_SEQ + l];
    float a = (s >= 0) ? upd[((size_t)(b * NH + h) * U_TOP + s) * DH + (d - h * DH)]
                       : vmean[b * DMODEL + d];
    x[d] = target[(size_t)r * DMODEL + d] + a;
  }
  __syncthreads();
  float partial = 0.f;
  for (int d = tid; d < DMODEL; d += 256) partial += x[d];
  red[tid] = partial; __syncthreads();
  for (int s = 128; s; s >>= 1) { if (tid < s) red[tid] += red[tid + s]; __syncthreads(); }
  float mu = red[0] * (1.f / DMODEL);
  __syncthreads();
  partial = 0.f;
  for (int d = tid; d < DMODEL; d += 256) { float t = x[d] - mu; partial += t * t; }
  red[tid] = partial; __syncthreads();
  for (int s = 128; s; s >>= 1) { if (tid < s) red[tid] += red[tid + s]; __syncthreads(); }
  float rstd = 1.0f / sqrtf(red[0] * (1.f / DMODEL) + 1e-5f);
  for (int d = tid; d < DMODEL; d += 256)
    normed1[(size_t)r * DMODEL + d] = (x[d] - mu) * rstd * g[d] + bb[d];
}

// ---------------- C[M,N] = (relu?)(A[M,K] * B[N,K]^T + bias) ----------------
template <bool RELU>
__global__ __launch_bounds__(256) void gemm_bt(
    const float* __restrict__ A, const float* __restrict__ B,
    const float* __restrict__ bias, float* __restrict__ C,
    int Mdim, int Ndim, int Kdim) {
  __shared__ float As[16][64];
  __shared__ float Bs[16][64];
  int bm = blockIdx.y * 64, bn = blockIdx.x * 64;
  int tid = threadIdx.x;
  int tx = tid & 15, ty = tid >> 4;
  float acc[4][4] = {};
  for (int k0 = 0; k0 < Kdim; k0 += 16) {
#pragma unroll
    for (int i = 0; i < 4; ++i) {
      int e = tid + i * 256;
      int m = e >> 4, k = e & 15;
      As[k][m] = A[(size_t)(bm + m) * Kdim + k0 + k];
      Bs[k][m] = B[(size_t)(bn + m) * Kdim + k0 + k];
    }
    __syncthreads();
#pragma unroll
    for (int kk = 0; kk < 16; ++kk) {
      float a0 = As[kk][ty * 4 + 0], a1 = As[kk][ty * 4 + 1];
      float a2 = As[kk][ty * 4 + 2], a3 = As[kk][ty * 4 + 3];
      float b0 = Bs[kk][tx * 4 + 0], b1 = Bs[kk][tx * 4 + 1];
      float b2 = Bs[kk][tx * 4 + 2], b3 = Bs[kk][tx * 4 + 3];
      acc[0][0] += a0 * b0; acc[0][1] += a0 * b1; acc[0][2] += a0 * b2; acc[0][3] += a0 * b3;
      acc[1][0] += a1 * b0; acc[1][1] += a1 * b1; acc[1][2] += a1 * b2; acc[1][3] += a1 * b3;
      acc[2][0] += a2 * b0; acc[2][1] += a2 * b1; acc[2][2] += a2 * b2; acc[2][3] += a2 * b3;
      acc[3][0] += a3 * b0; acc[3][1] += a3 * b1; acc[3][2] += a3 * b2; acc[3][3] += a3 * b3;
    }
    __syncthreads();
  }
#pragma unroll
  for (int i = 0; i < 4; ++i)
#pragma unroll
    for (int j = 0; j < 4; ++j) {
      int m = bm + ty * 4 + i, n = bn + tx * 4 + j;
      float v = acc[i][j] + bias[n];
      if (RELU) v = fmaxf(v, 0.f);
      C[(size_t)m * Ndim + n] = v;
    }
}

// ---------------- normed1 + proj -> LN2 -> out ----------------
__global__ __launch_bounds__(256) void ln2_out(
    const float* __restrict__ normed1, const float* __restrict__ proj,
    const float* __restrict__ g, const float* __restrict__ bb,
    float* __restrict__ out) {
  int r = blockIdx.x;
  __shared__ float x[DMODEL];
  __shared__ float red[256];
  int tid = threadIdx.x;
  for (int d = tid; d < DMODEL; d += 256)
    x[d] = normed1[(size_t)r * DMODEL + d] + proj[(size_t)r * DMODEL + d];
  __syncthreads();
  float partial = 0.f;
  for (int d = tid; d < DMODEL; d += 256) partial += x[d];
  red[tid] = partial; __syncthreads();
  for (int s = 128; s; s >>= 1) { if (tid < s) red[tid] += red[tid + s]; __syncthreads(); }
  float mu = red[0] * (1.f / DMODEL);
  __syncthreads();
  partial = 0.f;
  for (int d = tid; d < DMODEL; d += 256) { float t = x[d] - mu; partial += t * t; }
  red[tid] = partial; __syncthreads();
  for (int s = 128; s; s >>= 1) { if (tid < s) red[tid] += red[tid + s]; __syncthreads(); }
  float rstd = 1.0f / sqrtf(red[0] * (1.f / DMODEL) + 1e-5f);
  for (int d = tid; d < DMODEL; d += 256)
    out[(size_t)r * DMODEL + d] = (x[d] - mu) * rstd * g[d] + bb[d];
}

extern "C" void kernel_launch(void* const* d_in, const int* in_sizes, int n_in,
                              void* d_out, int out_size, void* d_ws, size_t ws_size,
                              hipStream_t stream) {
  const float* target = (const float*)d_in[0];
  const float* source = (const float*)d_in[1];
  const float* W1 = (const float*)d_in[2];
  const float* b1 = (const float*)d_in[3];
  const float* W2 = (const float*)d_in[4];
  const float* b2 = (const float*)d_in[5];
  const float* ln1_g = (const float*)d_in[6];
  const float* ln1_b = (const float*)d_in[7];
  const float* ln2_g = (const float*)d_in[8];
  const float* ln2_b = (const float*)d_in[9];
  float* out = (float*)d_out;

  char* ws = (char*)d_ws;
  int*   idx     = (int*)  (ws + 0x0000000);   // 143,360 B
  float* M       = (float*)(ws + 0x0040000);   // 131,072 B
  int*   top     = (int*)  (ws + 0x0080000);   // 4,480 B
  int*   sel     = (int*)  (ws + 0x0090000);   // 131,072 B
  float* upd     = (float*)(ws + 0x00C0000);   // 430,080 B
  float* vmean   = (float*)(ws + 0x0140000);   // 12,288 B
  float* normed1 = (float*)(ws + 0x0180000);   // 12,582,912 B
  float* h1      = (float*)(ws + 0x1000000);   // 33,554,432 B
  float* proj    = (float*)(ws + 0x3000000);   // 12,582,912 B -> total 60 MB

  gen_idx<<<(IDX_CNT + 255) / 256, 256, 0, stream>>>(idx);
  sample_scores<<<NBH * L_SEQ, 64, 0, stream>>>(target, source, idx, M);
  topk_sel<<<NBH, 256, 0, stream>>>(M, top, sel);
  vmean_kernel<<<BATCH, DMODEL, 0, stream>>>(source, vmean);
  attn_sel<<<NBH * U_TOP, 256, 0, stream>>>(target, source, top, upd);
  fuse_ln1<<<NROWS, 256, 0, stream>>>(target, upd, sel, vmean, ln1_g, ln1_b, normed1);
  {
    dim3 grid(DFF / 64, NROWS / 64);
    gemm_bt<true><<<grid, 256, 0, stream>>>(normed1, W1, b1, h1, NROWS, DFF, DMODEL);
  }
  {
    dim3 grid(DMODEL / 64, NROWS / 64);
    gemm_bt<false><<<grid, 256, 0, stream>>>(h1, W2, b2, proj, NROWS, DMODEL, DFF);
  }
  ln2_out<<<NROWS, 256, 0, stream>>>(normed1, proj, ln2_g, ln2_b, out);
}

// Round 6
// 420.138 us; speedup vs baseline: 2.3707x; 2.3707x over previous
//
#include <hip/hip_runtime.h>
#include <hip/hip_bf16.h>
#include <math.h>

#define L_SEQ 1024
#define BATCH 4
#define DMODEL 768
#define NH 8
#define DH 96
#define DFF 2048
#define U_TOP 35
#define NROWS (L_SEQ * BATCH)
#define NBH (BATCH * NH)
#define IDX_CNT (L_SEQ * U_TOP)   // 35840

typedef __attribute__((ext_vector_type(8))) short bf16x8;
typedef __attribute__((ext_vector_type(4))) float f32x4;

__device__ inline unsigned short f2bf(float f) {
  unsigned u = __float_as_uint(f);
  u += 0x7FFFu + ((u >> 16) & 1u);   // RNE
  return (unsigned short)(u >> 16);
}

// ---------------- Threefry-2x32 (exact JAX reproduction) ----------------
__device__ inline unsigned rotl32(unsigned v, int d) { return (v << d) | (v >> (32 - d)); }

__device__ inline void tf2x32(unsigned k0, unsigned k1, unsigned x0, unsigned x1,
                              unsigned& o0, unsigned& o1) {
  unsigned ks0 = k0, ks1 = k1, ks2 = k0 ^ k1 ^ 0x1BD11BDAu;
  x0 += ks0; x1 += ks1;
#define TFR(r) { x0 += x1; x1 = rotl32(x1, r); x1 ^= x0; }
  TFR(13) TFR(15) TFR(26) TFR(6)
  x0 += ks1; x1 += ks2 + 1u;
  TFR(17) TFR(29) TFR(16) TFR(24)
  x0 += ks2; x1 += ks0 + 2u;
  TFR(13) TFR(15) TFR(26) TFR(6)
  x0 += ks0; x1 += ks1 + 3u;
  TFR(17) TFR(29) TFR(16) TFR(24)
  x0 += ks1; x1 += ks2 + 4u;
  TFR(13) TFR(15) TFR(26) TFR(6)
  x0 += ks2; x1 += ks0 + 5u;
#undef TFR
  o0 = x0; o1 = x1;
}

// foldlike split + partitionable bits (verified passing in R5)
__global__ void gen_idx(int* __restrict__ idx) {
  int j = blockIdx.x * 256 + threadIdx.x;
  if (j >= IDX_CNT) return;
  unsigned k2a, k2b;
  tf2x32(0u, 42u, 0u, 1u, k2a, k2b);      // k2 = split(key)[1]
  unsigned o0, o1;
  tf2x32(k2a, k2b, 0u, (unsigned)j, o0, o1);
  idx[j] = (int)((o0 ^ o1) & 1023u);
}

// ---------------- M[b,h,l] = max_s qk - mean_s qk over 35 sampled keys ----------------
__global__ __launch_bounds__(64) void sample_scores(
    const float* __restrict__ target, const float* __restrict__ source,
    const int* __restrict__ idx, float* __restrict__ M) {
  int blk = blockIdx.x;            // bh*1024 + l
  int l = blk & (L_SEQ - 1);
  int bh = blk >> 10;
  int h = bh & (NH - 1), b = bh >> 3;
  int lane = threadIdx.x;
  const float* q = target + ((size_t)l * BATCH + b) * DMODEL + h * DH;
  float val = 0.f;
  bool active = lane < U_TOP;
  if (active) {
    int kl = idx[l * U_TOP + lane];
    const float* kr = source + ((size_t)kl * BATCH + b) * DMODEL + h * DH;
    float s = 0.f;
#pragma unroll 8
    for (int d = 0; d < DH; ++d) s += q[d] * kr[d];
    val = s;
  }
  float vmax = active ? val : -INFINITY;
  float vsum = active ? val : 0.f;
#pragma unroll
  for (int off = 32; off; off >>= 1) {
    vmax = fmaxf(vmax, __shfl_xor(vmax, off, 64));
    vsum += __shfl_xor(vsum, off, 64);
  }
  if (lane == 0) M[(size_t)bh * L_SEQ + l] = vmax - vsum * (1.f / U_TOP);
}

// ---------------- top-35 per (b,h), ties -> lowest index; build sel map ----------------
__global__ __launch_bounds__(256) void topk_sel(const float* __restrict__ M,
                                                int* __restrict__ top, int* __restrict__ sel) {
  int bh = blockIdx.x;
  __shared__ float vals[L_SEQ];
  __shared__ float rv[256];
  __shared__ int ri[256];
  int tid = threadIdx.x;
  for (int i = tid; i < L_SEQ; i += 256) {
    vals[i] = M[(size_t)bh * L_SEQ + i];
    sel[(size_t)bh * L_SEQ + i] = -1;
  }
  __syncthreads();
  for (int it = 0; it < U_TOP; ++it) {
    float bv = -INFINITY; int bi = 0x7FFFFFFF;
    for (int i = tid; i < L_SEQ; i += 256) {
      float v = vals[i];
      if (v > bv || (v == bv && i < bi)) { bv = v; bi = i; }
    }
    rv[tid] = bv; ri[tid] = bi;
    __syncthreads();
    for (int s = 128; s; s >>= 1) {
      if (tid < s) {
        float ov = rv[tid + s]; int oi = ri[tid + s];
        if (ov > rv[tid] || (ov == rv[tid] && oi < ri[tid])) { rv[tid] = ov; ri[tid] = oi; }
      }
      __syncthreads();
    }
    if (tid == 0) {
      int bidx = ri[0];
      top[bh * U_TOP + it] = bidx;
      sel[(size_t)bh * L_SEQ + bidx] = it;
      vals[bidx] = -INFINITY;
    }
    __syncthreads();
  }
}

// ---------------- V.mean over L (V = K = source) ----------------
__global__ __launch_bounds__(768) void vmean_kernel(const float* __restrict__ source,
                                                    float* __restrict__ vmean) {
  int b = blockIdx.x;
  int d = threadIdx.x;
  float s = 0.f;
  for (int l = 0; l < L_SEQ; ++l) s += source[((size_t)l * BATCH + b) * DMODEL + d];
  vmean[b * DMODEL + d] = s * (1.f / L_SEQ);
}

// ---------------- full attention for the 35 selected queries per (b,h) ----------------
__global__ __launch_bounds__(256) void attn_sel(
    const float* __restrict__ target, const float* __restrict__ source,
    const int* __restrict__ top, float* __restrict__ upd) {
  int blk = blockIdx.x;            // bh*35 + u
  int u = blk % U_TOP;
  int bh = blk / U_TOP;
  int h = bh & (NH - 1), b = bh >> 3;
  __shared__ float q[DH];
  __shared__ float sc[L_SEQ];
  __shared__ float red[256];
  int tid = threadIdx.x;
  int qpos = top[bh * U_TOP + u];
  if (tid < DH) q[tid] = target[((size_t)qpos * BATCH + b) * DMODEL + h * DH + tid];
  __syncthreads();
  const float scale = 1.0f / sqrtf((float)DH);
  for (int l = tid; l < L_SEQ; l += 256) {
    const float* kr = source + ((size_t)l * BATCH + b) * DMODEL + h * DH;
    float s = 0.f;
#pragma unroll 8
    for (int d = 0; d < DH; ++d) s += q[d] * kr[d];
    sc[l] = s * scale;
  }
  __syncthreads();
  float m = -INFINITY;
  for (int l = tid; l < L_SEQ; l += 256) m = fmaxf(m, sc[l]);
  red[tid] = m; __syncthreads();
  for (int s = 128; s; s >>= 1) { if (tid < s) red[tid] = fmaxf(red[tid], red[tid + s]); __syncthreads(); }
  m = red[0];
  __syncthreads();
  float sum = 0.f;
  for (int l = tid; l < L_SEQ; l += 256) { float p = expf(sc[l] - m); sc[l] = p; sum += p; }
  red[tid] = sum; __syncthreads();
  for (int s = 128; s; s >>= 1) { if (tid < s) red[tid] += red[tid + s]; __syncthreads(); }
  float inv = 1.f / red[0];
  __syncthreads();
  // PV: all 256 threads; 3 d-blocks of 32, 8 l-chunks of 128
  for (int db = 0; db < 3; ++db) {
    int d = db * 32 + (tid & 31);
    int lp = tid >> 5;
    float acc = 0.f;
    int l0 = lp * 128;
    for (int l = l0; l < l0 + 128; ++l)
      acc += sc[l] * source[((size_t)l * BATCH + b) * DMODEL + h * DH + d];
    red[tid] = acc;
    __syncthreads();
    if (tid < 32) {
      float s2 = 0.f;
#pragma unroll
      for (int p = 0; p < 8; ++p) s2 += red[p * 32 + tid];
      upd[(size_t)blk * DH + db * 32 + tid] = s2 * inv;
    }
    __syncthreads();
  }
}

// ---------------- attended + residual + LN1 -> normed1 (fp32 + bf16) ----------------
__global__ __launch_bounds__(256) void fuse_ln1(
    const float* __restrict__ target, const float* __restrict__ upd,
    const int* __restrict__ sel, const float* __restrict__ vmean,
    const float* __restrict__ g, const float* __restrict__ bb,
    float* __restrict__ normed1, unsigned short* __restrict__ normed1b) {
  int r = blockIdx.x;              // r = l*BATCH + b
  int l = r >> 2, b = r & 3;
  __shared__ float x[DMODEL];
  __shared__ float red[256];
  int tid = threadIdx.x;
  for (int d = tid; d < DMODEL; d += 256) {
    int h = d / DH;
    int s = sel[((size_t)(b * NH + h)) * L_SEQ + l];
    float a = (s >= 0) ? upd[((size_t)(b * NH + h) * U_TOP + s) * DH + (d - h * DH)]
                       : vmean[b * DMODEL + d];
    x[d] = target[(size_t)r * DMODEL + d] + a;
  }
  __syncthreads();
  float partial = 0.f;
  for (int d = tid; d < DMODEL; d += 256) partial += x[d];
  red[tid] = partial; __syncthreads();
  for (int s = 128; s; s >>= 1) { if (tid < s) red[tid] += red[tid + s]; __syncthreads(); }
  float mu = red[0] * (1.f / DMODEL);
  __syncthreads();
  partial = 0.f;
  for (int d = tid; d < DMODEL; d += 256) { float t = x[d] - mu; partial += t * t; }
  red[tid] = partial; __syncthreads();
  for (int s = 128; s; s >>= 1) { if (tid < s) red[tid] += red[tid + s]; __syncthreads(); }
  float rstd = 1.0f / sqrtf(red[0] * (1.f / DMODEL) + 1e-5f);
  for (int d = tid; d < DMODEL; d += 256) {
    float v = (x[d] - mu) * rstd * g[d] + bb[d];
    normed1[(size_t)r * DMODEL + d] = v;
    normed1b[(size_t)r * DMODEL + d] = f2bf(v);
  }
}

// ---------------- fp32 -> bf16 convert (for W1, W2) ----------------
__global__ __launch_bounds__(256) void convert_bf16(const float* __restrict__ in,
                                                    unsigned short* __restrict__ outp, int n4) {
  int i = blockIdx.x * 256 + threadIdx.x;
  int stride = gridDim.x * 256;
  for (; i < n4; i += stride) {
    float4 v = ((const float4*)in)[i];
    unsigned long long pk = (unsigned long long)f2bf(v.x)
                          | ((unsigned long long)f2bf(v.y) << 16)
                          | ((unsigned long long)f2bf(v.z) << 32)
                          | ((unsigned long long)f2bf(v.w) << 48);
    ((unsigned long long*)outp)[i] = pk;
  }
}

// ---------------- bf16 MFMA GEMM: C[M,N] = f(A[M,K] * B[N,K]^T + bias) ----------------
// 128x128 tile, BK=64, 4 waves (2x2), 16x16x32 MFMA, global_load_lds(16B),
// XOR-swizzled LDS (slot ^= row&7 on 16B slots) via pre-swizzled global source.
template <bool RELU, bool BF16OUT>
__global__ __launch_bounds__(256) void gemm_mfma(
    const unsigned short* __restrict__ A, const unsigned short* __restrict__ B,
    const float* __restrict__ bias, void* __restrict__ Cout,
    int Ndim, int Kdim) {
  __shared__ short As[128 * 64];
  __shared__ short Bs[128 * 64];
  int tid = threadIdx.x;
  int lane = tid & 63;
  int wid = tid >> 6;
  int wm = wid >> 1, wn = wid & 1;       // 2x2 waves, each 64x64
  int bm = blockIdx.y * 128, bn = blockIdx.x * 128;

  f32x4 acc[4][4] = {};

  for (int k0 = 0; k0 < Kdim; k0 += 64) {
    // ---- stage A,B tiles: each wave 32 rows, 4 iters of 8 rows ----
#pragma unroll
    for (int i = 0; i < 4; ++i) {
      int trow = wid * 32 + i * 8 + (lane >> 3);
      int slot = (lane & 7) ^ (trow & 7);          // pre-swizzled global source
      const unsigned short* ga = A + (size_t)(bm + trow) * Kdim + k0 + slot * 8;
      const unsigned short* gb = B + (size_t)(bn + trow) * Kdim + k0 + slot * 8;
      __builtin_amdgcn_global_load_lds(
          (const __attribute__((address_space(1))) void*)ga,
          (__attribute__((address_space(3))) void*)(As + (wid * 32 + i * 8) * 64),
          16, 0, 0);
      __builtin_amdgcn_global_load_lds(
          (const __attribute__((address_space(1))) void*)gb,
          (__attribute__((address_space(3))) void*)(Bs + (wid * 32 + i * 8) * 64),
          16, 0, 0);
    }
    __syncthreads();
    // ---- 2 K-chunks of 32 ----
#pragma unroll
    for (int c = 0; c < 2; ++c) {
      bf16x8 af[4], bf[4];
#pragma unroll
      for (int mi = 0; mi < 4; ++mi) {
        int row = wm * 64 + mi * 16 + (lane & 15);
        int phys = (c * 4 + (lane >> 4)) ^ (row & 7);
        af[mi] = *(const bf16x8*)(As + row * 64 + phys * 8);
      }
#pragma unroll
      for (int ni = 0; ni < 4; ++ni) {
        int row = wn * 64 + ni * 16 + (lane & 15);
        int phys = (c * 4 + (lane >> 4)) ^ (row & 7);
        bf[ni] = *(const bf16x8*)(Bs + row * 64 + phys * 8);
      }
#pragma unroll
      for (int mi = 0; mi < 4; ++mi)
#pragma unroll
        for (int ni = 0; ni < 4; ++ni)
          acc[mi][ni] = __builtin_amdgcn_mfma_f32_16x16x32_bf16(af[mi], bf[ni], acc[mi][ni], 0, 0, 0);
    }
    __syncthreads();
  }

  // ---- epilogue: C layout col=lane&15, row=(lane>>4)*4+j ----
#pragma unroll
  for (int mi = 0; mi < 4; ++mi)
#pragma unroll
    for (int ni = 0; ni < 4; ++ni) {
      int col = bn + wn * 64 + ni * 16 + (lane & 15);
      float bv = bias[col];
#pragma unroll
      for (int j = 0; j < 4; ++j) {
        int row = bm + wm * 64 + mi * 16 + (lane >> 4) * 4 + j;
        float v = acc[mi][ni][j] + bv;
        if (RELU) v = fmaxf(v, 0.f);
        if (BF16OUT)
          ((unsigned short*)Cout)[(size_t)row * Ndim + col] = f2bf(v);
        else
          ((float*)Cout)[(size_t)row * Ndim + col] = v;
      }
    }
}

// ---------------- normed1 + proj -> LN2 -> out ----------------
__global__ __launch_bounds__(256) void ln2_out(
    const float* __restrict__ normed1, const float* __restrict__ proj,
    const float* __restrict__ g, const float* __restrict__ bb,
    float* __restrict__ out) {
  int r = blockIdx.x;
  __shared__ float x[DMODEL];
  __shared__ float red[256];
  int tid = threadIdx.x;
  for (int d = tid; d < DMODEL; d += 256)
    x[d] = normed1[(size_t)r * DMODEL + d] + proj[(size_t)r * DMODEL + d];
  __syncthreads();
  float partial = 0.f;
  for (int d = tid; d < DMODEL; d += 256) partial += x[d];
  red[tid] = partial; __syncthreads();
  for (int s = 128; s; s >>= 1) { if (tid < s) red[tid] += red[tid + s]; __syncthreads(); }
  float mu = red[0] * (1.f / DMODEL);
  __syncthreads();
  partial = 0.f;
  for (int d = tid; d < DMODEL; d += 256) { float t = x[d] - mu; partial += t * t; }
  red[tid] = partial; __syncthreads();
  for (int s = 128; s; s >>= 1) { if (tid < s) red[tid] += red[tid + s]; __syncthreads(); }
  float rstd = 1.0f / sqrtf(red[0] * (1.f / DMODEL) + 1e-5f);
  for (int d = tid; d < DMODEL; d += 256)
    out[(size_t)r * DMODEL + d] = (x[d] - mu) * rstd * g[d] + bb[d];
}

extern "C" void kernel_launch(void* const* d_in, const int* in_sizes, int n_in,
                              void* d_out, int out_size, void* d_ws, size_t ws_size,
                              hipStream_t stream) {
  const float* target = (const float*)d_in[0];
  const float* source = (const float*)d_in[1];
  const float* W1 = (const float*)d_in[2];
  const float* b1 = (const float*)d_in[3];
  const float* W2 = (const float*)d_in[4];
  const float* b2 = (const float*)d_in[5];
  const float* ln1_g = (const float*)d_in[6];
  const float* ln1_b = (const float*)d_in[7];
  const float* ln2_g = (const float*)d_in[8];
  const float* ln2_b = (const float*)d_in[9];
  float* out = (float*)d_out;

  char* ws = (char*)d_ws;
  int*            idx      = (int*)           (ws + 0x0000000);  // 140 KB
  float*          M        = (float*)         (ws + 0x0040000);  // 128 KB
  int*            top      = (int*)           (ws + 0x0080000);  // 4.4 KB
  int*            sel      = (int*)           (ws + 0x0090000);  // 128 KB
  float*          upd      = (float*)         (ws + 0x00C0000);  // 420 KB
  float*          vmean    = (float*)         (ws + 0x0140000);  // 12 KB
  unsigned short* w1b      = (unsigned short*)(ws + 0x0180000);  // 3 MB
  unsigned short* w2b      = (unsigned short*)(ws + 0x0480000);  // 3 MB
  unsigned short* normed1b = (unsigned short*)(ws + 0x0780000);  // 6 MB
  float*          normed1  = (float*)         (ws + 0x0D80000);  // 12 MB
  unsigned short* h1b      = (unsigned short*)(ws + 0x1980000);  // 16 MB
  float*          proj     = (float*)         (ws + 0x2980000);  // 12 MB -> ends 0x3580000

  gen_idx<<<(IDX_CNT + 255) / 256, 256, 0, stream>>>(idx);
  sample_scores<<<NBH * L_SEQ, 64, 0, stream>>>(target, source, idx, M);
  topk_sel<<<NBH, 256, 0, stream>>>(M, top, sel);
  vmean_kernel<<<BATCH, DMODEL, 0, stream>>>(source, vmean);
  attn_sel<<<NBH * U_TOP, 256, 0, stream>>>(target, source, top, upd);
  convert_bf16<<<1024, 256, 0, stream>>>(W1, w1b, DFF * DMODEL / 4);
  convert_bf16<<<1024, 256, 0, stream>>>(W2, w2b, DFF * DMODEL / 4);
  fuse_ln1<<<NROWS, 256, 0, stream>>>(target, upd, sel, vmean, ln1_g, ln1_b, normed1, normed1b);
  {
    dim3 grid(DFF / 128, NROWS / 128);   // 16 x 32
    gemm_mfma<true, true><<<grid, 256, 0, stream>>>(normed1b, w1b, b1, h1b, DFF, DMODEL);
  }
  {
    dim3 grid(DMODEL / 128, NROWS / 128);  // 6 x 32
    gemm_mfma<false, false><<<grid, 256, 0, stream>>>(h1b, w2b, b2, proj, DMODEL, DFF);
  }
  ln2_out<<<NROWS, 256, 0, stream>>>(normed1, proj, ln2_g, ln2_b, out);
}

// Round 9
// 355.685 us; speedup vs baseline: 2.8003x; 1.1812x over previous
//
#include <hip/hip_runtime.h>
#include <hip/hip_bf16.h>
#include <math.h>

#define L_SEQ 1024
#define BATCH 4
#define DMODEL 768
#define NH 8
#define DH 96
#define DFF 2048
#define U_TOP 35
#define NROWS (L_SEQ * BATCH)
#define NBH (BATCH * NH)
#define IDX_CNT (L_SEQ * U_TOP)   // 35840
#define CHUNK 64
#define NCHUNK (L_SEQ / CHUNK)    // 16

typedef __attribute__((ext_vector_type(8))) short bf16x8;
typedef __attribute__((ext_vector_type(4))) float f32x4;

__device__ inline unsigned short f2bf(float f) {
  unsigned u = __float_as_uint(f);
  u += 0x7FFFu + ((u >> 16) & 1u);   // RNE
  return (unsigned short)(u >> 16);
}

// ---------------- Threefry-2x32 (exact JAX reproduction) ----------------
__device__ inline unsigned rotl32(unsigned v, int d) { return (v << d) | (v >> (32 - d)); }

__device__ inline void tf2x32(unsigned k0, unsigned k1, unsigned x0, unsigned x1,
                              unsigned& o0, unsigned& o1) {
  unsigned ks0 = k0, ks1 = k1, ks2 = k0 ^ k1 ^ 0x1BD11BDAu;
  x0 += ks0; x1 += ks1;
#define TFR(r) { x0 += x1; x1 = rotl32(x1, r); x1 ^= x0; }
  TFR(13) TFR(15) TFR(26) TFR(6)
  x0 += ks1; x1 += ks2 + 1u;
  TFR(17) TFR(29) TFR(16) TFR(24)
  x0 += ks2; x1 += ks0 + 2u;
  TFR(13) TFR(15) TFR(26) TFR(6)
  x0 += ks0; x1 += ks1 + 3u;
  TFR(17) TFR(29) TFR(16) TFR(24)
  x0 += ks1; x1 += ks2 + 4u;
  TFR(13) TFR(15) TFR(26) TFR(6)
  x0 += ks2; x1 += ks0 + 5u;
#undef TFR
  o0 = x0; o1 = x1;
}

// foldlike split + partitionable bits (verified passing in R5)
__global__ void gen_idx(int* __restrict__ idx) {
  int j = blockIdx.x * 256 + threadIdx.x;
  if (j >= IDX_CNT) return;
  unsigned k2a, k2b;
  tf2x32(0u, 42u, 0u, 1u, k2a, k2b);      // k2 = split(key)[1]
  unsigned o0, o1;
  tf2x32(k2a, k2b, 0u, (unsigned)j, o0, o1);
  idx[j] = (int)((o0 ^ o1) & 1023u);
}

// ---------------- M[b,h,l] = max_s qk - mean_s qk over 35 sampled keys ----------------
__global__ __launch_bounds__(64) void sample_scores(
    const float* __restrict__ target, const float* __restrict__ source,
    const int* __restrict__ idx, float* __restrict__ M) {
  int blk = blockIdx.x;            // bh*1024 + l
  int l = blk & (L_SEQ - 1);
  int bh = blk >> 10;
  int h = bh & (NH - 1), b = bh >> 3;
  int lane = threadIdx.x;
  const float* q = target + ((size_t)l * BATCH + b) * DMODEL + h * DH;
  float val = 0.f;
  bool active = lane < U_TOP;
  if (active) {
    int kl = idx[l * U_TOP + lane];
    const float* kr = source + ((size_t)kl * BATCH + b) * DMODEL + h * DH;
    float s = 0.f;
#pragma unroll 8
    for (int d = 0; d < DH; ++d) s += q[d] * kr[d];
    val = s;
  }
  float vmax = active ? val : -INFINITY;
  float vsum = active ? val : 0.f;
#pragma unroll
  for (int off = 32; off; off >>= 1) {
    vmax = fmaxf(vmax, __shfl_xor(vmax, off, 64));
    vsum += __shfl_xor(vsum, off, 64);
  }
  if (lane == 0) M[(size_t)bh * L_SEQ + l] = vmax - vsum * (1.f / U_TOP);
}

// ---------------- top-35 per (b,h), ties -> lowest index; build sel map ----------------
__global__ __launch_bounds__(256) void topk_sel(const float* __restrict__ M,
                                                int* __restrict__ top, int* __restrict__ sel) {
  int bh = blockIdx.x;
  __shared__ float vals[L_SEQ];
  __shared__ float rv[256];
  __shared__ int ri[256];
  int tid = threadIdx.x;
  for (int i = tid; i < L_SEQ; i += 256) {
    vals[i] = M[(size_t)bh * L_SEQ + i];
    sel[(size_t)bh * L_SEQ + i] = -1;
  }
  __syncthreads();
  for (int it = 0; it < U_TOP; ++it) {
    float bv = -INFINITY; int bi = 0x7FFFFFFF;
    for (int i = tid; i < L_SEQ; i += 256) {
      float v = vals[i];
      if (v > bv || (v == bv && i < bi)) { bv = v; bi = i; }
    }
    rv[tid] = bv; ri[tid] = bi;
    __syncthreads();
    for (int s = 128; s; s >>= 1) {
      if (tid < s) {
        float ov = rv[tid + s]; int oi = ri[tid + s];
        if (ov > rv[tid] || (ov == rv[tid] && oi < ri[tid])) { rv[tid] = ov; ri[tid] = oi; }
      }
      __syncthreads();
    }
    if (tid == 0) {
      int bidx = ri[0];
      top[bh * U_TOP + it] = bidx;
      sel[(size_t)bh * L_SEQ + bidx] = it;
      vals[bidx] = -INFINITY;
    }
    __syncthreads();
  }
}

// ---------------- V.mean over L (V = K = source) ----------------
__global__ __launch_bounds__(768) void vmean_kernel(const float* __restrict__ source,
                                                    float* __restrict__ vmean) {
  int b = blockIdx.x;
  int d = threadIdx.x;
  float s = 0.f;
  for (int l = 0; l < L_SEQ; ++l) s += source[((size_t)l * BATCH + b) * DMODEL + d];
  vmean[b * DMODEL + d] = s * (1.f / L_SEQ);
}

// ---------------- flash-style attention, split over l-chunks ----------------
// grid = NBH*NCHUNK; block computes partial (O,m,s) for 35 queries over 64 keys.
__global__ __launch_bounds__(256) void attn_flash(
    const float* __restrict__ target, const float* __restrict__ source,
    const int* __restrict__ top,
    float* __restrict__ part_O,   // [NBH*NCHUNK][35][96]
    float* __restrict__ part_m,   // [NBH*NCHUNK][35]
    float* __restrict__ part_s) {
  int blk = blockIdx.x;
  int chunk = blk & (NCHUNK - 1);
  int bh = blk >> 4;
  int h = bh & (NH - 1), b = bh >> 3;
  __shared__ float Qs[U_TOP][97];
  __shared__ float Ks[CHUNK][97];
  __shared__ float sc[U_TOP][65];
  __shared__ float mbuf[U_TOP], sbuf[U_TOP];
  int tid = threadIdx.x;
  for (int i = tid; i < U_TOP * DH; i += 256) {
    int u = i / DH, d = i - u * DH;
    int qpos = top[bh * U_TOP + u];
    Qs[u][d] = target[((size_t)qpos * BATCH + b) * DMODEL + h * DH + d];
  }
  int l0 = chunk * CHUNK;
  for (int i = tid; i < CHUNK * DH; i += 256) {
    int r = i / DH, d = i - r * DH;
    Ks[r][d] = source[((size_t)(l0 + r) * BATCH + b) * DMODEL + h * DH + d];
  }
  __syncthreads();
  const float scale = 1.0f / sqrtf((float)DH);
  for (int i = tid; i < U_TOP * CHUNK; i += 256) {
    int u = i >> 6, r = i & 63;
    float s = 0.f;
#pragma unroll 8
    for (int d = 0; d < DH; ++d) s += Qs[u][d] * Ks[r][d];
    sc[u][r] = s * scale;
  }
  __syncthreads();
  if (tid < U_TOP) {
    float m = -INFINITY;
    for (int r = 0; r < CHUNK; ++r) m = fmaxf(m, sc[tid][r]);
    float s = 0.f;
    for (int r = 0; r < CHUNK; ++r) { float p = expf(sc[tid][r] - m); sc[tid][r] = p; s += p; }
    mbuf[tid] = m; sbuf[tid] = s;
  }
  __syncthreads();
  size_t base = (size_t)blk * U_TOP * DH;
  for (int i = tid; i < U_TOP * DH; i += 256) {
    int u = i / DH, d = i - u * DH;
    float acc = 0.f;
#pragma unroll 8
    for (int r = 0; r < CHUNK; ++r) acc += sc[u][r] * Ks[r][d];   // V = K
    part_O[base + i] = acc;
  }
  if (tid < U_TOP) {
    part_m[blk * U_TOP + tid] = mbuf[tid];
    part_s[blk * U_TOP + tid] = sbuf[tid];
  }
}

// ---------------- merge NCHUNK partials per (b,h) ----------------
__global__ __launch_bounds__(256) void attn_combine(
    const float* __restrict__ part_O, const float* __restrict__ part_m,
    const float* __restrict__ part_s, float* __restrict__ upd) {
  int bh = blockIdx.x;
  __shared__ float w[NCHUNK][U_TOP];
  __shared__ float Sinv[U_TOP];
  int tid = threadIdx.x;
  if (tid < U_TOP) {
    float m = -INFINITY;
    for (int c = 0; c < NCHUNK; ++c)
      m = fmaxf(m, part_m[(bh * NCHUNK + c) * U_TOP + tid]);
    float s = 0.f;
    for (int c = 0; c < NCHUNK; ++c) {
      float wv = expf(part_m[(bh * NCHUNK + c) * U_TOP + tid] - m);
      w[c][tid] = wv;
      s += wv * part_s[(bh * NCHUNK + c) * U_TOP + tid];
    }
    Sinv[tid] = 1.f / s;
  }
  __syncthreads();
  for (int i = tid; i < U_TOP * DH; i += 256) {
    int u = i / DH;
    float acc = 0.f;
#pragma unroll
    for (int c = 0; c < NCHUNK; ++c)
      acc += w[c][u] * part_O[((size_t)bh * NCHUNK + c) * U_TOP * DH + i];
    upd[(size_t)bh * U_TOP * DH + i] = acc * Sinv[u];
  }
}

// ---------------- attended + residual + LN1 -> normed1 (fp32 + bf16) ----------------
__global__ __launch_bounds__(256) void fuse_ln1(
    const float* __restrict__ target, const float* __restrict__ upd,
    const int* __restrict__ sel, const float* __restrict__ vmean,
    const float* __restrict__ g, const float* __restrict__ bb,
    float* __restrict__ normed1, unsigned short* __restrict__ normed1b) {
  int r = blockIdx.x;              // r = l*BATCH + b
  int l = r >> 2, b = r & 3;
  __shared__ float x[DMODEL];
  __shared__ float red[256];
  int tid = threadIdx.x;
  for (int d = tid; d < DMODEL; d += 256) {
    int h = d / DH;
    int s = sel[((size_t)(b * NH + h)) * L_SEQ + l];
    float a = (s >= 0) ? upd[((size_t)(b * NH + h) * U_TOP + s) * DH + (d - h * DH)]
                       : vmean[b * DMODEL + d];
    x[d] = target[(size_t)r * DMODEL + d] + a;
  }
  __syncthreads();
  float partial = 0.f;
  for (int d = tid; d < DMODEL; d += 256) partial += x[d];
  red[tid] = partial; __syncthreads();
  for (int s = 128; s; s >>= 1) { if (tid < s) red[tid] += red[tid + s]; __syncthreads(); }
  float mu = red[0] * (1.f / DMODEL);
  __syncthreads();
  partial = 0.f;
  for (int d = tid; d < DMODEL; d += 256) { float t = x[d] - mu; partial += t * t; }
  red[tid] = partial; __syncthreads();
  for (int s = 128; s; s >>= 1) { if (tid < s) red[tid] += red[tid + s]; __syncthreads(); }
  float rstd = 1.0f / sqrtf(red[0] * (1.f / DMODEL) + 1e-5f);
  for (int d = tid; d < DMODEL; d += 256) {
    float v = (x[d] - mu) * rstd * g[d] + bb[d];
    normed1[(size_t)r * DMODEL + d] = v;
    normed1b[(size_t)r * DMODEL + d] = f2bf(v);
  }
}

// ---------------- fp32 -> bf16 convert (for W1, W2) ----------------
__global__ __launch_bounds__(256) void convert_bf16(const float* __restrict__ in,
                                                    unsigned short* __restrict__ outp, int n4) {
  int i = blockIdx.x * 256 + threadIdx.x;
  int stride = gridDim.x * 256;
  for (; i < n4; i += stride) {
    float4 v = ((const float4*)in)[i];
    unsigned long long pk = (unsigned long long)f2bf(v.x)
                          | ((unsigned long long)f2bf(v.y) << 16)
                          | ((unsigned long long)f2bf(v.z) << 32)
                          | ((unsigned long long)f2bf(v.w) << 48);
    ((unsigned long long*)outp)[i] = pk;
  }
}

// ---------------- bf16 MFMA GEMM (verified R6): 128x128 tile, BK=64 ----------------
template <bool RELU, bool BF16OUT>
__global__ __launch_bounds__(256) void gemm_mfma(
    const unsigned short* __restrict__ A, const unsigned short* __restrict__ B,
    const float* __restrict__ bias, void* __restrict__ Cout,
    int Ndim, int Kdim) {
  __shared__ short As[128 * 64];
  __shared__ short Bs[128 * 64];
  int tid = threadIdx.x;
  int lane = tid & 63;
  int wid = tid >> 6;
  int wm = wid >> 1, wn = wid & 1;       // 2x2 waves, each 64x64
  int bm = blockIdx.y * 128, bn = blockIdx.x * 128;

  f32x4 acc[4][4] = {};

  for (int k0 = 0; k0 < Kdim; k0 += 64) {
#pragma unroll
    for (int i = 0; i < 4; ++i) {
      int trow = wid * 32 + i * 8 + (lane >> 3);
      int slot = (lane & 7) ^ (trow & 7);          // pre-swizzled global source
      const unsigned short* ga = A + (size_t)(bm + trow) * Kdim + k0 + slot * 8;
      const unsigned short* gb = B + (size_t)(bn + trow) * Kdim + k0 + slot * 8;
      __builtin_amdgcn_global_load_lds(
          (const __attribute__((address_space(1))) void*)ga,
          (__attribute__((address_space(3))) void*)(As + (wid * 32 + i * 8) * 64),
          16, 0, 0);
      __builtin_amdgcn_global_load_lds(
          (const __attribute__((address_space(1))) void*)gb,
          (__attribute__((address_space(3))) void*)(Bs + (wid * 32 + i * 8) * 64),
          16, 0, 0);
    }
    __syncthreads();
#pragma unroll
    for (int c = 0; c < 2; ++c) {
      bf16x8 af[4], bf[4];
#pragma unroll
      for (int mi = 0; mi < 4; ++mi) {
        int row = wm * 64 + mi * 16 + (lane & 15);
        int phys = (c * 4 + (lane >> 4)) ^ (row & 7);
        af[mi] = *(const bf16x8*)(As + row * 64 + phys * 8);
      }
#pragma unroll
      for (int ni = 0; ni < 4; ++ni) {
        int row = wn * 64 + ni * 16 + (lane & 15);
        int phys = (c * 4 + (lane >> 4)) ^ (row & 7);
        bf[ni] = *(const bf16x8*)(Bs + row * 64 + phys * 8);
      }
#pragma unroll
      for (int mi = 0; mi < 4; ++mi)
#pragma unroll
        for (int ni = 0; ni < 4; ++ni)
          acc[mi][ni] = __builtin_amdgcn_mfma_f32_16x16x32_bf16(af[mi], bf[ni], acc[mi][ni], 0, 0, 0);
    }
    __syncthreads();
  }

#pragma unroll
  for (int mi = 0; mi < 4; ++mi)
#pragma unroll
    for (int ni = 0; ni < 4; ++ni) {
      int col = bn + wn * 64 + ni * 16 + (lane & 15);
      float bv = bias[col];
#pragma unroll
      for (int j = 0; j < 4; ++j) {
        int row = bm + wm * 64 + mi * 16 + (lane >> 4) * 4 + j;
        float v = acc[mi][ni][j] + bv;
        if (RELU) v = fmaxf(v, 0.f);
        if (BF16OUT)
          ((unsigned short*)Cout)[(size_t)row * Ndim + col] = f2bf(v);
        else
          ((float*)Cout)[(size_t)row * Ndim + col] = v;
      }
    }
}

// ---------------- normed1 + proj -> LN2 -> out (float4, single pass) ----------------
__global__ __launch_bounds__(192) void ln2_out(
    const float* __restrict__ normed1, const float* __restrict__ proj,
    const float* __restrict__ g, const float* __restrict__ bb,
    float* __restrict__ out) {
  int r = blockIdx.x;
  int tid = threadIdx.x;           // 192 threads x float4 = 768
  __shared__ float red[6];
  float4 a = ((const float4*)(normed1 + (size_t)r * DMODEL))[tid];
  float4 p = ((const float4*)(proj + (size_t)r * DMODEL))[tid];
  float4 x = {a.x + p.x, a.y + p.y, a.z + p.z, a.w + p.w};
  float s1 = x.x + x.y + x.z + x.w;
  float s2 = x.x * x.x + x.y * x.y + x.z * x.z + x.w * x.w;
#pragma unroll
  for (int off = 32; off; off >>= 1) {
    s1 += __shfl_xor(s1, off, 64);
    s2 += __shfl_xor(s2, off, 64);
  }
  int w = tid >> 6;
  if ((tid & 63) == 0) { red[w] = s1; red[3 + w] = s2; }
  __syncthreads();
  float S1 = red[0] + red[1] + red[2];
  float S2 = red[3] + red[4] + red[5];
  float mu = S1 * (1.f / DMODEL);
  float var = S2 * (1.f / DMODEL) - mu * mu;
  float rstd = 1.0f / sqrtf(var + 1e-5f);
  float4 gv = ((const float4*)g)[tid];
  float4 bv = ((const float4*)bb)[tid];
  float4 o = {(x.x - mu) * rstd * gv.x + bv.x, (x.y - mu) * rstd * gv.y + bv.y,
              (x.z - mu) * rstd * gv.z + bv.z, (x.w - mu) * rstd * gv.w + bv.w};
  ((float4*)(out + (size_t)r * DMODEL))[tid] = o;
}

extern "C" void kernel_launch(void* const* d_in, const int* in_sizes, int n_in,
                              void* d_out, int out_size, void* d_ws, size_t ws_size,
                              hipStream_t stream) {
  const float* target = (const float*)d_in[0];
  const float* source = (const float*)d_in[1];
  const float* W1 = (const float*)d_in[2];
  const float* b1 = (const float*)d_in[3];
  const float* W2 = (const float*)d_in[4];
  const float* b2 = (const float*)d_in[5];
  const float* ln1_g = (const float*)d_in[6];
  const float* ln1_b = (const float*)d_in[7];
  const float* ln2_g = (const float*)d_in[8];
  const float* ln2_b = (const float*)d_in[9];
  float* out = (float*)d_out;

  char* ws = (char*)d_ws;
  int*            idx      = (int*)           (ws + 0x0000000);  // 140 KB
  float*          M        = (float*)         (ws + 0x0040000);  // 128 KB
  int*            top      = (int*)           (ws + 0x0080000);  // 4.4 KB
  int*            sel      = (int*)           (ws + 0x0090000);  // 128 KB
  float*          upd      = (float*)         (ws + 0x00C0000);  // 420 KB
  float*          vmean    = (float*)         (ws + 0x0130000);  // 12 KB
  float*          part_m   = (float*)         (ws + 0x0140000);  // 72 KB
  float*          part_s   = (float*)         (ws + 0x0160000);  // 72 KB
  unsigned short* w1b      = (unsigned short*)(ws + 0x0180000);  // 3 MB
  unsigned short* w2b      = (unsigned short*)(ws + 0x0480000);  // 3 MB
  unsigned short* normed1b = (unsigned short*)(ws + 0x0780000);  // 6 MB
  float*          normed1  = (float*)         (ws + 0x0D80000);  // 12 MB
  unsigned short* h1b      = (unsigned short*)(ws + 0x1980000);  // 16 MB
  float*          part_O   = (float*)         (ws + 0x1980000);  // 6.9 MB, aliases h1b (used before gemm1)
  float*          proj     = (float*)         (ws + 0x2980000);  // 12 MB -> ends 0x3580000 (56 MB)

  gen_idx<<<(IDX_CNT + 255) / 256, 256, 0, stream>>>(idx);
  sample_scores<<<NBH * L_SEQ, 64, 0, stream>>>(target, source, idx, M);
  topk_sel<<<NBH, 256, 0, stream>>>(M, top, sel);
  vmean_kernel<<<BATCH, DMODEL, 0, stream>>>(source, vmean);
  attn_flash<<<NBH * NCHUNK, 256, 0, stream>>>(target, source, top, part_O, part_m, part_s);
  attn_combine<<<NBH, 256, 0, stream>>>(part_O, part_m, part_s, upd);
  convert_bf16<<<1024, 256, 0, stream>>>(W1, w1b, DFF * DMODEL / 4);
  convert_bf16<<<1024, 256, 0, stream>>>(W2, w2b, DFF * DMODEL / 4);
  fuse_ln1<<<NROWS, 256, 0, stream>>>(target, upd, sel, vmean, ln1_g, ln1_b, normed1, normed1b);
  {
    dim3 grid(DFF / 128, NROWS / 128);   // 16 x 32
    gemm_mfma<true, true><<<grid, 256, 0, stream>>>(normed1b, w1b, b1, h1b, DFF, DMODEL);
  }
  {
    dim3 grid(DMODEL / 128, NROWS / 128);  // 6 x 32
    gemm_mfma<false, false><<<grid, 256, 0, stream>>>(h1b, w2b, b2, proj, DMODEL, DFF);
  }
  ln2_out<<<NROWS, 192, 0, stream>>>(normed1, proj, ln2_g, ln2_b, out);
}

// Round 10
// 275.289 us; speedup vs baseline: 3.6181x; 1.2920x over previous
//
#include <hip/hip_runtime.h>
#include <hip/hip_bf16.h>
#include <math.h>

#define L_SEQ 1024
#define BATCH 4
#define DMODEL 768
#define NH 8
#define DH 96
#define DFF 2048
#define U_TOP 35
#define NROWS (L_SEQ * BATCH)
#define NBH (BATCH * NH)
#define IDX_CNT (L_SEQ * U_TOP)   // 35840
#define CHUNK 64
#define NCHUNK (L_SEQ / CHUNK)    // 16
#define VCH 64                    // vmean chunks per batch

typedef __attribute__((ext_vector_type(8))) short bf16x8;
typedef __attribute__((ext_vector_type(4))) float f32x4;

__device__ inline unsigned short f2bf(float f) {
  unsigned u = __float_as_uint(f);
  u += 0x7FFFu + ((u >> 16) & 1u);   // RNE
  return (unsigned short)(u >> 16);
}

// ---------------- Threefry-2x32 (exact JAX reproduction) ----------------
__device__ inline unsigned rotl32(unsigned v, int d) { return (v << d) | (v >> (32 - d)); }

__device__ inline void tf2x32(unsigned k0, unsigned k1, unsigned x0, unsigned x1,
                              unsigned& o0, unsigned& o1) {
  unsigned ks0 = k0, ks1 = k1, ks2 = k0 ^ k1 ^ 0x1BD11BDAu;
  x0 += ks0; x1 += ks1;
#define TFR(r) { x0 += x1; x1 = rotl32(x1, r); x1 ^= x0; }
  TFR(13) TFR(15) TFR(26) TFR(6)
  x0 += ks1; x1 += ks2 + 1u;
  TFR(17) TFR(29) TFR(16) TFR(24)
  x0 += ks2; x1 += ks0 + 2u;
  TFR(13) TFR(15) TFR(26) TFR(6)
  x0 += ks0; x1 += ks1 + 3u;
  TFR(17) TFR(29) TFR(16) TFR(24)
  x0 += ks1; x1 += ks2 + 4u;
  TFR(13) TFR(15) TFR(26) TFR(6)
  x0 += ks2; x1 += ks0 + 5u;
#undef TFR
  o0 = x0; o1 = x1;
}

// foldlike split + partitionable bits (verified passing in R5)
__global__ void gen_idx(int* __restrict__ idx) {
  int j = blockIdx.x * 256 + threadIdx.x;
  if (j >= IDX_CNT) return;
  unsigned k2a, k2b;
  tf2x32(0u, 42u, 0u, 1u, k2a, k2b);      // k2 = split(key)[1]
  unsigned o0, o1;
  tf2x32(k2a, k2b, 0u, (unsigned)j, o0, o1);
  idx[j] = (int)((o0 ^ o1) & 1023u);
}

// ---------------- M[b,h,l]: 4 waves/block, float4 dots ----------------
__global__ __launch_bounds__(256) void sample_scores(
    const float* __restrict__ target, const float* __restrict__ source,
    const int* __restrict__ idx, float* __restrict__ M) {
  int blk = blockIdx.x;            // bh*256 + l4
  int l4 = blk & 255;
  int bh = blk >> 8;
  int h = bh & (NH - 1), b = bh >> 3;
  int wv = threadIdx.x >> 6;
  int lane = threadIdx.x & 63;
  int l = l4 * 4 + wv;
  const float4* q = (const float4*)(target + ((size_t)l * BATCH + b) * DMODEL + h * DH);
  float val = 0.f;
  bool active = lane < U_TOP;
  if (active) {
    int kl = idx[l * U_TOP + lane];
    const float4* kr = (const float4*)(source + ((size_t)kl * BATCH + b) * DMODEL + h * DH);
    float s = 0.f;
#pragma unroll
    for (int d = 0; d < DH / 4; ++d) {
      float4 qa = q[d], ka = kr[d];
      s += qa.x * ka.x + qa.y * ka.y + qa.z * ka.z + qa.w * ka.w;
    }
    val = s;
  }
  float vmax = active ? val : -INFINITY;
  float vsum = active ? val : 0.f;
#pragma unroll
  for (int off = 32; off; off >>= 1) {
    vmax = fmaxf(vmax, __shfl_xor(vmax, off, 64));
    vsum += __shfl_xor(vsum, off, 64);
  }
  if (lane == 0) M[(size_t)bh * L_SEQ + l] = vmax - vsum * (1.f / U_TOP);
}

// ---------------- top-35 per (b,h): register-resident, shuffle-reduce ----------------
__global__ __launch_bounds__(256) void topk_sel(const float* __restrict__ M,
                                                int* __restrict__ top, int* __restrict__ sel) {
  int bh = blockIdx.x;
  int tid = threadIdx.x;
  int lane = tid & 63, w = tid >> 6;
  __shared__ float wval[4];
  __shared__ int widx[4];
  __shared__ int bidx_sh;
  float v[4]; int ir[4];
#pragma unroll
  for (int i = 0; i < 4; ++i) {
    int ii = tid + i * 256;
    v[i] = M[(size_t)bh * L_SEQ + ii];
    ir[i] = ii;
    sel[(size_t)bh * L_SEQ + ii] = -1;
  }
  for (int it = 0; it < U_TOP; ++it) {
    float bv = v[0]; int bi = ir[0];
#pragma unroll
    for (int i = 1; i < 4; ++i)
      if (v[i] > bv || (v[i] == bv && ir[i] < bi)) { bv = v[i]; bi = ir[i]; }
#pragma unroll
    for (int off = 32; off; off >>= 1) {
      float ov = __shfl_xor(bv, off, 64);
      int oi = __shfl_xor(bi, off, 64);
      if (ov > bv || (ov == bv && oi < bi)) { bv = ov; bi = oi; }
    }
    if (lane == 0) { wval[w] = bv; widx[w] = bi; }
    __syncthreads();
    if (tid == 0) {
      float fv = wval[0]; int fi = widx[0];
#pragma unroll
      for (int k = 1; k < 4; ++k)
        if (wval[k] > fv || (wval[k] == fv && widx[k] < fi)) { fv = wval[k]; fi = widx[k]; }
      top[bh * U_TOP + it] = fi;
      sel[(size_t)bh * L_SEQ + fi] = it;
      bidx_sh = fi;
    }
    __syncthreads();
    int rb = bidx_sh;
    if ((rb & 255) == tid) v[rb >> 8] = -INFINITY;
  }
}

// ---------------- V.mean: two-phase ----------------
__global__ __launch_bounds__(768) void vmean_part(const float* __restrict__ source,
                                                  float* __restrict__ part) {
  int blk = blockIdx.x;            // b*VCH + c
  int b = blk >> 6, c = blk & (VCH - 1);
  int d = threadIdx.x;
  float s = 0.f;
  int l0 = c * (L_SEQ / VCH);
#pragma unroll
  for (int l = l0; l < l0 + L_SEQ / VCH; ++l)
    s += source[((size_t)l * BATCH + b) * DMODEL + d];
  part[(size_t)blk * DMODEL + d] = s;
}

__global__ __launch_bounds__(768) void vmean_comb(const float* __restrict__ part,
                                                  float* __restrict__ vmean) {
  int b = blockIdx.x;
  int d = threadIdx.x;
  float s = 0.f;
  for (int c = 0; c < VCH; ++c) s += part[((size_t)(b * VCH + c)) * DMODEL + d];
  vmean[b * DMODEL + d] = s * (1.f / L_SEQ);
}

// ---------------- flash-style attention, split over l-chunks ----------------
__global__ __launch_bounds__(256) void attn_flash(
    const float* __restrict__ target, const float* __restrict__ source,
    const int* __restrict__ top,
    float* __restrict__ part_O,   // [NBH*NCHUNK][35][96]
    float* __restrict__ part_m,   // [NBH*NCHUNK][35]
    float* __restrict__ part_s) {
  int blk = blockIdx.x;
  int chunk = blk & (NCHUNK - 1);
  int bh = blk >> 4;
  int h = bh & (NH - 1), b = bh >> 3;
  __shared__ float Qs[U_TOP][97];
  __shared__ float Ks[CHUNK][97];
  __shared__ float sc[U_TOP][65];
  __shared__ float mbuf[U_TOP], sbuf[U_TOP];
  int tid = threadIdx.x;
  for (int i = tid; i < U_TOP * DH; i += 256) {
    int u = i / DH, d = i - u * DH;
    int qpos = top[bh * U_TOP + u];
    Qs[u][d] = target[((size_t)qpos * BATCH + b) * DMODEL + h * DH + d];
  }
  int l0 = chunk * CHUNK;
  for (int i = tid; i < CHUNK * DH; i += 256) {
    int r = i / DH, d = i - r * DH;
    Ks[r][d] = source[((size_t)(l0 + r) * BATCH + b) * DMODEL + h * DH + d];
  }
  __syncthreads();
  const float scale = 1.0f / sqrtf((float)DH);
  for (int i = tid; i < U_TOP * CHUNK; i += 256) {
    int u = i >> 6, r = i & 63;
    float s = 0.f;
#pragma unroll 8
    for (int d = 0; d < DH; ++d) s += Qs[u][d] * Ks[r][d];
    sc[u][r] = s * scale;
  }
  __syncthreads();
  if (tid < U_TOP) {
    float m = -INFINITY;
    for (int r = 0; r < CHUNK; ++r) m = fmaxf(m, sc[tid][r]);
    float s = 0.f;
    for (int r = 0; r < CHUNK; ++r) { float p = expf(sc[tid][r] - m); sc[tid][r] = p; s += p; }
    mbuf[tid] = m; sbuf[tid] = s;
  }
  __syncthreads();
  size_t base = (size_t)blk * U_TOP * DH;
  for (int i = tid; i < U_TOP * DH; i += 256) {
    int u = i / DH, d = i - u * DH;
    float acc = 0.f;
#pragma unroll 8
    for (int r = 0; r < CHUNK; ++r) acc += sc[u][r] * Ks[r][d];   // V = K
    part_O[base + i] = acc;
  }
  if (tid < U_TOP) {
    part_m[blk * U_TOP + tid] = mbuf[tid];
    part_s[blk * U_TOP + tid] = sbuf[tid];
  }
}

// ---------------- merge NCHUNK partials per (b,h) ----------------
__global__ __launch_bounds__(256) void attn_combine(
    const float* __restrict__ part_O, const float* __restrict__ part_m,
    const float* __restrict__ part_s, float* __restrict__ upd) {
  int bh = blockIdx.x;
  __shared__ float w[NCHUNK][U_TOP];
  __shared__ float Sinv[U_TOP];
  int tid = threadIdx.x;
  if (tid < U_TOP) {
    float m = -INFINITY;
    for (int c = 0; c < NCHUNK; ++c)
      m = fmaxf(m, part_m[(bh * NCHUNK + c) * U_TOP + tid]);
    float s = 0.f;
    for (int c = 0; c < NCHUNK; ++c) {
      float wv = expf(part_m[(bh * NCHUNK + c) * U_TOP + tid] - m);
      w[c][tid] = wv;
      s += wv * part_s[(bh * NCHUNK + c) * U_TOP + tid];
    }
    Sinv[tid] = 1.f / s;
  }
  __syncthreads();
  for (int i = tid; i < U_TOP * DH; i += 256) {
    int u = i / DH;
    float acc = 0.f;
#pragma unroll
    for (int c = 0; c < NCHUNK; ++c)
      acc += w[c][u] * part_O[((size_t)bh * NCHUNK + c) * U_TOP * DH + i];
    upd[(size_t)bh * U_TOP * DH + i] = acc * Sinv[u];
  }
}

// ---------------- attended + residual + LN1 -> normed1 (fp32 + bf16) ----------------
__global__ __launch_bounds__(256) void fuse_ln1(
    const float* __restrict__ target, const float* __restrict__ upd,
    const int* __restrict__ sel, const float* __restrict__ vmean,
    const float* __restrict__ g, const float* __restrict__ bb,
    float* __restrict__ normed1, unsigned short* __restrict__ normed1b) {
  int r = blockIdx.x;              // r = l*BATCH + b
  int l = r >> 2, b = r & 3;
  __shared__ float x[DMODEL];
  __shared__ float red[256];
  int tid = threadIdx.x;
  for (int d = tid; d < DMODEL; d += 256) {
    int h = d / DH;
    int s = sel[((size_t)(b * NH + h)) * L_SEQ + l];
    float a = (s >= 0) ? upd[((size_t)(b * NH + h) * U_TOP + s) * DH + (d - h * DH)]
                       : vmean[b * DMODEL + d];
    x[d] = target[(size_t)r * DMODEL + d] + a;
  }
  __syncthreads();
  float partial = 0.f;
  for (int d = tid; d < DMODEL; d += 256) partial += x[d];
  red[tid] = partial; __syncthreads();
  for (int s = 128; s; s >>= 1) { if (tid < s) red[tid] += red[tid + s]; __syncthreads(); }
  float mu = red[0] * (1.f / DMODEL);
  __syncthreads();
  partial = 0.f;
  for (int d = tid; d < DMODEL; d += 256) { float t = x[d] - mu; partial += t * t; }
  red[tid] = partial; __syncthreads();
  for (int s = 128; s; s >>= 1) { if (tid < s) red[tid] += red[tid + s]; __syncthreads(); }
  float rstd = 1.0f / sqrtf(red[0] * (1.f / DMODEL) + 1e-5f);
  for (int d = tid; d < DMODEL; d += 256) {
    float v = (x[d] - mu) * rstd * g[d] + bb[d];
    normed1[(size_t)r * DMODEL + d] = v;
    normed1b[(size_t)r * DMODEL + d] = f2bf(v);
  }
}

// ---------------- fp32 -> bf16 convert (for W1, W2) ----------------
__global__ __launch_bounds__(256) void convert_bf16(const float* __restrict__ in,
                                                    unsigned short* __restrict__ outp, int n4) {
  int i = blockIdx.x * 256 + threadIdx.x;
  int stride = gridDim.x * 256;
  for (; i < n4; i += stride) {
    float4 v = ((const float4*)in)[i];
    unsigned long long pk = (unsigned long long)f2bf(v.x)
                          | ((unsigned long long)f2bf(v.y) << 16)
                          | ((unsigned long long)f2bf(v.z) << 32)
                          | ((unsigned long long)f2bf(v.w) << 48);
    ((unsigned long long*)outp)[i] = pk;
  }
}

// ---------------- bf16 MFMA GEMM (verified R6): 128x128 tile, BK=64 ----------------
template <bool RELU, bool BF16OUT>
__global__ __launch_bounds__(256) void gemm_mfma(
    const unsigned short* __restrict__ A, const unsigned short* __restrict__ B,
    const float* __restrict__ bias, void* __restrict__ Cout,
    int Ndim, int Kdim) {
  __shared__ short As[128 * 64];
  __shared__ short Bs[128 * 64];
  int tid = threadIdx.x;
  int lane = tid & 63;
  int wid = tid >> 6;
  int wm = wid >> 1, wn = wid & 1;       // 2x2 waves, each 64x64
  int bm = blockIdx.y * 128, bn = blockIdx.x * 128;

  f32x4 acc[4][4] = {};

  for (int k0 = 0; k0 < Kdim; k0 += 64) {
#pragma unroll
    for (int i = 0; i < 4; ++i) {
      int trow = wid * 32 + i * 8 + (lane >> 3);
      int slot = (lane & 7) ^ (trow & 7);          // pre-swizzled global source
      const unsigned short* ga = A + (size_t)(bm + trow) * Kdim + k0 + slot * 8;
      const unsigned short* gb = B + (size_t)(bn + trow) * Kdim + k0 + slot * 8;
      __builtin_amdgcn_global_load_lds(
          (const __attribute__((address_space(1))) void*)ga,
          (__attribute__((address_space(3))) void*)(As + (wid * 32 + i * 8) * 64),
          16, 0, 0);
      __builtin_amdgcn_global_load_lds(
          (const __attribute__((address_space(1))) void*)gb,
          (__attribute__((address_space(3))) void*)(Bs + (wid * 32 + i * 8) * 64),
          16, 0, 0);
    }
    __syncthreads();
#pragma unroll
    for (int c = 0; c < 2; ++c) {
      bf16x8 af[4], bf[4];
#pragma unroll
      for (int mi = 0; mi < 4; ++mi) {
        int row = wm * 64 + mi * 16 + (lane & 15);
        int phys = (c * 4 + (lane >> 4)) ^ (row & 7);
        af[mi] = *(const bf16x8*)(As + row * 64 + phys * 8);
      }
#pragma unroll
      for (int ni = 0; ni < 4; ++ni) {
        int row = wn * 64 + ni * 16 + (lane & 15);
        int phys = (c * 4 + (lane >> 4)) ^ (row & 7);
        bf[ni] = *(const bf16x8*)(Bs + row * 64 + phys * 8);
      }
#pragma unroll
      for (int mi = 0; mi < 4; ++mi)
#pragma unroll
        for (int ni = 0; ni < 4; ++ni)
          acc[mi][ni] = __builtin_amdgcn_mfma_f32_16x16x32_bf16(af[mi], bf[ni], acc[mi][ni], 0, 0, 0);
    }
    __syncthreads();
  }

#pragma unroll
  for (int mi = 0; mi < 4; ++mi)
#pragma unroll
    for (int ni = 0; ni < 4; ++ni) {
      int col = bn + wn * 64 + ni * 16 + (lane & 15);
      float bv = bias[col];
#pragma unroll
      for (int j = 0; j < 4; ++j) {
        int row = bm + wm * 64 + mi * 16 + (lane >> 4) * 4 + j;
        float v = acc[mi][ni][j] + bv;
        if (RELU) v = fmaxf(v, 0.f);
        if (BF16OUT)
          ((unsigned short*)Cout)[(size_t)row * Ndim + col] = f2bf(v);
        else
          ((float*)Cout)[(size_t)row * Ndim + col] = v;
      }
    }
}

// ---------------- normed1 + proj -> LN2 -> out (float4, single pass) ----------------
__global__ __launch_bounds__(192) void ln2_out(
    const float* __restrict__ normed1, const float* __restrict__ proj,
    const float* __restrict__ g, const float* __restrict__ bb,
    float* __restrict__ out) {
  int r = blockIdx.x;
  int tid = threadIdx.x;           // 192 threads x float4 = 768
  __shared__ float red[6];
  float4 a = ((const float4*)(normed1 + (size_t)r * DMODEL))[tid];
  float4 p = ((const float4*)(proj + (size_t)r * DMODEL))[tid];
  float4 x = {a.x + p.x, a.y + p.y, a.z + p.z, a.w + p.w};
  float s1 = x.x + x.y + x.z + x.w;
  float s2 = x.x * x.x + x.y * x.y + x.z * x.z + x.w * x.w;
#pragma unroll
  for (int off = 32; off; off >>= 1) {
    s1 += __shfl_xor(s1, off, 64);
    s2 += __shfl_xor(s2, off, 64);
  }
  int w = tid >> 6;
  if ((tid & 63) == 0) { red[w] = s1; red[3 + w] = s2; }
  __syncthreads();
  float S1 = red[0] + red[1] + red[2];
  float S2 = red[3] + red[4] + red[5];
  float mu = S1 * (1.f / DMODEL);
  float var = S2 * (1.f / DMODEL) - mu * mu;
  float rstd = 1.0f / sqrtf(var + 1e-5f);
  float4 gv = ((const float4*)g)[tid];
  float4 bv = ((const float4*)bb)[tid];
  float4 o = {(x.x - mu) * rstd * gv.x + bv.x, (x.y - mu) * rstd * gv.y + bv.y,
              (x.z - mu) * rstd * gv.z + bv.z, (x.w - mu) * rstd * gv.w + bv.w};
  ((float4*)(out + (size_t)r * DMODEL))[tid] = o;
}

extern "C" void kernel_launch(void* const* d_in, const int* in_sizes, int n_in,
                              void* d_out, int out_size, void* d_ws, size_t ws_size,
                              hipStream_t stream) {
  const float* target = (const float*)d_in[0];
  const float* source = (const float*)d_in[1];
  const float* W1 = (const float*)d_in[2];
  const float* b1 = (const float*)d_in[3];
  const float* W2 = (const float*)d_in[4];
  const float* b2 = (const float*)d_in[5];
  const float* ln1_g = (const float*)d_in[6];
  const float* ln1_b = (const float*)d_in[7];
  const float* ln2_g = (const float*)d_in[8];
  const float* ln2_b = (const float*)d_in[9];
  float* out = (float*)d_out;

  char* ws = (char*)d_ws;
  int*            idx      = (int*)           (ws + 0x0000000);  // 140 KB
  float*          M        = (float*)         (ws + 0x0040000);  // 128 KB
  int*            top      = (int*)           (ws + 0x0080000);  // 4.4 KB
  int*            sel      = (int*)           (ws + 0x0090000);  // 128 KB
  float*          upd      = (float*)         (ws + 0x00C0000);  // 420 KB
  float*          vmean    = (float*)         (ws + 0x0130000);  // 12 KB
  float*          part_m   = (float*)         (ws + 0x0140000);  // 72 KB
  float*          part_s   = (float*)         (ws + 0x0160000);  // 72 KB
  unsigned short* w1b      = (unsigned short*)(ws + 0x0180000);  // 3 MB
  unsigned short* w2b      = (unsigned short*)(ws + 0x0480000);  // 3 MB
  unsigned short* normed1b = (unsigned short*)(ws + 0x0780000);  // 6 MB
  float*          normed1  = (float*)         (ws + 0x0D80000);  // 12 MB
  unsigned short* h1b      = (unsigned short*)(ws + 0x1980000);  // 16 MB region
  float*          part_O   = (float*)         (ws + 0x1980000);  // 6.9 MB, aliases h1b (dead before gemm1)
  float*          vpart    = (float*)         (ws + 0x2200000);  // 786 KB, aliases h1b (dead before gemm1)
  float*          proj     = (float*)         (ws + 0x2980000);  // 12 MB -> ends 0x3580000 (56 MB)

  gen_idx<<<(IDX_CNT + 255) / 256, 256, 0, stream>>>(idx);
  sample_scores<<<NBH * 256, 256, 0, stream>>>(target, source, idx, M);
  topk_sel<<<NBH, 256, 0, stream>>>(M, top, sel);
  vmean_part<<<BATCH * VCH, 768, 0, stream>>>(source, vpart);
  vmean_comb<<<BATCH, 768, 0, stream>>>(vpart, vmean);
  attn_flash<<<NBH * NCHUNK, 256, 0, stream>>>(target, source, top, part_O, part_m, part_s);
  attn_combine<<<NBH, 256, 0, stream>>>(part_O, part_m, part_s, upd);
  convert_bf16<<<1024, 256, 0, stream>>>(W1, w1b, DFF * DMODEL / 4);
  convert_bf16<<<1024, 256, 0, stream>>>(W2, w2b, DFF * DMODEL / 4);
  fuse_ln1<<<NROWS, 256, 0, stream>>>(target, upd, sel, vmean, ln1_g, ln1_b, normed1, normed1b);
  {
    dim3 grid(DFF / 128, NROWS / 128);   // 16 x 32
    gemm_mfma<true, true><<<grid, 256, 0, stream>>>(normed1b, w1b, b1, h1b, DFF, DMODEL);
  }
  {
    dim3 grid(DMODEL / 128, NROWS / 128);  // 6 x 32
    gemm_mfma<false, false><<<grid, 256, 0, stream>>>(h1b, w2b, b2, proj, DMODEL, DFF);
  }
  ln2_out<<<NROWS, 192, 0, stream>>>(normed1, proj, ln2_g, ln2_b, out);
}

// Round 11
// 238.941 us; speedup vs baseline: 4.1684x; 1.1521x over previous
//
#include <hip/hip_runtime.h>
#include <hip/hip_bf16.h>
#include <math.h>

#define L_SEQ 1024
#define BATCH 4
#define DMODEL 768
#define NH 8
#define DH 96
#define DFF 2048
#define U_TOP 35
#define NROWS (L_SEQ * BATCH)
#define NBH (BATCH * NH)
#define IDX_CNT (L_SEQ * U_TOP)   // 35840
#define CHUNK 64
#define NCHUNK (L_SEQ / CHUNK)    // 16
#define VCH 64                    // vmean chunks per batch
#define SCH 7                     // samples staged per chunk (5 chunks x 7 = 35)

typedef __attribute__((ext_vector_type(8))) short bf16x8;
typedef __attribute__((ext_vector_type(4))) float f32x4;

__device__ inline unsigned short f2bf(float f) {
  unsigned u = __float_as_uint(f);
  u += 0x7FFFu + ((u >> 16) & 1u);   // RNE
  return (unsigned short)(u >> 16);
}

// ---------------- Threefry-2x32 (exact JAX reproduction) ----------------
__device__ inline unsigned rotl32(unsigned v, int d) { return (v << d) | (v >> (32 - d)); }

__device__ inline void tf2x32(unsigned k0, unsigned k1, unsigned x0, unsigned x1,
                              unsigned& o0, unsigned& o1) {
  unsigned ks0 = k0, ks1 = k1, ks2 = k0 ^ k1 ^ 0x1BD11BDAu;
  x0 += ks0; x1 += ks1;
#define TFR(r) { x0 += x1; x1 = rotl32(x1, r); x1 ^= x0; }
  TFR(13) TFR(15) TFR(26) TFR(6)
  x0 += ks1; x1 += ks2 + 1u;
  TFR(17) TFR(29) TFR(16) TFR(24)
  x0 += ks2; x1 += ks0 + 2u;
  TFR(13) TFR(15) TFR(26) TFR(6)
  x0 += ks0; x1 += ks1 + 3u;
  TFR(17) TFR(29) TFR(16) TFR(24)
  x0 += ks1; x1 += ks2 + 4u;
  TFR(13) TFR(15) TFR(26) TFR(6)
  x0 += ks2; x1 += ks0 + 5u;
#undef TFR
  o0 = x0; o1 = x1;
}

// foldlike split + partitionable bits (verified passing in R5)
__global__ void gen_idx(int* __restrict__ idx) {
  int j = blockIdx.x * 256 + threadIdx.x;
  if (j >= IDX_CNT) return;
  unsigned k2a, k2b;
  tf2x32(0u, 42u, 0u, 1u, k2a, k2b);      // k2 = split(key)[1]
  unsigned o0, o1;
  tf2x32(k2a, k2b, 0u, (unsigned)j, o0, o1);
  idx[j] = (int)((o0 ^ o1) & 1023u);
}

// ---------------- M[b,h,l]: block per (b,l), all 8 heads, LDS-staged K rows ----------------
// K rows (3 KB each) staged coalesced ONCE per (b,l) instead of 8x (once per head).
// LDS layout [s][h*97+d]: dot-read bank = h + 8*((s+3p)%4) -> 2 lanes/bank (free).
__global__ __launch_bounds__(256) void sample_scores(
    const float* __restrict__ target, const float* __restrict__ source,
    const int* __restrict__ idx, float* __restrict__ M) {
  int blk = blockIdx.x;            // b*L_SEQ + l
  int l = blk & (L_SEQ - 1);
  int b = blk >> 10;
  __shared__ float Qs[776];            // [8 heads][97]
  __shared__ float Ks[SCH][776];
  __shared__ float qkbuf[NH][36];
  __shared__ int sidx[U_TOP];
  int tid = threadIdx.x;
  if (tid < U_TOP) sidx[tid] = idx[l * U_TOP + tid];
  if (tid < DMODEL / 4) {
    float4 v = ((const float4*)(target + ((size_t)l * BATCH + b) * DMODEL))[tid];
    int dg = tid * 4;
    int h = dg / DH;
    int off = h * 97 + (dg - h * DH);
    Qs[off] = v.x; Qs[off + 1] = v.y; Qs[off + 2] = v.z; Qs[off + 3] = v.w;
  }
  __syncthreads();
  for (int c = 0; c < U_TOP / SCH; ++c) {
    // stage 7 K rows (each 768 floats) coalesced
    for (int i = tid; i < SCH * (DMODEL / 4); i += 256) {
      int s = i / (DMODEL / 4), t4 = i - s * (DMODEL / 4);
      int kl = sidx[c * SCH + s];
      float4 v = ((const float4*)(source + ((size_t)kl * BATCH + b) * DMODEL))[t4];
      int dg = t4 * 4;
      int h = dg / DH;
      float* dst = &Ks[s][h * 97 + (dg - h * DH)];
      dst[0] = v.x; dst[1] = v.y; dst[2] = v.z; dst[3] = v.w;
    }
    __syncthreads();
    if (tid < SCH * 32) {
      int s = tid >> 5;
      int rem = tid & 31;
      int h = rem >> 2, p = rem & 3;
      int qoff = h * 97 + p * 24;
      const float* kk = &Ks[s][qoff];
      const float* qq = &Qs[qoff];
      float a = 0.f;
#pragma unroll
      for (int j = 0; j < 24; ++j) a += qq[j] * kk[j];
      a += __shfl_xor(a, 1, 64);
      a += __shfl_xor(a, 2, 64);
      if (p == 0) qkbuf[h][c * SCH + s] = a;
    }
    __syncthreads();
  }
  int w = tid >> 6, lane = tid & 63;
#pragma unroll
  for (int hi = 0; hi < 2; ++hi) {
    int hh = w * 2 + hi;
    float v = (lane < U_TOP) ? qkbuf[hh][lane] : -INFINITY;
    float sm = (lane < U_TOP) ? v : 0.f;
    float mx = v;
#pragma unroll
    for (int off = 32; off; off >>= 1) {
      mx = fmaxf(mx, __shfl_xor(mx, off, 64));
      sm += __shfl_xor(sm, off, 64);
    }
    if (lane == 0)
      M[(size_t)(b * NH + hh) * L_SEQ + l] = mx - sm * (1.f / U_TOP);
  }
}

// ---------------- top-35 per (b,h): register-resident, shuffle-reduce ----------------
__global__ __launch_bounds__(256) void topk_sel(const float* __restrict__ M,
                                                int* __restrict__ top, int* __restrict__ sel) {
  int bh = blockIdx.x;
  int tid = threadIdx.x;
  int lane = tid & 63, w = tid >> 6;
  __shared__ float wval[4];
  __shared__ int widx[4];
  __shared__ int bidx_sh;
  float v[4]; int ir[4];
#pragma unroll
  for (int i = 0; i < 4; ++i) {
    int ii = tid + i * 256;
    v[i] = M[(size_t)bh * L_SEQ + ii];
    ir[i] = ii;
    sel[(size_t)bh * L_SEQ + ii] = -1;
  }
  for (int it = 0; it < U_TOP; ++it) {
    float bv = v[0]; int bi = ir[0];
#pragma unroll
    for (int i = 1; i < 4; ++i)
      if (v[i] > bv || (v[i] == bv && ir[i] < bi)) { bv = v[i]; bi = ir[i]; }
#pragma unroll
    for (int off = 32; off; off >>= 1) {
      float ov = __shfl_xor(bv, off, 64);
      int oi = __shfl_xor(bi, off, 64);
      if (ov > bv || (ov == bv && oi < bi)) { bv = ov; bi = oi; }
    }
    if (lane == 0) { wval[w] = bv; widx[w] = bi; }
    __syncthreads();
    if (tid == 0) {
      float fv = wval[0]; int fi = widx[0];
#pragma unroll
      for (int k = 1; k < 4; ++k)
        if (wval[k] > fv || (wval[k] == fv && widx[k] < fi)) { fv = wval[k]; fi = widx[k]; }
      top[bh * U_TOP + it] = fi;
      sel[(size_t)bh * L_SEQ + fi] = it;
      bidx_sh = fi;
    }
    __syncthreads();
    int rb = bidx_sh;
    if ((rb & 255) == tid) v[rb >> 8] = -INFINITY;
  }
}

// ---------------- V.mean: two-phase ----------------
__global__ __launch_bounds__(768) void vmean_part(const float* __restrict__ source,
                                                  float* __restrict__ part) {
  int blk = blockIdx.x;            // b*VCH + c
  int b = blk >> 6, c = blk & (VCH - 1);
  int d = threadIdx.x;
  float s = 0.f;
  int l0 = c * (L_SEQ / VCH);
#pragma unroll
  for (int l = l0; l < l0 + L_SEQ / VCH; ++l)
    s += source[((size_t)l * BATCH + b) * DMODEL + d];
  part[(size_t)blk * DMODEL + d] = s;
}

__global__ __launch_bounds__(768) void vmean_comb(const float* __restrict__ part,
                                                  float* __restrict__ vmean) {
  int b = blockIdx.x;
  int d = threadIdx.x;
  float s = 0.f;
  for (int c = 0; c < VCH; ++c) s += part[((size_t)(b * VCH + c)) * DMODEL + d];
  vmean[b * DMODEL + d] = s * (1.f / L_SEQ);
}

// ---------------- flash-style attention, split over l-chunks ----------------
__global__ __launch_bounds__(256) void attn_flash(
    const float* __restrict__ target, const float* __restrict__ source,
    const int* __restrict__ top,
    float* __restrict__ part_O,   // [NBH*NCHUNK][35][96]
    float* __restrict__ part_m,   // [NBH*NCHUNK][35]
    float* __restrict__ part_s) {
  int blk = blockIdx.x;
  int chunk = blk & (NCHUNK - 1);
  int bh = blk >> 4;
  int h = bh & (NH - 1), b = bh >> 3;
  __shared__ float Qs[U_TOP][97];
  __shared__ float Ks[CHUNK][97];
  __shared__ float sc[U_TOP][65];
  __shared__ float mbuf[U_TOP], sbuf[U_TOP];
  int tid = threadIdx.x;
  for (int i = tid; i < U_TOP * DH; i += 256) {
    int u = i / DH, d = i - u * DH;
    int qpos = top[bh * U_TOP + u];
    Qs[u][d] = target[((size_t)qpos * BATCH + b) * DMODEL + h * DH + d];
  }
  int l0 = chunk * CHUNK;
  for (int i = tid; i < CHUNK * DH; i += 256) {
    int r = i / DH, d = i - r * DH;
    Ks[r][d] = source[((size_t)(l0 + r) * BATCH + b) * DMODEL + h * DH + d];
  }
  __syncthreads();
  const float scale = 1.0f / sqrtf((float)DH);
  for (int i = tid; i < U_TOP * CHUNK; i += 256) {
    int u = i >> 6, r = i & 63;
    float s = 0.f;
#pragma unroll 8
    for (int d = 0; d < DH; ++d) s += Qs[u][d] * Ks[r][d];
    sc[u][r] = s * scale;
  }
  __syncthreads();
  if (tid < U_TOP) {
    float m = -INFINITY;
    for (int r = 0; r < CHUNK; ++r) m = fmaxf(m, sc[tid][r]);
    float s = 0.f;
    for (int r = 0; r < CHUNK; ++r) { float p = expf(sc[tid][r] - m); sc[tid][r] = p; s += p; }
    mbuf[tid] = m; sbuf[tid] = s;
  }
  __syncthreads();
  size_t base = (size_t)blk * U_TOP * DH;
  for (int i = tid; i < U_TOP * DH; i += 256) {
    int u = i / DH, d = i - u * DH;
    float acc = 0.f;
#pragma unroll 8
    for (int r = 0; r < CHUNK; ++r) acc += sc[u][r] * Ks[r][d];   // V = K
    part_O[base + i] = acc;
  }
  if (tid < U_TOP) {
    part_m[blk * U_TOP + tid] = mbuf[tid];
    part_s[blk * U_TOP + tid] = sbuf[tid];
  }
}

// ---------------- merge NCHUNK partials per (b,h) ----------------
__global__ __launch_bounds__(256) void attn_combine(
    const float* __restrict__ part_O, const float* __restrict__ part_m,
    const float* __restrict__ part_s, float* __restrict__ upd) {
  int bh = blockIdx.x;
  __shared__ float w[NCHUNK][U_TOP];
  __shared__ float Sinv[U_TOP];
  int tid = threadIdx.x;
  if (tid < U_TOP) {
    float m = -INFINITY;
    for (int c = 0; c < NCHUNK; ++c)
      m = fmaxf(m, part_m[(bh * NCHUNK + c) * U_TOP + tid]);
    float s = 0.f;
    for (int c = 0; c < NCHUNK; ++c) {
      float wv = expf(part_m[(bh * NCHUNK + c) * U_TOP + tid] - m);
      w[c][tid] = wv;
      s += wv * part_s[(bh * NCHUNK + c) * U_TOP + tid];
    }
    Sinv[tid] = 1.f / s;
  }
  __syncthreads();
  for (int i = tid; i < U_TOP * DH; i += 256) {
    int u = i / DH;
    float acc = 0.f;
#pragma unroll
    for (int c = 0; c < NCHUNK; ++c)
      acc += w[c][u] * part_O[((size_t)bh * NCHUNK + c) * U_TOP * DH + i];
    upd[(size_t)bh * U_TOP * DH + i] = acc * Sinv[u];
  }
}

// ---------------- attended + residual + LN1 -> normed1 (fp32 + bf16) ----------------
__global__ __launch_bounds__(256) void fuse_ln1(
    const float* __restrict__ target, const float* __restrict__ upd,
    const int* __restrict__ sel, const float* __restrict__ vmean,
    const float* __restrict__ g, const float* __restrict__ bb,
    float* __restrict__ normed1, unsigned short* __restrict__ normed1b) {
  int r = blockIdx.x;              // r = l*BATCH + b
  int l = r >> 2, b = r & 3;
  __shared__ float x[DMODEL];
  __shared__ float red[256];
  int tid = threadIdx.x;
  for (int d = tid; d < DMODEL; d += 256) {
    int h = d / DH;
    int s = sel[((size_t)(b * NH + h)) * L_SEQ + l];
    float a = (s >= 0) ? upd[((size_t)(b * NH + h) * U_TOP + s) * DH + (d - h * DH)]
                       : vmean[b * DMODEL + d];
    x[d] = target[(size_t)r * DMODEL + d] + a;
  }
  __syncthreads();
  float partial = 0.f;
  for (int d = tid; d < DMODEL; d += 256) partial += x[d];
  red[tid] = partial; __syncthreads();
  for (int s = 128; s; s >>= 1) { if (tid < s) red[tid] += red[tid + s]; __syncthreads(); }
  float mu = red[0] * (1.f / DMODEL);
  __syncthreads();
  partial = 0.f;
  for (int d = tid; d < DMODEL; d += 256) { float t = x[d] - mu; partial += t * t; }
  red[tid] = partial; __syncthreads();
  for (int s = 128; s; s >>= 1) { if (tid < s) red[tid] += red[tid + s]; __syncthreads(); }
  float rstd = 1.0f / sqrtf(red[0] * (1.f / DMODEL) + 1e-5f);
  for (int d = tid; d < DMODEL; d += 256) {
    float v = (x[d] - mu) * rstd * g[d] + bb[d];
    normed1[(size_t)r * DMODEL + d] = v;
    normed1b[(size_t)r * DMODEL + d] = f2bf(v);
  }
}

// ---------------- fp32 -> bf16 convert (for W1, W2) ----------------
__global__ __launch_bounds__(256) void convert_bf16(const float* __restrict__ in,
                                                    unsigned short* __restrict__ outp, int n4) {
  int i = blockIdx.x * 256 + threadIdx.x;
  int stride = gridDim.x * 256;
  for (; i < n4; i += stride) {
    float4 v = ((const float4*)in)[i];
    unsigned long long pk = (unsigned long long)f2bf(v.x)
                          | ((unsigned long long)f2bf(v.y) << 16)
                          | ((unsigned long long)f2bf(v.z) << 32)
                          | ((unsigned long long)f2bf(v.w) << 48);
    ((unsigned long long*)outp)[i] = pk;
  }
}

// ---------------- bf16 MFMA GEMM (verified R6): 128x128 tile, BK=64 ----------------
template <bool RELU, bool BF16OUT>
__global__ __launch_bounds__(256) void gemm_mfma(
    const unsigned short* __restrict__ A, const unsigned short* __restrict__ B,
    const float* __restrict__ bias, void* __restrict__ Cout,
    int Ndim, int Kdim) {
  __shared__ short As[128 * 64];
  __shared__ short Bs[128 * 64];
  int tid = threadIdx.x;
  int lane = tid & 63;
  int wid = tid >> 6;
  int wm = wid >> 1, wn = wid & 1;       // 2x2 waves, each 64x64
  int bm = blockIdx.y * 128, bn = blockIdx.x * 128;

  f32x4 acc[4][4] = {};

  for (int k0 = 0; k0 < Kdim; k0 += 64) {
#pragma unroll
    for (int i = 0; i < 4; ++i) {
      int trow = wid * 32 + i * 8 + (lane >> 3);
      int slot = (lane & 7) ^ (trow & 7);          // pre-swizzled global source
      const unsigned short* ga = A + (size_t)(bm + trow) * Kdim + k0 + slot * 8;
      const unsigned short* gb = B + (size_t)(bn + trow) * Kdim + k0 + slot * 8;
      __builtin_amdgcn_global_load_lds(
          (const __attribute__((address_space(1))) void*)ga,
          (__attribute__((address_space(3))) void*)(As + (wid * 32 + i * 8) * 64),
          16, 0, 0);
      __builtin_amdgcn_global_load_lds(
          (const __attribute__((address_space(1))) void*)gb,
          (__attribute__((address_space(3))) void*)(Bs + (wid * 32 + i * 8) * 64),
          16, 0, 0);
    }
    __syncthreads();
#pragma unroll
    for (int c = 0; c < 2; ++c) {
      bf16x8 af[4], bf[4];
#pragma unroll
      for (int mi = 0; mi < 4; ++mi) {
        int row = wm * 64 + mi * 16 + (lane & 15);
        int phys = (c * 4 + (lane >> 4)) ^ (row & 7);
        af[mi] = *(const bf16x8*)(As + row * 64 + phys * 8);
      }
#pragma unroll
      for (int ni = 0; ni < 4; ++ni) {
        int row = wn * 64 + ni * 16 + (lane & 15);
        int phys = (c * 4 + (lane >> 4)) ^ (row & 7);
        bf[ni] = *(const bf16x8*)(Bs + row * 64 + phys * 8);
      }
#pragma unroll
      for (int mi = 0; mi < 4; ++mi)
#pragma unroll
        for (int ni = 0; ni < 4; ++ni)
          acc[mi][ni] = __builtin_amdgcn_mfma_f32_16x16x32_bf16(af[mi], bf[ni], acc[mi][ni], 0, 0, 0);
    }
    __syncthreads();
  }

#pragma unroll
  for (int mi = 0; mi < 4; ++mi)
#pragma unroll
    for (int ni = 0; ni < 4; ++ni) {
      int col = bn + wn * 64 + ni * 16 + (lane & 15);
      float bv = bias[col];
#pragma unroll
      for (int j = 0; j < 4; ++j) {
        int row = bm + wm * 64 + mi * 16 + (lane >> 4) * 4 + j;
        float v = acc[mi][ni][j] + bv;
        if (RELU) v = fmaxf(v, 0.f);
        if (BF16OUT)
          ((unsigned short*)Cout)[(size_t)row * Ndim + col] = f2bf(v);
        else
          ((float*)Cout)[(size_t)row * Ndim + col] = v;
      }
    }
}

// ---------------- normed1 + proj -> LN2 -> out (float4, single pass) ----------------
__global__ __launch_bounds__(192) void ln2_out(
    const float* __restrict__ normed1, const float* __restrict__ proj,
    const float* __restrict__ g, const float* __restrict__ bb,
    float* __restrict__ out) {
  int r = blockIdx.x;
  int tid = threadIdx.x;           // 192 threads x float4 = 768
  __shared__ float red[6];
  float4 a = ((const float4*)(normed1 + (size_t)r * DMODEL))[tid];
  float4 p = ((const float4*)(proj + (size_t)r * DMODEL))[tid];
  float4 x = {a.x + p.x, a.y + p.y, a.z + p.z, a.w + p.w};
  float s1 = x.x + x.y + x.z + x.w;
  float s2 = x.x * x.x + x.y * x.y + x.z * x.z + x.w * x.w;
#pragma unroll
  for (int off = 32; off; off >>= 1) {
    s1 += __shfl_xor(s1, off, 64);
    s2 += __shfl_xor(s2, off, 64);
  }
  int w = tid >> 6;
  if ((tid & 63) == 0) { red[w] = s1; red[3 + w] = s2; }
  __syncthreads();
  float S1 = red[0] + red[1] + red[2];
  float S2 = red[3] + red[4] + red[5];
  float mu = S1 * (1.f / DMODEL);
  float var = S2 * (1.f / DMODEL) - mu * mu;
  float rstd = 1.0f / sqrtf(var + 1e-5f);
  float4 gv = ((const float4*)g)[tid];
  float4 bv = ((const float4*)bb)[tid];
  float4 o = {(x.x - mu) * rstd * gv.x + bv.x, (x.y - mu) * rstd * gv.y + bv.y,
              (x.z - mu) * rstd * gv.z + bv.z, (x.w - mu) * rstd * gv.w + bv.w};
  ((float4*)(out + (size_t)r * DMODEL))[tid] = o;
}

extern "C" void kernel_launch(void* const* d_in, const int* in_sizes, int n_in,
                              void* d_out, int out_size, void* d_ws, size_t ws_size,
                              hipStream_t stream) {
  const float* target = (const float*)d_in[0];
  const float* source = (const float*)d_in[1];
  const float* W1 = (const float*)d_in[2];
  const float* b1 = (const float*)d_in[3];
  const float* W2 = (const float*)d_in[4];
  const float* b2 = (const float*)d_in[5];
  const float* ln1_g = (const float*)d_in[6];
  const float* ln1_b = (const float*)d_in[7];
  const float* ln2_g = (const float*)d_in[8];
  const float* ln2_b = (const float*)d_in[9];
  float* out = (float*)d_out;

  char* ws = (char*)d_ws;
  int*            idx      = (int*)           (ws + 0x0000000);  // 140 KB
  float*          M        = (float*)         (ws + 0x0040000);  // 128 KB
  int*            top      = (int*)           (ws + 0x0080000);  // 4.4 KB
  int*            sel      = (int*)           (ws + 0x0090000);  // 128 KB
  float*          upd      = (float*)         (ws + 0x00C0000);  // 420 KB
  float*          vmean    = (float*)         (ws + 0x0130000);  // 12 KB
  float*          part_m   = (float*)         (ws + 0x0140000);  // 72 KB
  float*          part_s   = (float*)         (ws + 0x0160000);  // 72 KB
  unsigned short* w1b      = (unsigned short*)(ws + 0x0180000);  // 3 MB
  unsigned short* w2b      = (unsigned short*)(ws + 0x0480000);  // 3 MB
  unsigned short* normed1b = (unsigned short*)(ws + 0x0780000);  // 6 MB
  float*          normed1  = (float*)         (ws + 0x0D80000);  // 12 MB
  unsigned short* h1b      = (unsigned short*)(ws + 0x1980000);  // 16 MB region
  float*          part_O   = (float*)         (ws + 0x1980000);  // 6.9 MB, aliases h1b (dead before gemm1)
  float*          vpart    = (float*)         (ws + 0x2200000);  // 786 KB, aliases h1b (dead before gemm1)
  float*          proj     = (float*)         (ws + 0x2980000);  // 12 MB -> ends 0x3580000 (56 MB)

  gen_idx<<<(IDX_CNT + 255) / 256, 256, 0, stream>>>(idx);
  sample_scores<<<BATCH * L_SEQ, 256, 0, stream>>>(target, source, idx, M);
  topk_sel<<<NBH, 256, 0, stream>>>(M, top, sel);
  vmean_part<<<BATCH * VCH, 768, 0, stream>>>(source, vpart);
  vmean_comb<<<BATCH, 768, 0, stream>>>(vpart, vmean);
  attn_flash<<<NBH * NCHUNK, 256, 0, stream>>>(target, source, top, part_O, part_m, part_s);
  attn_combine<<<NBH, 256, 0, stream>>>(part_O, part_m, part_s, upd);
  convert_bf16<<<1024, 256, 0, stream>>>(W1, w1b, DFF * DMODEL / 4);
  convert_bf16<<<1024, 256, 0, stream>>>(W2, w2b, DFF * DMODEL / 4);
  fuse_ln1<<<NROWS, 256, 0, stream>>>(target, upd, sel, vmean, ln1_g, ln1_b, normed1, normed1b);
  {
    dim3 grid(DFF / 128, NROWS / 128);   // 16 x 32
    gemm_mfma<true, true><<<grid, 256, 0, stream>>>(normed1b, w1b, b1, h1b, DFF, DMODEL);
  }
  {
    dim3 grid(DMODEL / 128, NROWS / 128);  // 6 x 32
    gemm_mfma<false, false><<<grid, 256, 0, stream>>>(h1b, w2b, b2, proj, DMODEL, DFF);
  }
  ln2_out<<<NROWS, 192, 0, stream>>>(normed1, proj, ln2_g, ln2_b, out);
}

// Round 12
// 234.575 us; speedup vs baseline: 4.2460x; 1.0186x over previous
//
#include <hip/hip_runtime.h>
#include <hip/hip_bf16.h>
#include <math.h>

#define L_SEQ 1024
#define BATCH 4
#define DMODEL 768
#define NH 8
#define DH 96
#define DFF 2048
#define U_TOP 35
#define NROWS (L_SEQ * BATCH)
#define NBH (BATCH * NH)
#define IDX_CNT (L_SEQ * U_TOP)   // 35840
#define CHUNK 64
#define NCHUNK (L_SEQ / CHUNK)    // 16
#define VCH 64                    // vmean chunks per batch
#define SCH 7                     // samples staged per chunk (5 chunks x 7 = 35)
#define KROW 808                  // Ks row stride (floats): 8 heads x 100 + 8 pad
#define QROW 101                  // Qs head stride (floats)

typedef __attribute__((ext_vector_type(8))) short bf16x8;
typedef __attribute__((ext_vector_type(4))) float f32x4;

__device__ inline unsigned short f2bf(float f) {
  unsigned u = __float_as_uint(f);
  u += 0x7FFFu + ((u >> 16) & 1u);   // RNE
  return (unsigned short)(u >> 16);
}

// ---------------- Threefry-2x32 (exact JAX reproduction) ----------------
__device__ inline unsigned rotl32(unsigned v, int d) { return (v << d) | (v >> (32 - d)); }

__device__ inline void tf2x32(unsigned k0, unsigned k1, unsigned x0, unsigned x1,
                              unsigned& o0, unsigned& o1) {
  unsigned ks0 = k0, ks1 = k1, ks2 = k0 ^ k1 ^ 0x1BD11BDAu;
  x0 += ks0; x1 += ks1;
#define TFR(r) { x0 += x1; x1 = rotl32(x1, r); x1 ^= x0; }
  TFR(13) TFR(15) TFR(26) TFR(6)
  x0 += ks1; x1 += ks2 + 1u;
  TFR(17) TFR(29) TFR(16) TFR(24)
  x0 += ks2; x1 += ks0 + 2u;
  TFR(13) TFR(15) TFR(26) TFR(6)
  x0 += ks0; x1 += ks1 + 3u;
  TFR(17) TFR(29) TFR(16) TFR(24)
  x0 += ks1; x1 += ks2 + 4u;
  TFR(13) TFR(15) TFR(26) TFR(6)
  x0 += ks2; x1 += ks0 + 5u;
#undef TFR
  o0 = x0; o1 = x1;
}

// foldlike split + partitionable bits (verified passing in R5)
__global__ void gen_idx(int* __restrict__ idx) {
  int j = blockIdx.x * 256 + threadIdx.x;
  if (j >= IDX_CNT) return;
  unsigned k2a, k2b;
  tf2x32(0u, 42u, 0u, 1u, k2a, k2b);      // k2 = split(key)[1]
  unsigned o0, o1;
  tf2x32(k2a, k2b, 0u, (unsigned)j, o0, o1);
  idx[j] = (int)((o0 ^ o1) & 1023u);
}

// ---------------- M[b,h,l]: block per (b,l), all heads; conflict-free LDS ----------------
// Ks[s][h][100] row stride 808: b128 staging writes (16B-aligned head base),
// dot-read bank = (8s+4h+24p+j)%32 -> exactly 2 lanes/bank (free).
// XCD-bijective swizzle: each XCD works one half-batch -> gather stays L2-resident.
__global__ __launch_bounds__(256) void sample_scores(
    const float* __restrict__ target, const float* __restrict__ source,
    const int* __restrict__ idx, float* __restrict__ M) {
  int orig = blockIdx.x;
  int blk = (orig & 7) * (BATCH * L_SEQ / 8) + (orig >> 3);   // bijective (4096 % 8 == 0)
  int l = blk & (L_SEQ - 1);
  int b = blk >> 10;
  __shared__ float Qs[NH * QROW];        // stride 101 (coprime to 32)
  __shared__ float Ks[SCH * KROW];
  __shared__ float qkbuf[NH][36];
  __shared__ int sidx[U_TOP];
  int tid = threadIdx.x;
  if (tid < U_TOP) sidx[tid] = idx[l * U_TOP + tid];
  if (tid < DMODEL / 4) {
    float4 v = ((const float4*)(target + ((size_t)l * BATCH + b) * DMODEL))[tid];
    int dg = tid * 4;
    int h = dg / DH;
    int off = h * QROW + (dg - h * DH);
    Qs[off] = v.x; Qs[off + 1] = v.y; Qs[off + 2] = v.z; Qs[off + 3] = v.w;
  }
  __syncthreads();
  for (int c = 0; c < U_TOP / SCH; ++c) {
    // stage 7 K rows coalesced; b128 LDS writes (aligned: head base = 400B)
    for (int i = tid; i < SCH * (DMODEL / 4); i += 256) {
      int s = i / (DMODEL / 4), t4 = i - s * (DMODEL / 4);
      int kl = sidx[c * SCH + s];
      float4 v = ((const float4*)(source + ((size_t)kl * BATCH + b) * DMODEL))[t4];
      int h = t4 / 24;                       // dg/96
      int dmod = (t4 - h * 24) * 4;
      *(float4*)&Ks[s * KROW + h * 100 + dmod] = v;
    }
    __syncthreads();
    if (tid < SCH * 32) {
      int s = tid >> 5;
      int rem = tid & 31;
      int h = rem >> 2, p = rem & 3;
      const float* kk = &Ks[s * KROW + h * 100 + p * 24];
      const float* qq = &Qs[h * QROW + p * 24];
      float a = 0.f;
#pragma unroll
      for (int j = 0; j < 24; ++j) a += qq[j] * kk[j];
      a += __shfl_xor(a, 1, 64);
      a += __shfl_xor(a, 2, 64);
      if (p == 0) qkbuf[h][c * SCH + s] = a;
    }
    __syncthreads();
  }
  int w = tid >> 6, lane = tid & 63;
#pragma unroll
  for (int hi = 0; hi < 2; ++hi) {
    int hh = w * 2 + hi;
    float v = (lane < U_TOP) ? qkbuf[hh][lane] : -INFINITY;
    float sm = (lane < U_TOP) ? v : 0.f;
    float mx = v;
#pragma unroll
    for (int off = 32; off; off >>= 1) {
      mx = fmaxf(mx, __shfl_xor(mx, off, 64));
      sm += __shfl_xor(sm, off, 64);
    }
    if (lane == 0)
      M[(size_t)(b * NH + hh) * L_SEQ + l] = mx - sm * (1.f / U_TOP);
  }
}

// ---------------- top-35 per (b,h): register-resident, shuffle-reduce ----------------
__global__ __launch_bounds__(256) void topk_sel(const float* __restrict__ M,
                                                int* __restrict__ top, int* __restrict__ sel) {
  int bh = blockIdx.x;
  int tid = threadIdx.x;
  int lane = tid & 63, w = tid >> 6;
  __shared__ float wval[4];
  __shared__ int widx[4];
  __shared__ int bidx_sh;
  float v[4]; int ir[4];
#pragma unroll
  for (int i = 0; i < 4; ++i) {
    int ii = tid + i * 256;
    v[i] = M[(size_t)bh * L_SEQ + ii];
    ir[i] = ii;
    sel[(size_t)bh * L_SEQ + ii] = -1;
  }
  for (int it = 0; it < U_TOP; ++it) {
    float bv = v[0]; int bi = ir[0];
#pragma unroll
    for (int i = 1; i < 4; ++i)
      if (v[i] > bv || (v[i] == bv && ir[i] < bi)) { bv = v[i]; bi = ir[i]; }
#pragma unroll
    for (int off = 32; off; off >>= 1) {
      float ov = __shfl_xor(bv, off, 64);
      int oi = __shfl_xor(bi, off, 64);
      if (ov > bv || (ov == bv && oi < bi)) { bv = ov; bi = oi; }
    }
    if (lane == 0) { wval[w] = bv; widx[w] = bi; }
    __syncthreads();
    if (tid == 0) {
      float fv = wval[0]; int fi = widx[0];
#pragma unroll
      for (int k = 1; k < 4; ++k)
        if (wval[k] > fv || (wval[k] == fv && widx[k] < fi)) { fv = wval[k]; fi = widx[k]; }
      top[bh * U_TOP + it] = fi;
      sel[(size_t)bh * L_SEQ + fi] = it;
      bidx_sh = fi;
    }
    __syncthreads();
    int rb = bidx_sh;
    if ((rb & 255) == tid) v[rb >> 8] = -INFINITY;
  }
}

// ---------------- V.mean: two-phase ----------------
__global__ __launch_bounds__(768) void vmean_part(const float* __restrict__ source,
                                                  float* __restrict__ part) {
  int blk = blockIdx.x;            // b*VCH + c
  int b = blk >> 6, c = blk & (VCH - 1);
  int d = threadIdx.x;
  float s = 0.f;
  int l0 = c * (L_SEQ / VCH);
#pragma unroll
  for (int l = l0; l < l0 + L_SEQ / VCH; ++l)
    s += source[((size_t)l * BATCH + b) * DMODEL + d];
  part[(size_t)blk * DMODEL + d] = s;
}

__global__ __launch_bounds__(768) void vmean_comb(const float* __restrict__ part,
                                                  float* __restrict__ vmean) {
  int b = blockIdx.x;
  int d = threadIdx.x;
  float s = 0.f;
  for (int c = 0; c < VCH; ++c) s += part[((size_t)(b * VCH + c)) * DMODEL + d];
  vmean[b * DMODEL + d] = s * (1.f / L_SEQ);
}

// ---------------- flash-style attention, split over l-chunks ----------------
__global__ __launch_bounds__(256) void attn_flash(
    const float* __restrict__ target, const float* __restrict__ source,
    const int* __restrict__ top,
    float* __restrict__ part_O,   // [NBH*NCHUNK][35][96]
    float* __restrict__ part_m,   // [NBH*NCHUNK][35]
    float* __restrict__ part_s) {
  int blk = blockIdx.x;
  int chunk = blk & (NCHUNK - 1);
  int bh = blk >> 4;
  int h = bh & (NH - 1), b = bh >> 3;
  __shared__ float Qs[U_TOP][97];
  __shared__ float Ks[CHUNK][97];
  __shared__ float sc[U_TOP][65];
  __shared__ float mbuf[U_TOP], sbuf[U_TOP];
  int tid = threadIdx.x;
  for (int i = tid; i < U_TOP * DH; i += 256) {
    int u = i / DH, d = i - u * DH;
    int qpos = top[bh * U_TOP + u];
    Qs[u][d] = target[((size_t)qpos * BATCH + b) * DMODEL + h * DH + d];
  }
  int l0 = chunk * CHUNK;
  for (int i = tid; i < CHUNK * DH; i += 256) {
    int r = i / DH, d = i - r * DH;
    Ks[r][d] = source[((size_t)(l0 + r) * BATCH + b) * DMODEL + h * DH + d];
  }
  __syncthreads();
  const float scale = 1.0f / sqrtf((float)DH);
  for (int i = tid; i < U_TOP * CHUNK; i += 256) {
    int u = i >> 6, r = i & 63;
    float s = 0.f;
#pragma unroll 8
    for (int d = 0; d < DH; ++d) s += Qs[u][d] * Ks[r][d];
    sc[u][r] = s * scale;
  }
  __syncthreads();
  if (tid < U_TOP) {
    float m = -INFINITY;
    for (int r = 0; r < CHUNK; ++r) m = fmaxf(m, sc[tid][r]);
    float s = 0.f;
    for (int r = 0; r < CHUNK; ++r) { float p = expf(sc[tid][r] - m); sc[tid][r] = p; s += p; }
    mbuf[tid] = m; sbuf[tid] = s;
  }
  __syncthreads();
  size_t base = (size_t)blk * U_TOP * DH;
  for (int i = tid; i < U_TOP * DH; i += 256) {
    int u = i / DH, d = i - u * DH;
    float acc = 0.f;
#pragma unroll 8
    for (int r = 0; r < CHUNK; ++r) acc += sc[u][r] * Ks[r][d];   // V = K
    part_O[base + i] = acc;
  }
  if (tid < U_TOP) {
    part_m[blk * U_TOP + tid] = mbuf[tid];
    part_s[blk * U_TOP + tid] = sbuf[tid];
  }
}

// ---------------- merge NCHUNK partials per (b,h) ----------------
__global__ __launch_bounds__(256) void attn_combine(
    const float* __restrict__ part_O, const float* __restrict__ part_m,
    const float* __restrict__ part_s, float* __restrict__ upd) {
  int bh = blockIdx.x;
  __shared__ float w[NCHUNK][U_TOP];
  __shared__ float Sinv[U_TOP];
  int tid = threadIdx.x;
  if (tid < U_TOP) {
    float m = -INFINITY;
    for (int c = 0; c < NCHUNK; ++c)
      m = fmaxf(m, part_m[(bh * NCHUNK + c) * U_TOP + tid]);
    float s = 0.f;
    for (int c = 0; c < NCHUNK; ++c) {
      float wv = expf(part_m[(bh * NCHUNK + c) * U_TOP + tid] - m);
      w[c][tid] = wv;
      s += wv * part_s[(bh * NCHUNK + c) * U_TOP + tid];
    }
    Sinv[tid] = 1.f / s;
  }
  __syncthreads();
  for (int i = tid; i < U_TOP * DH; i += 256) {
    int u = i / DH;
    float acc = 0.f;
#pragma unroll
    for (int c = 0; c < NCHUNK; ++c)
      acc += w[c][u] * part_O[((size_t)bh * NCHUNK + c) * U_TOP * DH + i];
    upd[(size_t)bh * U_TOP * DH + i] = acc * Sinv[u];
  }
}

// ---------------- attended + residual + LN1 -> normed1 (fp32 + bf16) ----------------
__global__ __launch_bounds__(256) void fuse_ln1(
    const float* __restrict__ target, const float* __restrict__ upd,
    const int* __restrict__ sel, const float* __restrict__ vmean,
    const float* __restrict__ g, const float* __restrict__ bb,
    float* __restrict__ normed1, unsigned short* __restrict__ normed1b) {
  int r = blockIdx.x;              // r = l*BATCH + b
  int l = r >> 2, b = r & 3;
  __shared__ float x[DMODEL];
  __shared__ float red[256];
  int tid = threadIdx.x;
  for (int d = tid; d < DMODEL; d += 256) {
    int h = d / DH;
    int s = sel[((size_t)(b * NH + h)) * L_SEQ + l];
    float a = (s >= 0) ? upd[((size_t)(b * NH + h) * U_TOP + s) * DH + (d - h * DH)]
                       : vmean[b * DMODEL + d];
    x[d] = target[(size_t)r * DMODEL + d] + a;
  }
  __syncthreads();
  float partial = 0.f;
  for (int d = tid; d < DMODEL; d += 256) partial += x[d];
  red[tid] = partial; __syncthreads();
  for (int s = 128; s; s >>= 1) { if (tid < s) red[tid] += red[tid + s]; __syncthreads(); }
  float mu = red[0] * (1.f / DMODEL);
  __syncthreads();
  partial = 0.f;
  for (int d = tid; d < DMODEL; d += 256) { float t = x[d] - mu; partial += t * t; }
  red[tid] = partial; __syncthreads();
  for (int s = 128; s; s >>= 1) { if (tid < s) red[tid] += red[tid + s]; __syncthreads(); }
  float rstd = 1.0f / sqrtf(red[0] * (1.f / DMODEL) + 1e-5f);
  for (int d = tid; d < DMODEL; d += 256) {
    float v = (x[d] - mu) * rstd * g[d] + bb[d];
    normed1[(size_t)r * DMODEL + d] = v;
    normed1b[(size_t)r * DMODEL + d] = f2bf(v);
  }
}

// ---------------- fp32 -> bf16 convert (for W1, W2) ----------------
__global__ __launch_bounds__(256) void convert_bf16(const float* __restrict__ in,
                                                    unsigned short* __restrict__ outp, int n4) {
  int i = blockIdx.x * 256 + threadIdx.x;
  int stride = gridDim.x * 256;
  for (; i < n4; i += stride) {
    float4 v = ((const float4*)in)[i];
    unsigned long long pk = (unsigned long long)f2bf(v.x)
                          | ((unsigned long long)f2bf(v.y) << 16)
                          | ((unsigned long long)f2bf(v.z) << 32)
                          | ((unsigned long long)f2bf(v.w) << 48);
    ((unsigned long long*)outp)[i] = pk;
  }
}

// ---------------- bf16 MFMA GEMM (verified R6): 128x128 tile, BK=64 ----------------
template <bool RELU, bool BF16OUT>
__global__ __launch_bounds__(256) void gemm_mfma(
    const unsigned short* __restrict__ A, const unsigned short* __restrict__ B,
    const float* __restrict__ bias, void* __restrict__ Cout,
    int Ndim, int Kdim) {
  __shared__ short As[128 * 64];
  __shared__ short Bs[128 * 64];
  int tid = threadIdx.x;
  int lane = tid & 63;
  int wid = tid >> 6;
  int wm = wid >> 1, wn = wid & 1;       // 2x2 waves, each 64x64
  int bm = blockIdx.y * 128, bn = blockIdx.x * 128;

  f32x4 acc[4][4] = {};

  for (int k0 = 0; k0 < Kdim; k0 += 64) {
#pragma unroll
    for (int i = 0; i < 4; ++i) {
      int trow = wid * 32 + i * 8 + (lane >> 3);
      int slot = (lane & 7) ^ (trow & 7);          // pre-swizzled global source
      const unsigned short* ga = A + (size_t)(bm + trow) * Kdim + k0 + slot * 8;
      const unsigned short* gb = B + (size_t)(bn + trow) * Kdim + k0 + slot * 8;
      __builtin_amdgcn_global_load_lds(
          (const __attribute__((address_space(1))) void*)ga,
          (__attribute__((address_space(3))) void*)(As + (wid * 32 + i * 8) * 64),
          16, 0, 0);
      __builtin_amdgcn_global_load_lds(
          (const __attribute__((address_space(1))) void*)gb,
          (__attribute__((address_space(3))) void*)(Bs + (wid * 32 + i * 8) * 64),
          16, 0, 0);
    }
    __syncthreads();
#pragma unroll
    for (int c = 0; c < 2; ++c) {
      bf16x8 af[4], bf[4];
#pragma unroll
      for (int mi = 0; mi < 4; ++mi) {
        int row = wm * 64 + mi * 16 + (lane & 15);
        int phys = (c * 4 + (lane >> 4)) ^ (row & 7);
        af[mi] = *(const bf16x8*)(As + row * 64 + phys * 8);
      }
#pragma unroll
      for (int ni = 0; ni < 4; ++ni) {
        int row = wn * 64 + ni * 16 + (lane & 15);
        int phys = (c * 4 + (lane >> 4)) ^ (row & 7);
        bf[ni] = *(const bf16x8*)(Bs + row * 64 + phys * 8);
      }
#pragma unroll
      for (int mi = 0; mi < 4; ++mi)
#pragma unroll
        for (int ni = 0; ni < 4; ++ni)
          acc[mi][ni] = __builtin_amdgcn_mfma_f32_16x16x32_bf16(af[mi], bf[ni], acc[mi][ni], 0, 0, 0);
    }
    __syncthreads();
  }

#pragma unroll
  for (int mi = 0; mi < 4; ++mi)
#pragma unroll
    for (int ni = 0; ni < 4; ++ni) {
      int col = bn + wn * 64 + ni * 16 + (lane & 15);
      float bv = bias[col];
#pragma unroll
      for (int j = 0; j < 4; ++j) {
        int row = bm + wm * 64 + mi * 16 + (lane >> 4) * 4 + j;
        float v = acc[mi][ni][j] + bv;
        if (RELU) v = fmaxf(v, 0.f);
        if (BF16OUT)
          ((unsigned short*)Cout)[(size_t)row * Ndim + col] = f2bf(v);
        else
          ((float*)Cout)[(size_t)row * Ndim + col] = v;
      }
    }
}

// ---------------- normed1 + proj -> LN2 -> out (float4, single pass) ----------------
__global__ __launch_bounds__(192) void ln2_out(
    const float* __restrict__ normed1, const float* __restrict__ proj,
    const float* __restrict__ g, const float* __restrict__ bb,
    float* __restrict__ out) {
  int r = blockIdx.x;
  int tid = threadIdx.x;           // 192 threads x float4 = 768
  __shared__ float red[6];
  float4 a = ((const float4*)(normed1 + (size_t)r * DMODEL))[tid];
  float4 p = ((const float4*)(proj + (size_t)r * DMODEL))[tid];
  float4 x = {a.x + p.x, a.y + p.y, a.z + p.z, a.w + p.w};
  float s1 = x.x + x.y + x.z + x.w;
  float s2 = x.x * x.x + x.y * x.y + x.z * x.z + x.w * x.w;
#pragma unroll
  for (int off = 32; off; off >>= 1) {
    s1 += __shfl_xor(s1, off, 64);
    s2 += __shfl_xor(s2, off, 64);
  }
  int w = tid >> 6;
  if ((tid & 63) == 0) { red[w] = s1; red[3 + w] = s2; }
  __syncthreads();
  float S1 = red[0] + red[1] + red[2];
  float S2 = red[3] + red[4] + red[5];
  float mu = S1 * (1.f / DMODEL);
  float var = S2 * (1.f / DMODEL) - mu * mu;
  float rstd = 1.0f / sqrtf(var + 1e-5f);
  float4 gv = ((const float4*)g)[tid];
  float4 bv = ((const float4*)bb)[tid];
  float4 o = {(x.x - mu) * rstd * gv.x + bv.x, (x.y - mu) * rstd * gv.y + bv.y,
              (x.z - mu) * rstd * gv.z + bv.z, (x.w - mu) * rstd * gv.w + bv.w};
  ((float4*)(out + (size_t)r * DMODEL))[tid] = o;
}

extern "C" void kernel_launch(void* const* d_in, const int* in_sizes, int n_in,
                              void* d_out, int out_size, void* d_ws, size_t ws_size,
                              hipStream_t stream) {
  const float* target = (const float*)d_in[0];
  const float* source = (const float*)d_in[1];
  const float* W1 = (const float*)d_in[2];
  const float* b1 = (const float*)d_in[3];
  const float* W2 = (const float*)d_in[4];
  const float* b2 = (const float*)d_in[5];
  const float* ln1_g = (const float*)d_in[6];
  const float* ln1_b = (const float*)d_in[7];
  const float* ln2_g = (const float*)d_in[8];
  const float* ln2_b = (const float*)d_in[9];
  float* out = (float*)d_out;

  char* ws = (char*)d_ws;
  int*            idx      = (int*)           (ws + 0x0000000);  // 140 KB
  float*          M        = (float*)         (ws + 0x0040000);  // 128 KB
  int*            top      = (int*)           (ws + 0x0080000);  // 4.4 KB
  int*            sel      = (int*)           (ws + 0x0090000);  // 128 KB
  float*          upd      = (float*)         (ws + 0x00C0000);  // 420 KB
  float*          vmean    = (float*)         (ws + 0x0130000);  // 12 KB
  float*          part_m   = (float*)         (ws + 0x0140000);  // 72 KB
  float*          part_s   = (float*)         (ws + 0x0160000);  // 72 KB
  unsigned short* w1b      = (unsigned short*)(ws + 0x0180000);  // 3 MB
  unsigned short* w2b      = (unsigned short*)(ws + 0x0480000);  // 3 MB
  unsigned short* normed1b = (unsigned short*)(ws + 0x0780000);  // 6 MB
  float*          normed1  = (float*)         (ws + 0x0D80000);  // 12 MB
  unsigned short* h1b      = (unsigned short*)(ws + 0x1980000);  // 16 MB region
  float*          part_O   = (float*)         (ws + 0x1980000);  // 6.9 MB, aliases h1b (dead before gemm1)
  float*          vpart    = (float*)         (ws + 0x2200000);  // 786 KB, aliases h1b (dead before gemm1)
  float*          proj     = (float*)         (ws + 0x2980000);  // 12 MB -> ends 0x3580000 (56 MB)

  gen_idx<<<(IDX_CNT + 255) / 256, 256, 0, stream>>>(idx);
  sample_scores<<<BATCH * L_SEQ, 256, 0, stream>>>(target, source, idx, M);
  topk_sel<<<NBH, 256, 0, stream>>>(M, top, sel);
  vmean_part<<<BATCH * VCH, 768, 0, stream>>>(source, vpart);
  vmean_comb<<<BATCH, 768, 0, stream>>>(vpart, vmean);
  attn_flash<<<NBH * NCHUNK, 256, 0, stream>>>(target, source, top, part_O, part_m, part_s);
  attn_combine<<<NBH, 256, 0, stream>>>(part_O, part_m, part_s, upd);
  convert_bf16<<<1024, 256, 0, stream>>>(W1, w1b, DFF * DMODEL / 4);
  convert_bf16<<<1024, 256, 0, stream>>>(W2, w2b, DFF * DMODEL / 4);
  fuse_ln1<<<NROWS, 256, 0, stream>>>(target, upd, sel, vmean, ln1_g, ln1_b, normed1, normed1b);
  {
    dim3 grid(DFF / 128, NROWS / 128);   // 16 x 32
    gemm_mfma<true, true><<<grid, 256, 0, stream>>>(normed1b, w1b, b1, h1b, DFF, DMODEL);
  }
  {
    dim3 grid(DMODEL / 128, NROWS / 128);  // 6 x 32
    gemm_mfma<false, false><<<grid, 256, 0, stream>>>(h1b, w2b, b2, proj, DMODEL, DFF);
  }
  ln2_out<<<NROWS, 192, 0, stream>>>(normed1, proj, ln2_g, ln2_b, out);
}

// Round 13
// 225.532 us; speedup vs baseline: 4.4163x; 1.0401x over previous
//
#include <hip/hip_runtime.h>
#include <hip/hip_bf16.h>
#include <math.h>

#define L_SEQ 1024
#define BATCH 4
#define DMODEL 768
#define NH 8
#define DH 96
#define DFF 2048
#define U_TOP 35
#define NROWS (L_SEQ * BATCH)
#define NBH (BATCH * NH)
#define IDX_CNT (L_SEQ * U_TOP)   // 35840
#define CHUNK 64
#define NCHUNK (L_SEQ / CHUNK)    // 16
#define VCH 64                    // vmean chunks per batch
#define SCH 7                     // samples staged per chunk (5 chunks x 7 = 35)
#define KROW 808                  // Ks row stride (floats): 8 heads x 100 + 8 pad

typedef __attribute__((ext_vector_type(8))) short bf16x8;
typedef __attribute__((ext_vector_type(4))) float f32x4;

__device__ inline unsigned short f2bf(float f) {
  unsigned u = __float_as_uint(f);
  u += 0x7FFFu + ((u >> 16) & 1u);   // RNE
  return (unsigned short)(u >> 16);
}

// ---------------- Threefry-2x32 (exact JAX reproduction) ----------------
__device__ inline unsigned rotl32(unsigned v, int d) { return (v << d) | (v >> (32 - d)); }

__device__ inline void tf2x32(unsigned k0, unsigned k1, unsigned x0, unsigned x1,
                              unsigned& o0, unsigned& o1) {
  unsigned ks0 = k0, ks1 = k1, ks2 = k0 ^ k1 ^ 0x1BD11BDAu;
  x0 += ks0; x1 += ks1;
#define TFR(r) { x0 += x1; x1 = rotl32(x1, r); x1 ^= x0; }
  TFR(13) TFR(15) TFR(26) TFR(6)
  x0 += ks1; x1 += ks2 + 1u;
  TFR(17) TFR(29) TFR(16) TFR(24)
  x0 += ks2; x1 += ks0 + 2u;
  TFR(13) TFR(15) TFR(26) TFR(6)
  x0 += ks0; x1 += ks1 + 3u;
  TFR(17) TFR(29) TFR(16) TFR(24)
  x0 += ks1; x1 += ks2 + 4u;
  TFR(13) TFR(15) TFR(26) TFR(6)
  x0 += ks2; x1 += ks0 + 5u;
#undef TFR
  o0 = x0; o1 = x1;
}

// foldlike split + partitionable bits (verified passing in R5)
__global__ void gen_idx(int* __restrict__ idx) {
  int j = blockIdx.x * 256 + threadIdx.x;
  if (j >= IDX_CNT) return;
  unsigned k2a, k2b;
  tf2x32(0u, 42u, 0u, 1u, k2a, k2b);      // k2 = split(key)[1]
  unsigned o0, o1;
  tf2x32(k2a, k2b, 0u, (unsigned)j, o0, o1);
  idx[j] = (int)((o0 ^ o1) & 1023u);
}

// ---------------- M[b,h,l]: block per (b,l); Q in registers, K via ds_read_b128 ----------------
// Thread (s=tid>>5, h=(tid>>2)&7, p=tid&3) owns a 24-float slice.
// Ks[s][h][100]: all dot-read bases 16B-aligned -> 6x ds_read_b128; start-quad
// (2s+h+6p)%8 uniform over wave -> bandwidth-minimal, no conflict overhead.
__global__ __launch_bounds__(256) void sample_scores(
    const float* __restrict__ target, const float* __restrict__ source,
    const int* __restrict__ idx, float* __restrict__ M) {
  int orig = blockIdx.x;
  int blk = (orig & 7) * (BATCH * L_SEQ / 8) + (orig >> 3);   // bijective (4096 % 8 == 0)
  int l = blk & (L_SEQ - 1);
  int b = blk >> 10;
  __shared__ float Ks[SCH * KROW];
  __shared__ float qkbuf[NH][36];
  __shared__ int sidx[U_TOP];
  int tid = threadIdx.x;
  if (tid < U_TOP) sidx[tid] = idx[l * U_TOP + tid];
  int h = (tid >> 2) & 7, p = tid & 3;
  float4 qreg[6];
  {
    const float4* qg = (const float4*)(target + ((size_t)l * BATCH + b) * DMODEL + h * DH + p * 24);
#pragma unroll
    for (int j = 0; j < 6; ++j) qreg[j] = qg[j];
  }
  __syncthreads();
  for (int c = 0; c < U_TOP / SCH; ++c) {
    // stage 7 K rows coalesced; b128 LDS writes (16B-aligned head bases)
    for (int i = tid; i < SCH * (DMODEL / 4); i += 256) {
      int s = i / (DMODEL / 4), t4 = i - s * (DMODEL / 4);
      int kl = sidx[c * SCH + s];
      float4 v = ((const float4*)(source + ((size_t)kl * BATCH + b) * DMODEL))[t4];
      int hh = t4 / 24;
      int dmod = (t4 - hh * 24) * 4;
      *(float4*)&Ks[s * KROW + hh * 100 + dmod] = v;
    }
    __syncthreads();
    int s = tid >> 5;
    if (s < SCH) {
      const float4* kk = (const float4*)&Ks[s * KROW + h * 100 + p * 24];
      float a = 0.f;
#pragma unroll
      for (int j = 0; j < 6; ++j) {
        float4 kv = kk[j];
        float4 qv = qreg[j];
        a += qv.x * kv.x + qv.y * kv.y + qv.z * kv.z + qv.w * kv.w;
      }
      a += __shfl_xor(a, 1, 64);
      a += __shfl_xor(a, 2, 64);
      if (p == 0) qkbuf[h][c * SCH + s] = a;
    }
    __syncthreads();
  }
  int w = tid >> 6, lane = tid & 63;
#pragma unroll
  for (int hi = 0; hi < 2; ++hi) {
    int hh = w * 2 + hi;
    float v = (lane < U_TOP) ? qkbuf[hh][lane] : -INFINITY;
    float sm = (lane < U_TOP) ? v : 0.f;
    float mx = v;
#pragma unroll
    for (int off = 32; off; off >>= 1) {
      mx = fmaxf(mx, __shfl_xor(mx, off, 64));
      sm += __shfl_xor(sm, off, 64);
    }
    if (lane == 0)
      M[(size_t)(b * NH + hh) * L_SEQ + l] = mx - sm * (1.f / U_TOP);
  }
}

// ---------------- top-35 per (b,h): register-resident, shuffle-reduce ----------------
__global__ __launch_bounds__(256) void topk_sel(const float* __restrict__ M,
                                                int* __restrict__ top, int* __restrict__ sel) {
  int bh = blockIdx.x;
  int tid = threadIdx.x;
  int lane = tid & 63, w = tid >> 6;
  __shared__ float wval[4];
  __shared__ int widx[4];
  __shared__ int bidx_sh;
  float v[4]; int ir[4];
#pragma unroll
  for (int i = 0; i < 4; ++i) {
    int ii = tid + i * 256;
    v[i] = M[(size_t)bh * L_SEQ + ii];
    ir[i] = ii;
    sel[(size_t)bh * L_SEQ + ii] = -1;
  }
  for (int it = 0; it < U_TOP; ++it) {
    float bv = v[0]; int bi = ir[0];
#pragma unroll
    for (int i = 1; i < 4; ++i)
      if (v[i] > bv || (v[i] == bv && ir[i] < bi)) { bv = v[i]; bi = ir[i]; }
#pragma unroll
    for (int off = 32; off; off >>= 1) {
      float ov = __shfl_xor(bv, off, 64);
      int oi = __shfl_xor(bi, off, 64);
      if (ov > bv || (ov == bv && oi < bi)) { bv = ov; bi = oi; }
    }
    if (lane == 0) { wval[w] = bv; widx[w] = bi; }
    __syncthreads();
    if (tid == 0) {
      float fv = wval[0]; int fi = widx[0];
#pragma unroll
      for (int k = 1; k < 4; ++k)
        if (wval[k] > fv || (wval[k] == fv && widx[k] < fi)) { fv = wval[k]; fi = widx[k]; }
      top[bh * U_TOP + it] = fi;
      sel[(size_t)bh * L_SEQ + fi] = it;
      bidx_sh = fi;
    }
    __syncthreads();
    int rb = bidx_sh;
    if ((rb & 255) == tid) v[rb >> 8] = -INFINITY;
  }
}

// ---------------- V.mean: two-phase ----------------
__global__ __launch_bounds__(768) void vmean_part(const float* __restrict__ source,
                                                  float* __restrict__ part) {
  int blk = blockIdx.x;            // b*VCH + c
  int b = blk >> 6, c = blk & (VCH - 1);
  int d = threadIdx.x;
  float s = 0.f;
  int l0 = c * (L_SEQ / VCH);
#pragma unroll
  for (int l = l0; l < l0 + L_SEQ / VCH; ++l)
    s += source[((size_t)l * BATCH + b) * DMODEL + d];
  part[(size_t)blk * DMODEL + d] = s;
}

__global__ __launch_bounds__(768) void vmean_comb(const float* __restrict__ part,
                                                  float* __restrict__ vmean) {
  int b = blockIdx.x;
  int d = threadIdx.x;
  float s = 0.f;
  for (int c = 0; c < VCH; ++c) s += part[((size_t)(b * VCH + c)) * DMODEL + d];
  vmean[b * DMODEL + d] = s * (1.f / L_SEQ);
}

// ---------------- flash-style attention, split over l-chunks ----------------
__global__ __launch_bounds__(256) void attn_flash(
    const float* __restrict__ target, const float* __restrict__ source,
    const int* __restrict__ top,
    float* __restrict__ part_O,   // [NBH*NCHUNK][35][96]
    float* __restrict__ part_m,   // [NBH*NCHUNK][35]
    float* __restrict__ part_s) {
  int blk = blockIdx.x;
  int chunk = blk & (NCHUNK - 1);
  int bh = blk >> 4;
  int h = bh & (NH - 1), b = bh >> 3;
  __shared__ float Qs[U_TOP][97];
  __shared__ float Ks[CHUNK][97];
  __shared__ float sc[U_TOP][65];
  __shared__ float mbuf[U_TOP], sbuf[U_TOP];
  int tid = threadIdx.x;
  for (int i = tid; i < U_TOP * DH; i += 256) {
    int u = i / DH, d = i - u * DH;
    int qpos = top[bh * U_TOP + u];
    Qs[u][d] = target[((size_t)qpos * BATCH + b) * DMODEL + h * DH + d];
  }
  int l0 = chunk * CHUNK;
  for (int i = tid; i < CHUNK * DH; i += 256) {
    int r = i / DH, d = i - r * DH;
    Ks[r][d] = source[((size_t)(l0 + r) * BATCH + b) * DMODEL + h * DH + d];
  }
  __syncthreads();
  const float scale = 1.0f / sqrtf((float)DH);
  for (int i = tid; i < U_TOP * CHUNK; i += 256) {
    int u = i >> 6, r = i & 63;
    float s = 0.f;
#pragma unroll 8
    for (int d = 0; d < DH; ++d) s += Qs[u][d] * Ks[r][d];
    sc[u][r] = s * scale;
  }
  __syncthreads();
  if (tid < U_TOP) {
    float m = -INFINITY;
    for (int r = 0; r < CHUNK; ++r) m = fmaxf(m, sc[tid][r]);
    float s = 0.f;
    for (int r = 0; r < CHUNK; ++r) { float p = expf(sc[tid][r] - m); sc[tid][r] = p; s += p; }
    mbuf[tid] = m; sbuf[tid] = s;
  }
  __syncthreads();
  size_t base = (size_t)blk * U_TOP * DH;
  for (int i = tid; i < U_TOP * DH; i += 256) {
    int u = i / DH, d = i - u * DH;
    float acc = 0.f;
#pragma unroll 8
    for (int r = 0; r < CHUNK; ++r) acc += sc[u][r] * Ks[r][d];   // V = K
    part_O[base + i] = acc;
  }
  if (tid < U_TOP) {
    part_m[blk * U_TOP + tid] = mbuf[tid];
    part_s[blk * U_TOP + tid] = sbuf[tid];
  }
}

// ---------------- merge NCHUNK partials per (b,h) ----------------
__global__ __launch_bounds__(256) void attn_combine(
    const float* __restrict__ part_O, const float* __restrict__ part_m,
    const float* __restrict__ part_s, float* __restrict__ upd) {
  int bh = blockIdx.x;
  __shared__ float w[NCHUNK][U_TOP];
  __shared__ float Sinv[U_TOP];
  int tid = threadIdx.x;
  if (tid < U_TOP) {
    float m = -INFINITY;
    for (int c = 0; c < NCHUNK; ++c)
      m = fmaxf(m, part_m[(bh * NCHUNK + c) * U_TOP + tid]);
    float s = 0.f;
    for (int c = 0; c < NCHUNK; ++c) {
      float wv = expf(part_m[(bh * NCHUNK + c) * U_TOP + tid] - m);
      w[c][tid] = wv;
      s += wv * part_s[(bh * NCHUNK + c) * U_TOP + tid];
    }
    Sinv[tid] = 1.f / s;
  }
  __syncthreads();
  for (int i = tid; i < U_TOP * DH; i += 256) {
    int u = i / DH;
    float acc = 0.f;
#pragma unroll
    for (int c = 0; c < NCHUNK; ++c)
      acc += w[c][u] * part_O[((size_t)bh * NCHUNK + c) * U_TOP * DH + i];
    upd[(size_t)bh * U_TOP * DH + i] = acc * Sinv[u];
  }
}

// ---------------- attended + residual + LN1 -> normed1 (fp32 + bf16) ----------------
__global__ __launch_bounds__(256) void fuse_ln1(
    const float* __restrict__ target, const float* __restrict__ upd,
    const int* __restrict__ sel, const float* __restrict__ vmean,
    const float* __restrict__ g, const float* __restrict__ bb,
    float* __restrict__ normed1, unsigned short* __restrict__ normed1b) {
  int r = blockIdx.x;              // r = l*BATCH + b
  int l = r >> 2, b = r & 3;
  __shared__ float x[DMODEL];
  __shared__ float red[256];
  int tid = threadIdx.x;
  for (int d = tid; d < DMODEL; d += 256) {
    int h = d / DH;
    int s = sel[((size_t)(b * NH + h)) * L_SEQ + l];
    float a = (s >= 0) ? upd[((size_t)(b * NH + h) * U_TOP + s) * DH + (d - h * DH)]
                       : vmean[b * DMODEL + d];
    x[d] = target[(size_t)r * DMODEL + d] + a;
  }
  __syncthreads();
  float partial = 0.f;
  for (int d = tid; d < DMODEL; d += 256) partial += x[d];
  red[tid] = partial; __syncthreads();
  for (int s = 128; s; s >>= 1) { if (tid < s) red[tid] += red[tid + s]; __syncthreads(); }
  float mu = red[0] * (1.f / DMODEL);
  __syncthreads();
  partial = 0.f;
  for (int d = tid; d < DMODEL; d += 256) { float t = x[d] - mu; partial += t * t; }
  red[tid] = partial; __syncthreads();
  for (int s = 128; s; s >>= 1) { if (tid < s) red[tid] += red[tid + s]; __syncthreads(); }
  float rstd = 1.0f / sqrtf(red[0] * (1.f / DMODEL) + 1e-5f);
  for (int d = tid; d < DMODEL; d += 256) {
    float v = (x[d] - mu) * rstd * g[d] + bb[d];
    normed1[(size_t)r * DMODEL + d] = v;
    normed1b[(size_t)r * DMODEL + d] = f2bf(v);
  }
}

// ---------------- fp32 -> bf16 convert (for W1, W2) ----------------
__global__ __launch_bounds__(256) void convert_bf16(const float* __restrict__ in,
                                                    unsigned short* __restrict__ outp, int n4) {
  int i = blockIdx.x * 256 + threadIdx.x;
  int stride = gridDim.x * 256;
  for (; i < n4; i += stride) {
    float4 v = ((const float4*)in)[i];
    unsigned long long pk = (unsigned long long)f2bf(v.x)
                          | ((unsigned long long)f2bf(v.y) << 16)
                          | ((unsigned long long)f2bf(v.z) << 32)
                          | ((unsigned long long)f2bf(v.w) << 48);
    ((unsigned long long*)outp)[i] = pk;
  }
}

// ---------------- bf16 MFMA GEMM (verified R6): 128x128 tile, BK=64 ----------------
template <bool RELU, bool BF16OUT>
__global__ __launch_bounds__(256) void gemm_mfma(
    const unsigned short* __restrict__ A, const unsigned short* __restrict__ B,
    const float* __restrict__ bias, void* __restrict__ Cout,
    int Ndim, int Kdim) {
  __shared__ short As[128 * 64];
  __shared__ short Bs[128 * 64];
  int tid = threadIdx.x;
  int lane = tid & 63;
  int wid = tid >> 6;
  int wm = wid >> 1, wn = wid & 1;       // 2x2 waves, each 64x64
  int bm = blockIdx.y * 128, bn = blockIdx.x * 128;

  f32x4 acc[4][4] = {};

  for (int k0 = 0; k0 < Kdim; k0 += 64) {
#pragma unroll
    for (int i = 0; i < 4; ++i) {
      int trow = wid * 32 + i * 8 + (lane >> 3);
      int slot = (lane & 7) ^ (trow & 7);          // pre-swizzled global source
      const unsigned short* ga = A + (size_t)(bm + trow) * Kdim + k0 + slot * 8;
      const unsigned short* gb = B + (size_t)(bn + trow) * Kdim + k0 + slot * 8;
      __builtin_amdgcn_global_load_lds(
          (const __attribute__((address_space(1))) void*)ga,
          (__attribute__((address_space(3))) void*)(As + (wid * 32 + i * 8) * 64),
          16, 0, 0);
      __builtin_amdgcn_global_load_lds(
          (const __attribute__((address_space(1))) void*)gb,
          (__attribute__((address_space(3))) void*)(Bs + (wid * 32 + i * 8) * 64),
          16, 0, 0);
    }
    __syncthreads();
#pragma unroll
    for (int c = 0; c < 2; ++c) {
      bf16x8 af[4], bf[4];
#pragma unroll
      for (int mi = 0; mi < 4; ++mi) {
        int row = wm * 64 + mi * 16 + (lane & 15);
        int phys = (c * 4 + (lane >> 4)) ^ (row & 7);
        af[mi] = *(const bf16x8*)(As + row * 64 + phys * 8);
      }
#pragma unroll
      for (int ni = 0; ni < 4; ++ni) {
        int row = wn * 64 + ni * 16 + (lane & 15);
        int phys = (c * 4 + (lane >> 4)) ^ (row & 7);
        bf[ni] = *(const bf16x8*)(Bs + row * 64 + phys * 8);
      }
#pragma unroll
      for (int mi = 0; mi < 4; ++mi)
#pragma unroll
        for (int ni = 0; ni < 4; ++ni)
          acc[mi][ni] = __builtin_amdgcn_mfma_f32_16x16x32_bf16(af[mi], bf[ni], acc[mi][ni], 0, 0, 0);
    }
    __syncthreads();
  }

#pragma unroll
  for (int mi = 0; mi < 4; ++mi)
#pragma unroll
    for (int ni = 0; ni < 4; ++ni) {
      int col = bn + wn * 64 + ni * 16 + (lane & 15);
      float bv = bias[col];
#pragma unroll
      for (int j = 0; j < 4; ++j) {
        int row = bm + wm * 64 + mi * 16 + (lane >> 4) * 4 + j;
        float v = acc[mi][ni][j] + bv;
        if (RELU) v = fmaxf(v, 0.f);
        if (BF16OUT)
          ((unsigned short*)Cout)[(size_t)row * Ndim + col] = f2bf(v);
        else
          ((float*)Cout)[(size_t)row * Ndim + col] = v;
      }
    }
}

// ---------------- normed1 + proj -> LN2 -> out (float4, single pass) ----------------
__global__ __launch_bounds__(192) void ln2_out(
    const float* __restrict__ normed1, const float* __restrict__ proj,
    const float* __restrict__ g, const float* __restrict__ bb,
    float* __restrict__ out) {
  int r = blockIdx.x;
  int tid = threadIdx.x;           // 192 threads x float4 = 768
  __shared__ float red[6];
  float4 a = ((const float4*)(normed1 + (size_t)r * DMODEL))[tid];
  float4 p = ((const float4*)(proj + (size_t)r * DMODEL))[tid];
  float4 x = {a.x + p.x, a.y + p.y, a.z + p.z, a.w + p.w};
  float s1 = x.x + x.y + x.z + x.w;
  float s2 = x.x * x.x + x.y * x.y + x.z * x.z + x.w * x.w;
#pragma unroll
  for (int off = 32; off; off >>= 1) {
    s1 += __shfl_xor(s1, off, 64);
    s2 += __shfl_xor(s2, off, 64);
  }
  int w = tid >> 6;
  if ((tid & 63) == 0) { red[w] = s1; red[3 + w] = s2; }
  __syncthreads();
  float S1 = red[0] + red[1] + red[2];
  float S2 = red[3] + red[4] + red[5];
  float mu = S1 * (1.f / DMODEL);
  float var = S2 * (1.f / DMODEL) - mu * mu;
  float rstd = 1.0f / sqrtf(var + 1e-5f);
  float4 gv = ((const float4*)g)[tid];
  float4 bv = ((const float4*)bb)[tid];
  float4 o = {(x.x - mu) * rstd * gv.x + bv.x, (x.y - mu) * rstd * gv.y + bv.y,
              (x.z - mu) * rstd * gv.z + bv.z, (x.w - mu) * rstd * gv.w + bv.w};
  ((float4*)(out + (size_t)r * DMODEL))[tid] = o;
}

extern "C" void kernel_launch(void* const* d_in, const int* in_sizes, int n_in,
                              void* d_out, int out_size, void* d_ws, size_t ws_size,
                              hipStream_t stream) {
  const float* target = (const float*)d_in[0];
  const float* source = (const float*)d_in[1];
  const float* W1 = (const float*)d_in[2];
  const float* b1 = (const float*)d_in[3];
  const float* W2 = (const float*)d_in[4];
  const float* b2 = (const float*)d_in[5];
  const float* ln1_g = (const float*)d_in[6];
  const float* ln1_b = (const float*)d_in[7];
  const float* ln2_g = (const float*)d_in[8];
  const float* ln2_b = (const float*)d_in[9];
  float* out = (float*)d_out;

  char* ws = (char*)d_ws;
  int*            idx      = (int*)           (ws + 0x0000000);  // 140 KB
  float*          M        = (float*)         (ws + 0x0040000);  // 128 KB
  int*            top      = (int*)           (ws + 0x0080000);  // 4.4 KB
  int*            sel      = (int*)           (ws + 0x0090000);  // 128 KB
  float*          upd      = (float*)         (ws + 0x00C0000);  // 420 KB
  float*          vmean    = (float*)         (ws + 0x0130000);  // 12 KB
  float*          part_m   = (float*)         (ws + 0x0140000);  // 72 KB
  float*          part_s   = (float*)         (ws + 0x0160000);  // 72 KB
  unsigned short* w1b      = (unsigned short*)(ws + 0x0180000);  // 3 MB
  unsigned short* w2b      = (unsigned short*)(ws + 0x0480000);  // 3 MB
  unsigned short* normed1b = (unsigned short*)(ws + 0x0780000);  // 6 MB
  float*          normed1  = (float*)         (ws + 0x0D80000);  // 12 MB
  unsigned short* h1b      = (unsigned short*)(ws + 0x1980000);  // 16 MB region
  float*          part_O   = (float*)         (ws + 0x1980000);  // 6.9 MB, aliases h1b (dead before gemm1)
  float*          vpart    = (float*)         (ws + 0x2200000);  // 786 KB, aliases h1b (dead before gemm1)
  float*          proj     = (float*)         (ws + 0x2980000);  // 12 MB -> ends 0x3580000 (56 MB)

  gen_idx<<<(IDX_CNT + 255) / 256, 256, 0, stream>>>(idx);
  sample_scores<<<BATCH * L_SEQ, 256, 0, stream>>>(target, source, idx, M);
  topk_sel<<<NBH, 256, 0, stream>>>(M, top, sel);
  vmean_part<<<BATCH * VCH, 768, 0, stream>>>(source, vpart);
  vmean_comb<<<BATCH, 768, 0, stream>>>(vpart, vmean);
  attn_flash<<<NBH * NCHUNK, 256, 0, stream>>>(target, source, top, part_O, part_m, part_s);
  attn_combine<<<NBH, 256, 0, stream>>>(part_O, part_m, part_s, upd);
  convert_bf16<<<1024, 256, 0, stream>>>(W1, w1b, DFF * DMODEL / 4);
  convert_bf16<<<1024, 256, 0, stream>>>(W2, w2b, DFF * DMODEL / 4);
  fuse_ln1<<<NROWS, 256, 0, stream>>>(target, upd, sel, vmean, ln1_g, ln1_b, normed1, normed1b);
  {
    dim3 grid(DFF / 128, NROWS / 128);   // 16 x 32
    gemm_mfma<true, true><<<grid, 256, 0, stream>>>(normed1b, w1b, b1, h1b, DFF, DMODEL);
  }
  {
    dim3 grid(DMODEL / 128, NROWS / 128);  // 6 x 32
    gemm_mfma<false, false><<<grid, 256, 0, stream>>>(h1b, w2b, b2, proj, DMODEL, DFF);
  }
  ln2_out<<<NROWS, 192, 0, stream>>>(normed1, proj, ln2_g, ln2_b, out);
}

// Round 14
// 212.607 us; speedup vs baseline: 4.6847x; 1.0608x over previous
//
#include <hip/hip_runtime.h>
#include <hip/hip_bf16.h>
#include <math.h>

#define L_SEQ 1024
#define BATCH 4
#define DMODEL 768
#define NH 8
#define DH 96
#define DFF 2048
#define U_TOP 35
#define NROWS (L_SEQ * BATCH)
#define NBH (BATCH * NH)
#define IDX_CNT (L_SEQ * U_TOP)   // 35840
#define CHUNK 64
#define NCHUNK (L_SEQ / CHUNK)    // 16
#define VCH 64                    // vmean chunks per batch

typedef __attribute__((ext_vector_type(8))) short bf16x8;
typedef __attribute__((ext_vector_type(4))) float f32x4;

__device__ inline unsigned short f2bf(float f) {
  unsigned u = __float_as_uint(f);
  u += 0x7FFFu + ((u >> 16) & 1u);   // RNE
  return (unsigned short)(u >> 16);
}

// ---------------- Threefry-2x32 (exact JAX reproduction) ----------------
__device__ inline unsigned rotl32(unsigned v, int d) { return (v << d) | (v >> (32 - d)); }

__device__ inline void tf2x32(unsigned k0, unsigned k1, unsigned x0, unsigned x1,
                              unsigned& o0, unsigned& o1) {
  unsigned ks0 = k0, ks1 = k1, ks2 = k0 ^ k1 ^ 0x1BD11BDAu;
  x0 += ks0; x1 += ks1;
#define TFR(r) { x0 += x1; x1 = rotl32(x1, r); x1 ^= x0; }
  TFR(13) TFR(15) TFR(26) TFR(6)
  x0 += ks1; x1 += ks2 + 1u;
  TFR(17) TFR(29) TFR(16) TFR(24)
  x0 += ks2; x1 += ks0 + 2u;
  TFR(13) TFR(15) TFR(26) TFR(6)
  x0 += ks0; x1 += ks1 + 3u;
  TFR(17) TFR(29) TFR(16) TFR(24)
  x0 += ks1; x1 += ks2 + 4u;
  TFR(13) TFR(15) TFR(26) TFR(6)
  x0 += ks2; x1 += ks0 + 5u;
#undef TFR
  o0 = x0; o1 = x1;
}

// foldlike split + partitionable bits (verified passing in R5)
__global__ void gen_idx(int* __restrict__ idx) {
  int j = blockIdx.x * 256 + threadIdx.x;
  if (j >= IDX_CNT) return;
  unsigned k2a, k2b;
  tf2x32(0u, 42u, 0u, 1u, k2a, k2b);      // k2 = split(key)[1]
  unsigned o0, o1;
  tf2x32(k2a, k2b, 0u, (unsigned)j, o0, o1);
  idx[j] = (int)((o0 ^ o1) & 1023u);
}

// ---------------- M[b,h,l]: register-direct L2 gather, no LDS staging ----------------
// Thread (s8=tid>>5, h=(tid>>2)&7, p=tid&3): 5 independent c-iters, each
// 6x float4 direct loads (L2-resident via XCD swizzle) + 24 FMA + 2 shfl.
// Wave = 2 K-rows, lanes sweep contiguous 16B chunks -> coalesced.
__global__ __launch_bounds__(256) void sample_scores(
    const float* __restrict__ target, const float* __restrict__ source,
    const int* __restrict__ idx, float* __restrict__ M) {
  int orig = blockIdx.x;
  int blk = (orig & 7) * (BATCH * L_SEQ / 8) + (orig >> 3);   // bijective (4096 % 8 == 0)
  int l = blk & (L_SEQ - 1);
  int b = blk >> 10;
  __shared__ float qkbuf[NH][40];
  __shared__ int sidx[40];
  int tid = threadIdx.x;
  if (tid < 40) sidx[tid] = (tid < U_TOP) ? idx[l * U_TOP + tid] : 0;
  int h = (tid >> 2) & 7, p = tid & 3;
  int s8 = tid >> 5;
  float4 qreg[6];
  {
    const float4* qg = (const float4*)(target + ((size_t)l * BATCH + b) * DMODEL + h * DH + p * 24);
#pragma unroll
    for (int j = 0; j < 6; ++j) qreg[j] = qg[j];
  }
  __syncthreads();
#pragma unroll
  for (int c = 0; c < 5; ++c) {
    int s = c * 8 + s8;
    if (s < U_TOP) {
      int kl = sidx[s];
      const float4* kg = (const float4*)(source + ((size_t)kl * BATCH + b) * DMODEL + h * DH + p * 24);
      float a = 0.f;
#pragma unroll
      for (int j = 0; j < 6; ++j) {
        float4 kv = kg[j];
        float4 qv = qreg[j];
        a += qv.x * kv.x + qv.y * kv.y + qv.z * kv.z + qv.w * kv.w;
      }
      a += __shfl_xor(a, 1, 64);
      a += __shfl_xor(a, 2, 64);
      if (p == 0) qkbuf[h][s] = a;
    }
  }
  __syncthreads();
  int w = tid >> 6, lane = tid & 63;
#pragma unroll
  for (int hi = 0; hi < 2; ++hi) {
    int hh = w * 2 + hi;
    float v = (lane < U_TOP) ? qkbuf[hh][lane] : -INFINITY;
    float sm = (lane < U_TOP) ? v : 0.f;
    float mx = v;
#pragma unroll
    for (int off = 32; off; off >>= 1) {
      mx = fmaxf(mx, __shfl_xor(mx, off, 64));
      sm += __shfl_xor(sm, off, 64);
    }
    if (lane == 0)
      M[(size_t)(b * NH + hh) * L_SEQ + l] = mx - sm * (1.f / U_TOP);
  }
}

// ---------------- top-35 per (b,h): register-resident, shuffle-reduce ----------------
__global__ __launch_bounds__(256) void topk_sel(const float* __restrict__ M,
                                                int* __restrict__ top, int* __restrict__ sel) {
  int bh = blockIdx.x;
  int tid = threadIdx.x;
  int lane = tid & 63, w = tid >> 6;
  __shared__ float wval[4];
  __shared__ int widx[4];
  __shared__ int bidx_sh;
  float v[4]; int ir[4];
#pragma unroll
  for (int i = 0; i < 4; ++i) {
    int ii = tid + i * 256;
    v[i] = M[(size_t)bh * L_SEQ + ii];
    ir[i] = ii;
    sel[(size_t)bh * L_SEQ + ii] = -1;
  }
  for (int it = 0; it < U_TOP; ++it) {
    float bv = v[0]; int bi = ir[0];
#pragma unroll
    for (int i = 1; i < 4; ++i)
      if (v[i] > bv || (v[i] == bv && ir[i] < bi)) { bv = v[i]; bi = ir[i]; }
#pragma unroll
    for (int off = 32; off; off >>= 1) {
      float ov = __shfl_xor(bv, off, 64);
      int oi = __shfl_xor(bi, off, 64);
      if (ov > bv || (ov == bv && oi < bi)) { bv = ov; bi = oi; }
    }
    if (lane == 0) { wval[w] = bv; widx[w] = bi; }
    __syncthreads();
    if (tid == 0) {
      float fv = wval[0]; int fi = widx[0];
#pragma unroll
      for (int k = 1; k < 4; ++k)
        if (wval[k] > fv || (wval[k] == fv && widx[k] < fi)) { fv = wval[k]; fi = widx[k]; }
      top[bh * U_TOP + it] = fi;
      sel[(size_t)bh * L_SEQ + fi] = it;
      bidx_sh = fi;
    }
    __syncthreads();
    int rb = bidx_sh;
    if ((rb & 255) == tid) v[rb >> 8] = -INFINITY;
  }
}

// ---------------- V.mean: two-phase ----------------
__global__ __launch_bounds__(768) void vmean_part(const float* __restrict__ source,
                                                  float* __restrict__ part) {
  int blk = blockIdx.x;            // b*VCH + c
  int b = blk >> 6, c = blk & (VCH - 1);
  int d = threadIdx.x;
  float s = 0.f;
  int l0 = c * (L_SEQ / VCH);
#pragma unroll
  for (int l = l0; l < l0 + L_SEQ / VCH; ++l)
    s += source[((size_t)l * BATCH + b) * DMODEL + d];
  part[(size_t)blk * DMODEL + d] = s;
}

__global__ __launch_bounds__(768) void vmean_comb(const float* __restrict__ part,
                                                  float* __restrict__ vmean) {
  int b = blockIdx.x;
  int d = threadIdx.x;
  float s = 0.f;
  for (int c = 0; c < VCH; ++c) s += part[((size_t)(b * VCH + c)) * DMODEL + d];
  vmean[b * DMODEL + d] = s * (1.f / L_SEQ);
}

// ---------------- flash-style attention, split over l-chunks ----------------
__global__ __launch_bounds__(256) void attn_flash(
    const float* __restrict__ target, const float* __restrict__ source,
    const int* __restrict__ top,
    float* __restrict__ part_O,   // [NBH*NCHUNK][35][96]
    float* __restrict__ part_m,   // [NBH*NCHUNK][35]
    float* __restrict__ part_s) {
  int blk = blockIdx.x;
  int chunk = blk & (NCHUNK - 1);
  int bh = blk >> 4;
  int h = bh & (NH - 1), b = bh >> 3;
  __shared__ float Qs[U_TOP][97];
  __shared__ float Ks[CHUNK][97];
  __shared__ float sc[U_TOP][65];
  __shared__ float mbuf[U_TOP], sbuf[U_TOP];
  int tid = threadIdx.x;
  for (int i = tid; i < U_TOP * DH; i += 256) {
    int u = i / DH, d = i - u * DH;
    int qpos = top[bh * U_TOP + u];
    Qs[u][d] = target[((size_t)qpos * BATCH + b) * DMODEL + h * DH + d];
  }
  int l0 = chunk * CHUNK;
  for (int i = tid; i < CHUNK * DH; i += 256) {
    int r = i / DH, d = i - r * DH;
    Ks[r][d] = source[((size_t)(l0 + r) * BATCH + b) * DMODEL + h * DH + d];
  }
  __syncthreads();
  const float scale = 1.0f / sqrtf((float)DH);
  for (int i = tid; i < U_TOP * CHUNK; i += 256) {
    int u = i >> 6, r = i & 63;
    float s = 0.f;
#pragma unroll 8
    for (int d = 0; d < DH; ++d) s += Qs[u][d] * Ks[r][d];
    sc[u][r] = s * scale;
  }
  __syncthreads();
  if (tid < U_TOP) {
    float m = -INFINITY;
    for (int r = 0; r < CHUNK; ++r) m = fmaxf(m, sc[tid][r]);
    float s = 0.f;
    for (int r = 0; r < CHUNK; ++r) { float p = expf(sc[tid][r] - m); sc[tid][r] = p; s += p; }
    mbuf[tid] = m; sbuf[tid] = s;
  }
  __syncthreads();
  size_t base = (size_t)blk * U_TOP * DH;
  for (int i = tid; i < U_TOP * DH; i += 256) {
    int u = i / DH, d = i - u * DH;
    float acc = 0.f;
#pragma unroll 8
    for (int r = 0; r < CHUNK; ++r) acc += sc[u][r] * Ks[r][d];   // V = K
    part_O[base + i] = acc;
  }
  if (tid < U_TOP) {
    part_m[blk * U_TOP + tid] = mbuf[tid];
    part_s[blk * U_TOP + tid] = sbuf[tid];
  }
}

// ---------------- merge NCHUNK partials per (b,h) ----------------
__global__ __launch_bounds__(256) void attn_combine(
    const float* __restrict__ part_O, const float* __restrict__ part_m,
    const float* __restrict__ part_s, float* __restrict__ upd) {
  int bh = blockIdx.x;
  __shared__ float w[NCHUNK][U_TOP];
  __shared__ float Sinv[U_TOP];
  int tid = threadIdx.x;
  if (tid < U_TOP) {
    float m = -INFINITY;
    for (int c = 0; c < NCHUNK; ++c)
      m = fmaxf(m, part_m[(bh * NCHUNK + c) * U_TOP + tid]);
    float s = 0.f;
    for (int c = 0; c < NCHUNK; ++c) {
      float wv = expf(part_m[(bh * NCHUNK + c) * U_TOP + tid] - m);
      w[c][tid] = wv;
      s += wv * part_s[(bh * NCHUNK + c) * U_TOP + tid];
    }
    Sinv[tid] = 1.f / s;
  }
  __syncthreads();
  for (int i = tid; i < U_TOP * DH; i += 256) {
    int u = i / DH;
    float acc = 0.f;
#pragma unroll
    for (int c = 0; c < NCHUNK; ++c)
      acc += w[c][u] * part_O[((size_t)bh * NCHUNK + c) * U_TOP * DH + i];
    upd[(size_t)bh * U_TOP * DH + i] = acc * Sinv[u];
  }
}

// ---------------- attended + residual + LN1 -> normed1 (fp32 + bf16) ----------------
__global__ __launch_bounds__(256) void fuse_ln1(
    const float* __restrict__ target, const float* __restrict__ upd,
    const int* __restrict__ sel, const float* __restrict__ vmean,
    const float* __restrict__ g, const float* __restrict__ bb,
    float* __restrict__ normed1, unsigned short* __restrict__ normed1b) {
  int r = blockIdx.x;              // r = l*BATCH + b
  int l = r >> 2, b = r & 3;
  __shared__ float x[DMODEL];
  __shared__ float red[256];
  int tid = threadIdx.x;
  for (int d = tid; d < DMODEL; d += 256) {
    int h = d / DH;
    int s = sel[((size_t)(b * NH + h)) * L_SEQ + l];
    float a = (s >= 0) ? upd[((size_t)(b * NH + h) * U_TOP + s) * DH + (d - h * DH)]
                       : vmean[b * DMODEL + d];
    x[d] = target[(size_t)r * DMODEL + d] + a;
  }
  __syncthreads();
  float partial = 0.f;
  for (int d = tid; d < DMODEL; d += 256) partial += x[d];
  red[tid] = partial; __syncthreads();
  for (int s = 128; s; s >>= 1) { if (tid < s) red[tid] += red[tid + s]; __syncthreads(); }
  float mu = red[0] * (1.f / DMODEL);
  __syncthreads();
  partial = 0.f;
  for (int d = tid; d < DMODEL; d += 256) { float t = x[d] - mu; partial += t * t; }
  red[tid] = partial; __syncthreads();
  for (int s = 128; s; s >>= 1) { if (tid < s) red[tid] += red[tid + s]; __syncthreads(); }
  float rstd = 1.0f / sqrtf(red[0] * (1.f / DMODEL) + 1e-5f);
  for (int d = tid; d < DMODEL; d += 256) {
    float v = (x[d] - mu) * rstd * g[d] + bb[d];
    normed1[(size_t)r * DMODEL + d] = v;
    normed1b[(size_t)r * DMODEL + d] = f2bf(v);
  }
}

// ---------------- fp32 -> bf16 convert (for W1, W2) ----------------
__global__ __launch_bounds__(256) void convert_bf16(const float* __restrict__ in,
                                                    unsigned short* __restrict__ outp, int n4) {
  int i = blockIdx.x * 256 + threadIdx.x;
  int stride = gridDim.x * 256;
  for (; i < n4; i += stride) {
    float4 v = ((const float4*)in)[i];
    unsigned long long pk = (unsigned long long)f2bf(v.x)
                          | ((unsigned long long)f2bf(v.y) << 16)
                          | ((unsigned long long)f2bf(v.z) << 32)
                          | ((unsigned long long)f2bf(v.w) << 48);
    ((unsigned long long*)outp)[i] = pk;
  }
}

// ---------------- bf16 MFMA GEMM (verified R6): 128x128 tile, BK=64 ----------------
template <bool RELU, bool BF16OUT>
__global__ __launch_bounds__(256) void gemm_mfma(
    const unsigned short* __restrict__ A, const unsigned short* __restrict__ B,
    const float* __restrict__ bias, void* __restrict__ Cout,
    int Ndim, int Kdim) {
  __shared__ short As[128 * 64];
  __shared__ short Bs[128 * 64];
  int tid = threadIdx.x;
  int lane = tid & 63;
  int wid = tid >> 6;
  int wm = wid >> 1, wn = wid & 1;       // 2x2 waves, each 64x64
  int bm = blockIdx.y * 128, bn = blockIdx.x * 128;

  f32x4 acc[4][4] = {};

  for (int k0 = 0; k0 < Kdim; k0 += 64) {
#pragma unroll
    for (int i = 0; i < 4; ++i) {
      int trow = wid * 32 + i * 8 + (lane >> 3);
      int slot = (lane & 7) ^ (trow & 7);          // pre-swizzled global source
      const unsigned short* ga = A + (size_t)(bm + trow) * Kdim + k0 + slot * 8;
      const unsigned short* gb = B + (size_t)(bn + trow) * Kdim + k0 + slot * 8;
      __builtin_amdgcn_global_load_lds(
          (const __attribute__((address_space(1))) void*)ga,
          (__attribute__((address_space(3))) void*)(As + (wid * 32 + i * 8) * 64),
          16, 0, 0);
      __builtin_amdgcn_global_load_lds(
          (const __attribute__((address_space(1))) void*)gb,
          (__attribute__((address_space(3))) void*)(Bs + (wid * 32 + i * 8) * 64),
          16, 0, 0);
    }
    __syncthreads();
#pragma unroll
    for (int c = 0; c < 2; ++c) {
      bf16x8 af[4], bf[4];
#pragma unroll
      for (int mi = 0; mi < 4; ++mi) {
        int row = wm * 64 + mi * 16 + (lane & 15);
        int phys = (c * 4 + (lane >> 4)) ^ (row & 7);
        af[mi] = *(const bf16x8*)(As + row * 64 + phys * 8);
      }
#pragma unroll
      for (int ni = 0; ni < 4; ++ni) {
        int row = wn * 64 + ni * 16 + (lane & 15);
        int phys = (c * 4 + (lane >> 4)) ^ (row & 7);
        bf[ni] = *(const bf16x8*)(Bs + row * 64 + phys * 8);
      }
#pragma unroll
      for (int mi = 0; mi < 4; ++mi)
#pragma unroll
        for (int ni = 0; ni < 4; ++ni)
          acc[mi][ni] = __builtin_amdgcn_mfma_f32_16x16x32_bf16(af[mi], bf[ni], acc[mi][ni], 0, 0, 0);
    }
    __syncthreads();
  }

#pragma unroll
  for (int mi = 0; mi < 4; ++mi)
#pragma unroll
    for (int ni = 0; ni < 4; ++ni) {
      int col = bn + wn * 64 + ni * 16 + (lane & 15);
      float bv = bias[col];
#pragma unroll
      for (int j = 0; j < 4; ++j) {
        int row = bm + wm * 64 + mi * 16 + (lane >> 4) * 4 + j;
        float v = acc[mi][ni][j] + bv;
        if (RELU) v = fmaxf(v, 0.f);
        if (BF16OUT)
          ((unsigned short*)Cout)[(size_t)row * Ndim + col] = f2bf(v);
        else
          ((float*)Cout)[(size_t)row * Ndim + col] = v;
      }
    }
}

// ---------------- normed1 + proj -> LN2 -> out (float4, single pass) ----------------
__global__ __launch_bounds__(192) void ln2_out(
    const float* __restrict__ normed1, const float* __restrict__ proj,
    const float* __restrict__ g, const float* __restrict__ bb,
    float* __restrict__ out) {
  int r = blockIdx.x;
  int tid = threadIdx.x;           // 192 threads x float4 = 768
  __shared__ float red[6];
  float4 a = ((const float4*)(normed1 + (size_t)r * DMODEL))[tid];
  float4 p = ((const float4*)(proj + (size_t)r * DMODEL))[tid];
  float4 x = {a.x + p.x, a.y + p.y, a.z + p.z, a.w + p.w};
  float s1 = x.x + x.y + x.z + x.w;
  float s2 = x.x * x.x + x.y * x.y + x.z * x.z + x.w * x.w;
#pragma unroll
  for (int off = 32; off; off >>= 1) {
    s1 += __shfl_xor(s1, off, 64);
    s2 += __shfl_xor(s2, off, 64);
  }
  int w = tid >> 6;
  if ((tid & 63) == 0) { red[w] = s1; red[3 + w] = s2; }
  __syncthreads();
  float S1 = red[0] + red[1] + red[2];
  float S2 = red[3] + red[4] + red[5];
  float mu = S1 * (1.f / DMODEL);
  float var = S2 * (1.f / DMODEL) - mu * mu;
  float rstd = 1.0f / sqrtf(var + 1e-5f);
  float4 gv = ((const float4*)g)[tid];
  float4 bv = ((const float4*)bb)[tid];
  float4 o = {(x.x - mu) * rstd * gv.x + bv.x, (x.y - mu) * rstd * gv.y + bv.y,
              (x.z - mu) * rstd * gv.z + bv.z, (x.w - mu) * rstd * gv.w + bv.w};
  ((float4*)(out + (size_t)r * DMODEL))[tid] = o;
}

extern "C" void kernel_launch(void* const* d_in, const int* in_sizes, int n_in,
                              void* d_out, int out_size, void* d_ws, size_t ws_size,
                              hipStream_t stream) {
  const float* target = (const float*)d_in[0];
  const float* source = (const float*)d_in[1];
  const float* W1 = (const float*)d_in[2];
  const float* b1 = (const float*)d_in[3];
  const float* W2 = (const float*)d_in[4];
  const float* b2 = (const float*)d_in[5];
  const float* ln1_g = (const float*)d_in[6];
  const float* ln1_b = (const float*)d_in[7];
  const float* ln2_g = (const float*)d_in[8];
  const float* ln2_b = (const float*)d_in[9];
  float* out = (float*)d_out;

  char* ws = (char*)d_ws;
  int*            idx      = (int*)           (ws + 0x0000000);  // 140 KB
  float*          M        = (float*)         (ws + 0x0040000);  // 128 KB
  int*            top      = (int*)           (ws + 0x0080000);  // 4.4 KB
  int*            sel      = (int*)           (ws + 0x0090000);  // 128 KB
  float*          upd      = (float*)         (ws + 0x00C0000);  // 420 KB
  float*          vmean    = (float*)         (ws + 0x0130000);  // 12 KB
  float*          part_m   = (float*)         (ws + 0x0140000);  // 72 KB
  float*          part_s   = (float*)         (ws + 0x0160000);  // 72 KB
  unsigned short* w1b      = (unsigned short*)(ws + 0x0180000);  // 3 MB
  unsigned short* w2b      = (unsigned short*)(ws + 0x0480000);  // 3 MB
  unsigned short* normed1b = (unsigned short*)(ws + 0x0780000);  // 6 MB
  float*          normed1  = (float*)         (ws + 0x0D80000);  // 12 MB
  unsigned short* h1b      = (unsigned short*)(ws + 0x1980000);  // 16 MB region
  float*          part_O   = (float*)         (ws + 0x1980000);  // 6.9 MB, aliases h1b (dead before gemm1)
  float*          vpart    = (float*)         (ws + 0x2200000);  // 786 KB, aliases h1b (dead before gemm1)
  float*          proj     = (float*)         (ws + 0x2980000);  // 12 MB -> ends 0x3580000 (56 MB)

  gen_idx<<<(IDX_CNT + 255) / 256, 256, 0, stream>>>(idx);
  sample_scores<<<BATCH * L_SEQ, 256, 0, stream>>>(target, source, idx, M);
  topk_sel<<<NBH, 256, 0, stream>>>(M, top, sel);
  vmean_part<<<BATCH * VCH, 768, 0, stream>>>(source, vpart);
  vmean_comb<<<BATCH, 768, 0, stream>>>(vpart, vmean);
  attn_flash<<<NBH * NCHUNK, 256, 0, stream>>>(target, source, top, part_O, part_m, part_s);
  attn_combine<<<NBH, 256, 0, stream>>>(part_O, part_m, part_s, upd);
  convert_bf16<<<1024, 256, 0, stream>>>(W1, w1b, DFF * DMODEL / 4);
  convert_bf16<<<1024, 256, 0, stream>>>(W2, w2b, DFF * DMODEL / 4);
  fuse_ln1<<<NROWS, 256, 0, stream>>>(target, upd, sel, vmean, ln1_g, ln1_b, normed1, normed1b);
  {
    dim3 grid(DFF / 128, NROWS / 128);   // 16 x 32
    gemm_mfma<true, true><<<grid, 256, 0, stream>>>(normed1b, w1b, b1, h1b, DFF, DMODEL);
  }
  {
    dim3 grid(DMODEL / 128, NROWS / 128);  // 6 x 32
    gemm_mfma<false, false><<<grid, 256, 0, stream>>>(h1b, w2b, b2, proj, DMODEL, DFF);
  }
  ln2_out<<<NROWS, 192, 0, stream>>>(normed1, proj, ln2_g, ln2_b, out);
}

// Round 15
// 187.963 us; speedup vs baseline: 5.2990x; 1.1311x over previous
//
#include <hip/hip_runtime.h>
#include <hip/hip_bf16.h>
#include <math.h>

#define L_SEQ 1024
#define BATCH 4
#define DMODEL 768
#define NH 8
#define DH 96
#define DFF 2048
#define U_TOP 35
#define NROWS (L_SEQ * BATCH)
#define NBH (BATCH * NH)
#define IDX_CNT (L_SEQ * U_TOP)   // 35840
#define CHUNK 64
#define NCHUNK (L_SEQ / CHUNK)    // 16
#define VCH 64                    // vmean chunks per batch

typedef __attribute__((ext_vector_type(8))) short bf16x8;
typedef __attribute__((ext_vector_type(4))) float f32x4;

__device__ inline unsigned short f2bf(float f) {
  unsigned u = __float_as_uint(f);
  u += 0x7FFFu + ((u >> 16) & 1u);   // RNE
  return (unsigned short)(u >> 16);
}

// ---------------- Threefry-2x32 (exact JAX reproduction) ----------------
__device__ inline unsigned rotl32(unsigned v, int d) { return (v << d) | (v >> (32 - d)); }

__device__ inline void tf2x32(unsigned k0, unsigned k1, unsigned x0, unsigned x1,
                              unsigned& o0, unsigned& o1) {
  unsigned ks0 = k0, ks1 = k1, ks2 = k0 ^ k1 ^ 0x1BD11BDAu;
  x0 += ks0; x1 += ks1;
#define TFR(r) { x0 += x1; x1 = rotl32(x1, r); x1 ^= x0; }
  TFR(13) TFR(15) TFR(26) TFR(6)
  x0 += ks1; x1 += ks2 + 1u;
  TFR(17) TFR(29) TFR(16) TFR(24)
  x0 += ks2; x1 += ks0 + 2u;
  TFR(13) TFR(15) TFR(26) TFR(6)
  x0 += ks0; x1 += ks1 + 3u;
  TFR(17) TFR(29) TFR(16) TFR(24)
  x0 += ks1; x1 += ks2 + 4u;
  TFR(13) TFR(15) TFR(26) TFR(6)
  x0 += ks2; x1 += ks0 + 5u;
#undef TFR
  o0 = x0; o1 = x1;
}

// foldlike split + partitionable bits (verified passing in R5)
__global__ void gen_idx(int* __restrict__ idx) {
  int j = blockIdx.x * 256 + threadIdx.x;
  if (j >= IDX_CNT) return;
  unsigned k2a, k2b;
  tf2x32(0u, 42u, 0u, 1u, k2a, k2b);      // k2 = split(key)[1]
  unsigned o0, o1;
  tf2x32(k2a, k2b, 0u, (unsigned)j, o0, o1);
  idx[j] = (int)((o0 ^ o1) & 1023u);
}

// ---------------- M[b,h,l]: register-direct L2 gather (verified R14) ----------------
__global__ __launch_bounds__(256) void sample_scores(
    const float* __restrict__ target, const float* __restrict__ source,
    const int* __restrict__ idx, float* __restrict__ M) {
  int orig = blockIdx.x;
  int blk = (orig & 7) * (BATCH * L_SEQ / 8) + (orig >> 3);   // bijective (4096 % 8 == 0)
  int l = blk & (L_SEQ - 1);
  int b = blk >> 10;
  __shared__ float qkbuf[NH][40];
  __shared__ int sidx[40];
  int tid = threadIdx.x;
  if (tid < 40) sidx[tid] = (tid < U_TOP) ? idx[l * U_TOP + tid] : 0;
  int h = (tid >> 2) & 7, p = tid & 3;
  int s8 = tid >> 5;
  float4 qreg[6];
  {
    const float4* qg = (const float4*)(target + ((size_t)l * BATCH + b) * DMODEL + h * DH + p * 24);
#pragma unroll
    for (int j = 0; j < 6; ++j) qreg[j] = qg[j];
  }
  __syncthreads();
#pragma unroll
  for (int c = 0; c < 5; ++c) {
    int s = c * 8 + s8;
    if (s < U_TOP) {
      int kl = sidx[s];
      const float4* kg = (const float4*)(source + ((size_t)kl * BATCH + b) * DMODEL + h * DH + p * 24);
      float a = 0.f;
#pragma unroll
      for (int j = 0; j < 6; ++j) {
        float4 kv = kg[j];
        float4 qv = qreg[j];
        a += qv.x * kv.x + qv.y * kv.y + qv.z * kv.z + qv.w * kv.w;
      }
      a += __shfl_xor(a, 1, 64);
      a += __shfl_xor(a, 2, 64);
      if (p == 0) qkbuf[h][s] = a;
    }
  }
  __syncthreads();
  int w = tid >> 6, lane = tid & 63;
#pragma unroll
  for (int hi = 0; hi < 2; ++hi) {
    int hh = w * 2 + hi;
    float v = (lane < U_TOP) ? qkbuf[hh][lane] : -INFINITY;
    float sm = (lane < U_TOP) ? v : 0.f;
    float mx = v;
#pragma unroll
    for (int off = 32; off; off >>= 1) {
      mx = fmaxf(mx, __shfl_xor(mx, off, 64));
      sm += __shfl_xor(sm, off, 64);
    }
    if (lane == 0)
      M[(size_t)(b * NH + hh) * L_SEQ + l] = mx - sm * (1.f / U_TOP);
  }
}

// ---------------- top-35 per (b,h): register-resident, shuffle-reduce ----------------
__global__ __launch_bounds__(256) void topk_sel(const float* __restrict__ M,
                                                int* __restrict__ top, int* __restrict__ sel) {
  int bh = blockIdx.x;
  int tid = threadIdx.x;
  int lane = tid & 63, w = tid >> 6;
  __shared__ float wval[4];
  __shared__ int widx[4];
  __shared__ int bidx_sh;
  float v[4]; int ir[4];
#pragma unroll
  for (int i = 0; i < 4; ++i) {
    int ii = tid + i * 256;
    v[i] = M[(size_t)bh * L_SEQ + ii];
    ir[i] = ii;
    sel[(size_t)bh * L_SEQ + ii] = -1;
  }
  for (int it = 0; it < U_TOP; ++it) {
    float bv = v[0]; int bi = ir[0];
#pragma unroll
    for (int i = 1; i < 4; ++i)
      if (v[i] > bv || (v[i] == bv && ir[i] < bi)) { bv = v[i]; bi = ir[i]; }
#pragma unroll
    for (int off = 32; off; off >>= 1) {
      float ov = __shfl_xor(bv, off, 64);
      int oi = __shfl_xor(bi, off, 64);
      if (ov > bv || (ov == bv && oi < bi)) { bv = ov; bi = oi; }
    }
    if (lane == 0) { wval[w] = bv; widx[w] = bi; }
    __syncthreads();
    if (tid == 0) {
      float fv = wval[0]; int fi = widx[0];
#pragma unroll
      for (int k = 1; k < 4; ++k)
        if (wval[k] > fv || (wval[k] == fv && widx[k] < fi)) { fv = wval[k]; fi = widx[k]; }
      top[bh * U_TOP + it] = fi;
      sel[(size_t)bh * L_SEQ + fi] = it;
      bidx_sh = fi;
    }
    __syncthreads();
    int rb = bidx_sh;
    if ((rb & 255) == tid) v[rb >> 8] = -INFINITY;
  }
}

// ---------------- V.mean: two-phase ----------------
__global__ __launch_bounds__(768) void vmean_part(const float* __restrict__ source,
                                                  float* __restrict__ part) {
  int blk = blockIdx.x;            // b*VCH + c
  int b = blk >> 6, c = blk & (VCH - 1);
  int d = threadIdx.x;
  float s = 0.f;
  int l0 = c * (L_SEQ / VCH);
#pragma unroll
  for (int l = l0; l < l0 + L_SEQ / VCH; ++l)
    s += source[((size_t)l * BATCH + b) * DMODEL + d];
  part[(size_t)blk * DMODEL + d] = s;
}

__global__ __launch_bounds__(768) void vmean_comb(const float* __restrict__ part,
                                                  float* __restrict__ vmean) {
  int b = blockIdx.x;
  int d = threadIdx.x;
  float s = 0.f;
  for (int c = 0; c < VCH; ++c) s += part[((size_t)(b * VCH + c)) * DMODEL + d];
  vmean[b * DMODEL + d] = s * (1.f / L_SEQ);
}

// ---------------- flash attention chunk via MFMA ----------------
// S(48x64) = Q*K^T (bf16 MFMA, K-dim 96), wave-parallel softmax,
// O = P*V via pre-transposed Vt(96x64). P reuses the dead Q buffer.
// Strides: Qb/Kb 104 bf16 (13x16B), Vt 72 (9x16B) -> aligned b128 frags, <=2-way banks.
__global__ __launch_bounds__(256) void attn_flash(
    const float* __restrict__ target, const float* __restrict__ source,
    const int* __restrict__ top,
    float* __restrict__ part_O,   // [NBH*NCHUNK][35][96]
    float* __restrict__ part_m,   // [NBH*NCHUNK][35]
    float* __restrict__ part_s) {
  int blk = blockIdx.x;
  int chunk = blk & (NCHUNK - 1);
  int bh = blk >> 4;
  int h = bh & (NH - 1), b = bh >> 3;
  __shared__ short Qb[48 * 104];     // Q (scaled), later P
  __shared__ short Kb[CHUNK * 104];
  __shared__ short Vt[96 * 72];
  __shared__ float sc[48 * 66];
  int tid = threadIdx.x;
  const float scale = 0.1020620726f;   // 1/sqrt(96)
  // zero pad rows 35..47 of Qb (S rows defined; P pad rows = 0)
  for (int i = tid; i < 13 * 104; i += 256) Qb[35 * 104 + i] = 0;
  // stage Q (35 x 96) scaled -> bf16
  for (int i = tid; i < U_TOP * 24; i += 256) {
    int u = i / 24, d4 = i - u * 24;
    int qpos = top[bh * U_TOP + u];
    float4 v = *(const float4*)(target + ((size_t)qpos * BATCH + b) * DMODEL + h * DH + d4 * 4);
    short* dst = Qb + u * 104 + d4 * 4;
    dst[0] = f2bf(v.x * scale); dst[1] = f2bf(v.y * scale);
    dst[2] = f2bf(v.z * scale); dst[3] = f2bf(v.w * scale);
  }
  // stage K (64 x 96) -> bf16
  int l0 = chunk * CHUNK;
  for (int i = tid; i < CHUNK * 24; i += 256) {
    int r = i / 24, d4 = i - r * 24;
    float4 v = *(const float4*)(source + ((size_t)(l0 + r) * BATCH + b) * DMODEL + h * DH + d4 * 4);
    short* dst = Kb + r * 104 + d4 * 4;
    dst[0] = f2bf(v.x); dst[1] = f2bf(v.y); dst[2] = f2bf(v.z); dst[3] = f2bf(v.w);
  }
  __syncthreads();
  // build Vt[d][r] from Kb (LDS->LDS transpose)
  for (int i = tid; i < CHUNK * 24; i += 256) {
    int r = i & (CHUNK - 1), d4 = i >> 6;
    const short* srcp = Kb + r * 104 + d4 * 4;
#pragma unroll
    for (int cc = 0; cc < 4; ++cc) Vt[(d4 * 4 + cc) * 72 + r] = srcp[cc];
  }
  int wv = tid >> 6, lane = tid & 63;
  int lr = lane & 15, lg = lane >> 4;
  __syncthreads();
  // QK^T: wave wv owns n-tile wv; S = Q*K^T (both [row][k], mfma -> X*Y^T)
  {
    int n = wv;
#pragma unroll
    for (int m = 0; m < 3; ++m) {
      f32x4 acc = {};
#pragma unroll
      for (int kc = 0; kc < 3; ++kc) {
        bf16x8 a = *(const bf16x8*)(Qb + (m * 16 + lr) * 104 + kc * 32 + lg * 8);
        bf16x8 bb = *(const bf16x8*)(Kb + (n * 16 + lr) * 104 + kc * 32 + lg * 8);
        acc = __builtin_amdgcn_mfma_f32_16x16x32_bf16(a, bb, acc, 0, 0, 0);
      }
#pragma unroll
      for (int j = 0; j < 4; ++j)
        sc[(m * 16 + lg * 4 + j) * 66 + n * 16 + lr] = acc[j];
    }
  }
  __syncthreads();
  // wave-parallel softmax: u = wv + 4i, lane = r; P (bf16) into Qb
#pragma unroll
  for (int i = 0; i < 9; ++i) {
    int u = wv + 4 * i;
    if (u < U_TOP) {
      float s = sc[u * 66 + lane];
      float mx = s;
#pragma unroll
      for (int off = 32; off; off >>= 1) mx = fmaxf(mx, __shfl_xor(mx, off, 64));
      float pp = expf(s - mx);
      float sm = pp;
#pragma unroll
      for (int off = 32; off; off >>= 1) sm += __shfl_xor(sm, off, 64);
      Qb[u * 104 + lane] = f2bf(pp);
      if (lane == 0) {
        part_m[blk * U_TOP + u] = mx;
        part_s[blk * U_TOP + u] = sm;
      }
    }
  }
  __syncthreads();
  // PV: O(48x96) = P(48x64) * Vt^T ; 18 C-tiles over 4 waves
  for (int t = wv; t < 18; t += 4) {
    int m = t / 6, n = t - (t / 6) * 6;
    f32x4 acc = {};
#pragma unroll
    for (int kc = 0; kc < 2; ++kc) {
      bf16x8 a = *(const bf16x8*)(Qb + (m * 16 + lr) * 104 + kc * 32 + lg * 8);
      bf16x8 bb = *(const bf16x8*)(Vt + (n * 16 + lr) * 72 + kc * 32 + lg * 8);
      acc = __builtin_amdgcn_mfma_f32_16x16x32_bf16(a, bb, acc, 0, 0, 0);
    }
#pragma unroll
    for (int j = 0; j < 4; ++j) {
      int u = m * 16 + lg * 4 + j;
      if (u < U_TOP)
        part_O[(size_t)blk * U_TOP * DH + u * DH + n * 16 + lr] = acc[j];
    }
  }
}

// ---------------- merge NCHUNK partials per (b,h) ----------------
__global__ __launch_bounds__(256) void attn_combine(
    const float* __restrict__ part_O, const float* __restrict__ part_m,
    const float* __restrict__ part_s, float* __restrict__ upd) {
  int bh = blockIdx.x;
  __shared__ float w[NCHUNK][U_TOP];
  __shared__ float Sinv[U_TOP];
  int tid = threadIdx.x;
  if (tid < U_TOP) {
    float m = -INFINITY;
    for (int c = 0; c < NCHUNK; ++c)
      m = fmaxf(m, part_m[(bh * NCHUNK + c) * U_TOP + tid]);
    float s = 0.f;
    for (int c = 0; c < NCHUNK; ++c) {
      float wv = expf(part_m[(bh * NCHUNK + c) * U_TOP + tid] - m);
      w[c][tid] = wv;
      s += wv * part_s[(bh * NCHUNK + c) * U_TOP + tid];
    }
    Sinv[tid] = 1.f / s;
  }
  __syncthreads();
  for (int i = tid; i < U_TOP * DH; i += 256) {
    int u = i / DH;
    float acc = 0.f;
#pragma unroll
    for (int c = 0; c < NCHUNK; ++c)
      acc += w[c][u] * part_O[((size_t)bh * NCHUNK + c) * U_TOP * DH + i];
    upd[(size_t)bh * U_TOP * DH + i] = acc * Sinv[u];
  }
}

// ---------------- attended + residual + LN1 -> normed1 (fp32 + bf16) ----------------
__global__ __launch_bounds__(256) void fuse_ln1(
    const float* __restrict__ target, const float* __restrict__ upd,
    const int* __restrict__ sel, const float* __restrict__ vmean,
    const float* __restrict__ g, const float* __restrict__ bb,
    float* __restrict__ normed1, unsigned short* __restrict__ normed1b) {
  int r = blockIdx.x;              // r = l*BATCH + b
  int l = r >> 2, b = r & 3;
  __shared__ float x[DMODEL];
  __shared__ float red[256];
  int tid = threadIdx.x;
  for (int d = tid; d < DMODEL; d += 256) {
    int h = d / DH;
    int s = sel[((size_t)(b * NH + h)) * L_SEQ + l];
    float a = (s >= 0) ? upd[((size_t)(b * NH + h) * U_TOP + s) * DH + (d - h * DH)]
                       : vmean[b * DMODEL + d];
    x[d] = target[(size_t)r * DMODEL + d] + a;
  }
  __syncthreads();
  float partial = 0.f;
  for (int d = tid; d < DMODEL; d += 256) partial += x[d];
  red[tid] = partial; __syncthreads();
  for (int s = 128; s; s >>= 1) { if (tid < s) red[tid] += red[tid + s]; __syncthreads(); }
  float mu = red[0] * (1.f / DMODEL);
  __syncthreads();
  partial = 0.f;
  for (int d = tid; d < DMODEL; d += 256) { float t = x[d] - mu; partial += t * t; }
  red[tid] = partial; __syncthreads();
  for (int s = 128; s; s >>= 1) { if (tid < s) red[tid] += red[tid + s]; __syncthreads(); }
  float rstd = 1.0f / sqrtf(red[0] * (1.f / DMODEL) + 1e-5f);
  for (int d = tid; d < DMODEL; d += 256) {
    float v = (x[d] - mu) * rstd * g[d] + bb[d];
    normed1[(size_t)r * DMODEL + d] = v;
    normed1b[(size_t)r * DMODEL + d] = f2bf(v);
  }
}

// ---------------- fp32 -> bf16 convert (for W1, W2) ----------------
__global__ __launch_bounds__(256) void convert_bf16(const float* __restrict__ in,
                                                    unsigned short* __restrict__ outp, int n4) {
  int i = blockIdx.x * 256 + threadIdx.x;
  int stride = gridDim.x * 256;
  for (; i < n4; i += stride) {
    float4 v = ((const float4*)in)[i];
    unsigned long long pk = (unsigned long long)f2bf(v.x)
                          | ((unsigned long long)f2bf(v.y) << 16)
                          | ((unsigned long long)f2bf(v.z) << 32)
                          | ((unsigned long long)f2bf(v.w) << 48);
    ((unsigned long long*)outp)[i] = pk;
  }
}

// ---------------- bf16 MFMA GEMM (verified R6): 128x128 tile, BK=64 ----------------
template <bool RELU, bool BF16OUT>
__global__ __launch_bounds__(256) void gemm_mfma(
    const unsigned short* __restrict__ A, const unsigned short* __restrict__ B,
    const float* __restrict__ bias, void* __restrict__ Cout,
    int Ndim, int Kdim) {
  __shared__ short As[128 * 64];
  __shared__ short Bs[128 * 64];
  int tid = threadIdx.x;
  int lane = tid & 63;
  int wid = tid >> 6;
  int wm = wid >> 1, wn = wid & 1;       // 2x2 waves, each 64x64
  int bm = blockIdx.y * 128, bn = blockIdx.x * 128;

  f32x4 acc[4][4] = {};

  for (int k0 = 0; k0 < Kdim; k0 += 64) {
#pragma unroll
    for (int i = 0; i < 4; ++i) {
      int trow = wid * 32 + i * 8 + (lane >> 3);
      int slot = (lane & 7) ^ (trow & 7);          // pre-swizzled global source
      const unsigned short* ga = A + (size_t)(bm + trow) * Kdim + k0 + slot * 8;
      const unsigned short* gb = B + (size_t)(bn + trow) * Kdim + k0 + slot * 8;
      __builtin_amdgcn_global_load_lds(
          (const __attribute__((address_space(1))) void*)ga,
          (__attribute__((address_space(3))) void*)(As + (wid * 32 + i * 8) * 64),
          16, 0, 0);
      __builtin_amdgcn_global_load_lds(
          (const __attribute__((address_space(1))) void*)gb,
          (__attribute__((address_space(3))) void*)(Bs + (wid * 32 + i * 8) * 64),
          16, 0, 0);
    }
    __syncthreads();
#pragma unroll
    for (int c = 0; c < 2; ++c) {
      bf16x8 af[4], bf[4];
#pragma unroll
      for (int mi = 0; mi < 4; ++mi) {
        int row = wm * 64 + mi * 16 + (lane & 15);
        int phys = (c * 4 + (lane >> 4)) ^ (row & 7);
        af[mi] = *(const bf16x8*)(As + row * 64 + phys * 8);
      }
#pragma unroll
      for (int ni = 0; ni < 4; ++ni) {
        int row = wn * 64 + ni * 16 + (lane & 15);
        int phys = (c * 4 + (lane >> 4)) ^ (row & 7);
        bf[ni] = *(const bf16x8*)(Bs + row * 64 + phys * 8);
      }
#pragma unroll
      for (int mi = 0; mi < 4; ++mi)
#pragma unroll
        for (int ni = 0; ni < 4; ++ni)
          acc[mi][ni] = __builtin_amdgcn_mfma_f32_16x16x32_bf16(af[mi], bf[ni], acc[mi][ni], 0, 0, 0);
    }
    __syncthreads();
  }

#pragma unroll
  for (int mi = 0; mi < 4; ++mi)
#pragma unroll
    for (int ni = 0; ni < 4; ++ni) {
      int col = bn + wn * 64 + ni * 16 + (lane & 15);
      float bv = bias[col];
#pragma unroll
      for (int j = 0; j < 4; ++j) {
        int row = bm + wm * 64 + mi * 16 + (lane >> 4) * 4 + j;
        float v = acc[mi][ni][j] + bv;
        if (RELU) v = fmaxf(v, 0.f);
        if (BF16OUT)
          ((unsigned short*)Cout)[(size_t)row * Ndim + col] = f2bf(v);
        else
          ((float*)Cout)[(size_t)row * Ndim + col] = v;
      }
    }
}

// ---------------- normed1 + proj -> LN2 -> out (float4, single pass) ----------------
__global__ __launch_bounds__(192) void ln2_out(
    const float* __restrict__ normed1, const float* __restrict__ proj,
    const float* __restrict__ g, const float* __restrict__ bb,
    float* __restrict__ out) {
  int r = blockIdx.x;
  int tid = threadIdx.x;           // 192 threads x float4 = 768
  __shared__ float red[6];
  float4 a = ((const float4*)(normed1 + (size_t)r * DMODEL))[tid];
  float4 p = ((const float4*)(proj + (size_t)r * DMODEL))[tid];
  float4 x = {a.x + p.x, a.y + p.y, a.z + p.z, a.w + p.w};
  float s1 = x.x + x.y + x.z + x.w;
  float s2 = x.x * x.x + x.y * x.y + x.z * x.z + x.w * x.w;
#pragma unroll
  for (int off = 32; off; off >>= 1) {
    s1 += __shfl_xor(s1, off, 64);
    s2 += __shfl_xor(s2, off, 64);
  }
  int w = tid >> 6;
  if ((tid & 63) == 0) { red[w] = s1; red[3 + w] = s2; }
  __syncthreads();
  float S1 = red[0] + red[1] + red[2];
  float S2 = red[3] + red[4] + red[5];
  float mu = S1 * (1.f / DMODEL);
  float var = S2 * (1.f / DMODEL) - mu * mu;
  float rstd = 1.0f / sqrtf(var + 1e-5f);
  float4 gv = ((const float4*)g)[tid];
  float4 bv = ((const float4*)bb)[tid];
  float4 o = {(x.x - mu) * rstd * gv.x + bv.x, (x.y - mu) * rstd * gv.y + bv.y,
              (x.z - mu) * rstd * gv.z + bv.z, (x.w - mu) * rstd * gv.w + bv.w};
  ((float4*)(out + (size_t)r * DMODEL))[tid] = o;
}

extern "C" void kernel_launch(void* const* d_in, const int* in_sizes, int n_in,
                              void* d_out, int out_size, void* d_ws, size_t ws_size,
                              hipStream_t stream) {
  const float* target = (const float*)d_in[0];
  const float* source = (const float*)d_in[1];
  const float* W1 = (const float*)d_in[2];
  const float* b1 = (const float*)d_in[3];
  const float* W2 = (const float*)d_in[4];
  const float* b2 = (const float*)d_in[5];
  const float* ln1_g = (const float*)d_in[6];
  const float* ln1_b = (const float*)d_in[7];
  const float* ln2_g = (const float*)d_in[8];
  const float* ln2_b = (const float*)d_in[9];
  float* out = (float*)d_out;

  char* ws = (char*)d_ws;
  int*            idx      = (int*)           (ws + 0x0000000);  // 140 KB
  float*          M        = (float*)         (ws + 0x0040000);  // 128 KB
  int*            top      = (int*)           (ws + 0x0080000);  // 4.4 KB
  int*            sel      = (int*)           (ws + 0x0090000);  // 128 KB
  float*          upd      = (float*)         (ws + 0x00C0000);  // 420 KB
  float*          vmean    = (float*)         (ws + 0x0130000);  // 12 KB
  float*          part_m   = (float*)         (ws + 0x0140000);  // 72 KB
  float*          part_s   = (float*)         (ws + 0x0160000);  // 72 KB
  unsigned short* w1b      = (unsigned short*)(ws + 0x0180000);  // 3 MB
  unsigned short* w2b      = (unsigned short*)(ws + 0x0480000);  // 3 MB
  unsigned short* normed1b = (unsigned short*)(ws + 0x0780000);  // 6 MB
  float*          normed1  = (float*)         (ws + 0x0D80000);  // 12 MB
  unsigned short* h1b      = (unsigned short*)(ws + 0x1980000);  // 16 MB region
  float*          part_O   = (float*)         (ws + 0x1980000);  // 6.9 MB, aliases h1b (dead before gemm1)
  float*          vpart    = (float*)         (ws + 0x2200000);  // 786 KB, aliases h1b (dead before gemm1)
  float*          proj     = (float*)         (ws + 0x2980000);  // 12 MB -> ends 0x3580000 (56 MB)

  gen_idx<<<(IDX_CNT + 255) / 256, 256, 0, stream>>>(idx);
  sample_scores<<<BATCH * L_SEQ, 256, 0, stream>>>(target, source, idx, M);
  topk_sel<<<NBH, 256, 0, stream>>>(M, top, sel);
  vmean_part<<<BATCH * VCH, 768, 0, stream>>>(source, vpart);
  vmean_comb<<<BATCH, 768, 0, stream>>>(vpart, vmean);
  attn_flash<<<NBH * NCHUNK, 256, 0, stream>>>(target, source, top, part_O, part_m, part_s);
  attn_combine<<<NBH, 256, 0, stream>>>(part_O, part_m, part_s, upd);
  convert_bf16<<<1024, 256, 0, stream>>>(W1, w1b, DFF * DMODEL / 4);
  convert_bf16<<<1024, 256, 0, stream>>>(W2, w2b, DFF * DMODEL / 4);
  fuse_ln1<<<NROWS, 256, 0, stream>>>(target, upd, sel, vmean, ln1_g, ln1_b, normed1, normed1b);
  {
    dim3 grid(DFF / 128, NROWS / 128);   // 16 x 32
    gemm_mfma<true, true><<<grid, 256, 0, stream>>>(normed1b, w1b, b1, h1b, DFF, DMODEL);
  }
  {
    dim3 grid(DMODEL / 128, NROWS / 128);  // 6 x 32
    gemm_mfma<false, false><<<grid, 256, 0, stream>>>(h1b, w2b, b2, proj, DMODEL, DFF);
  }
  ln2_out<<<NROWS, 192, 0, stream>>>(normed1, proj, ln2_g, ln2_b, out);
}

// Round 17
// 175.210 us; speedup vs baseline: 5.6847x; 1.0728x over previous
//
#include <hip/hip_runtime.h>
#include <hip/hip_bf16.h>
#include <math.h>

#define L_SEQ 1024
#define BATCH 4
#define DMODEL 768
#define NH 8
#define DH 96
#define DFF 2048
#define U_TOP 35
#define NROWS (L_SEQ * BATCH)
#define NBH (BATCH * NH)
#define IDX_CNT (L_SEQ * U_TOP)   // 35840
#define CHUNK 64
#define NCHUNK (L_SEQ / CHUNK)    // 16
#define VCH 64                    // vmean chunks per batch

typedef __attribute__((ext_vector_type(8))) short bf16x8;
typedef __attribute__((ext_vector_type(4))) float f32x4;

__device__ inline unsigned short f2bf(float f) {
  unsigned u = __float_as_uint(f);
  u += 0x7FFFu + ((u >> 16) & 1u);   // RNE
  return (unsigned short)(u >> 16);
}

// ---------------- Threefry-2x32 (exact JAX reproduction) ----------------
__device__ inline unsigned rotl32(unsigned v, int d) { return (v << d) | (v >> (32 - d)); }

__device__ inline void tf2x32(unsigned k0, unsigned k1, unsigned x0, unsigned x1,
                              unsigned& o0, unsigned& o1) {
  unsigned ks0 = k0, ks1 = k1, ks2 = k0 ^ k1 ^ 0x1BD11BDAu;
  x0 += ks0; x1 += ks1;
#define TFR(r) { x0 += x1; x1 = rotl32(x1, r); x1 ^= x0; }
  TFR(13) TFR(15) TFR(26) TFR(6)
  x0 += ks1; x1 += ks2 + 1u;
  TFR(17) TFR(29) TFR(16) TFR(24)
  x0 += ks2; x1 += ks0 + 2u;
  TFR(13) TFR(15) TFR(26) TFR(6)
  x0 += ks0; x1 += ks1 + 3u;
  TFR(17) TFR(29) TFR(16) TFR(24)
  x0 += ks1; x1 += ks2 + 4u;
  TFR(13) TFR(15) TFR(26) TFR(6)
  x0 += ks2; x1 += ks0 + 5u;
#undef TFR
  o0 = x0; o1 = x1;
}

// foldlike split + partitionable bits (verified passing in R5)
__global__ void gen_idx(int* __restrict__ idx) {
  int j = blockIdx.x * 256 + threadIdx.x;
  if (j >= IDX_CNT) return;
  unsigned k2a, k2b;
  tf2x32(0u, 42u, 0u, 1u, k2a, k2b);      // k2 = split(key)[1]
  unsigned o0, o1;
  tf2x32(k2a, k2b, 0u, (unsigned)j, o0, o1);
  idx[j] = (int)((o0 ^ o1) & 1023u);
}

// ---------------- M[b,h,l]: register-direct L2 gather (verified R14) ----------------
__global__ __launch_bounds__(256) void sample_scores(
    const float* __restrict__ target, const float* __restrict__ source,
    const int* __restrict__ idx, float* __restrict__ M) {
  int orig = blockIdx.x;
  int blk = (orig & 7) * (BATCH * L_SEQ / 8) + (orig >> 3);   // bijective (4096 % 8 == 0)
  int l = blk & (L_SEQ - 1);
  int b = blk >> 10;
  __shared__ float qkbuf[NH][40];
  __shared__ int sidx[40];
  int tid = threadIdx.x;
  if (tid < 40) sidx[tid] = (tid < U_TOP) ? idx[l * U_TOP + tid] : 0;
  int h = (tid >> 2) & 7, p = tid & 3;
  int s8 = tid >> 5;
  float4 qreg[6];
  {
    const float4* qg = (const float4*)(target + ((size_t)l * BATCH + b) * DMODEL + h * DH + p * 24);
#pragma unroll
    for (int j = 0; j < 6; ++j) qreg[j] = qg[j];
  }
  __syncthreads();
#pragma unroll
  for (int c = 0; c < 5; ++c) {
    int s = c * 8 + s8;
    if (s < U_TOP) {
      int kl = sidx[s];
      const float4* kg = (const float4*)(source + ((size_t)kl * BATCH + b) * DMODEL + h * DH + p * 24);
      float a = 0.f;
#pragma unroll
      for (int j = 0; j < 6; ++j) {
        float4 kv = kg[j];
        float4 qv = qreg[j];
        a += qv.x * kv.x + qv.y * kv.y + qv.z * kv.z + qv.w * kv.w;
      }
      a += __shfl_xor(a, 1, 64);
      a += __shfl_xor(a, 2, 64);
      if (p == 0) qkbuf[h][s] = a;
    }
  }
  __syncthreads();
  int w = tid >> 6, lane = tid & 63;
#pragma unroll
  for (int hi = 0; hi < 2; ++hi) {
    int hh = w * 2 + hi;
    float v = (lane < U_TOP) ? qkbuf[hh][lane] : -INFINITY;
    float sm = (lane < U_TOP) ? v : 0.f;
    float mx = v;
#pragma unroll
    for (int off = 32; off; off >>= 1) {
      mx = fmaxf(mx, __shfl_xor(mx, off, 64));
      sm += __shfl_xor(sm, off, 64);
    }
    if (lane == 0)
      M[(size_t)(b * NH + hh) * L_SEQ + l] = mx - sm * (1.f / U_TOP);
  }
}

// ---------------- top-35 per (b,h): register-resident, shuffle-reduce ----------------
__global__ __launch_bounds__(256) void topk_sel(const float* __restrict__ M,
                                                int* __restrict__ top, int* __restrict__ sel) {
  int bh = blockIdx.x;
  int tid = threadIdx.x;
  int lane = tid & 63, w = tid >> 6;
  __shared__ float wval[4];
  __shared__ int widx[4];
  __shared__ int bidx_sh;
  float v[4]; int ir[4];
#pragma unroll
  for (int i = 0; i < 4; ++i) {
    int ii = tid + i * 256;
    v[i] = M[(size_t)bh * L_SEQ + ii];
    ir[i] = ii;
    sel[(size_t)bh * L_SEQ + ii] = -1;
  }
  for (int it = 0; it < U_TOP; ++it) {
    float bv = v[0]; int bi = ir[0];
#pragma unroll
    for (int i = 1; i < 4; ++i)
      if (v[i] > bv || (v[i] == bv && ir[i] < bi)) { bv = v[i]; bi = ir[i]; }
#pragma unroll
    for (int off = 32; off; off >>= 1) {
      float ov = __shfl_xor(bv, off, 64);
      int oi = __shfl_xor(bi, off, 64);
      if (ov > bv || (ov == bv && oi < bi)) { bv = ov; bi = oi; }
    }
    if (lane == 0) { wval[w] = bv; widx[w] = bi; }
    __syncthreads();
    if (tid == 0) {
      float fv = wval[0]; int fi = widx[0];
#pragma unroll
      for (int k = 1; k < 4; ++k)
        if (wval[k] > fv || (wval[k] == fv && widx[k] < fi)) { fv = wval[k]; fi = widx[k]; }
      top[bh * U_TOP + it] = fi;
      sel[(size_t)bh * L_SEQ + fi] = it;
      bidx_sh = fi;
    }
    __syncthreads();
    int rb = bidx_sh;
    if ((rb & 255) == tid) v[rb >> 8] = -INFINITY;
  }
}

// ---------------- V.mean: two-phase ----------------
__global__ __launch_bounds__(768) void vmean_part(const float* __restrict__ source,
                                                  float* __restrict__ part) {
  int blk = blockIdx.x;            // b*VCH + c
  int b = blk >> 6, c = blk & (VCH - 1);
  int d = threadIdx.x;
  float s = 0.f;
  int l0 = c * (L_SEQ / VCH);
#pragma unroll
  for (int l = l0; l < l0 + L_SEQ / VCH; ++l)
    s += source[((size_t)l * BATCH + b) * DMODEL + d];
  part[(size_t)blk * DMODEL + d] = s;
}

__global__ __launch_bounds__(768) void vmean_comb(const float* __restrict__ part,
                                                  float* __restrict__ vmean) {
  int b = blockIdx.x;
  int d = threadIdx.x;
  float s = 0.f;
  for (int c = 0; c < VCH; ++c) s += part[((size_t)(b * VCH + c)) * DMODEL + d];
  vmean[b * DMODEL + d] = s * (1.f / L_SEQ);
}

// ---------------- flash attention chunk via MFMA (verified R15) ----------------
__global__ __launch_bounds__(256) void attn_flash(
    const float* __restrict__ target, const float* __restrict__ source,
    const int* __restrict__ top,
    float* __restrict__ part_O,   // [NBH*NCHUNK][35][96]
    float* __restrict__ part_m,   // [NBH*NCHUNK][35]
    float* __restrict__ part_s) {
  int blk = blockIdx.x;
  int chunk = blk & (NCHUNK - 1);
  int bh = blk >> 4;
  int h = bh & (NH - 1), b = bh >> 3;
  __shared__ short Qb[48 * 104];     // Q (scaled), later P
  __shared__ short Kb[CHUNK * 104];
  __shared__ short Vt[96 * 72];
  __shared__ float sc[48 * 66];
  int tid = threadIdx.x;
  const float scale = 0.1020620726f;   // 1/sqrt(96)
  for (int i = tid; i < 13 * 104; i += 256) Qb[35 * 104 + i] = 0;
  for (int i = tid; i < U_TOP * 24; i += 256) {
    int u = i / 24, d4 = i - u * 24;
    int qpos = top[bh * U_TOP + u];
    float4 v = *(const float4*)(target + ((size_t)qpos * BATCH + b) * DMODEL + h * DH + d4 * 4);
    short* dst = Qb + u * 104 + d4 * 4;
    dst[0] = f2bf(v.x * scale); dst[1] = f2bf(v.y * scale);
    dst[2] = f2bf(v.z * scale); dst[3] = f2bf(v.w * scale);
  }
  int l0 = chunk * CHUNK;
  for (int i = tid; i < CHUNK * 24; i += 256) {
    int r = i / 24, d4 = i - r * 24;
    float4 v = *(const float4*)(source + ((size_t)(l0 + r) * BATCH + b) * DMODEL + h * DH + d4 * 4);
    short* dst = Kb + r * 104 + d4 * 4;
    dst[0] = f2bf(v.x); dst[1] = f2bf(v.y); dst[2] = f2bf(v.z); dst[3] = f2bf(v.w);
  }
  __syncthreads();
  for (int i = tid; i < CHUNK * 24; i += 256) {
    int r = i & (CHUNK - 1), d4 = i >> 6;
    const short* srcp = Kb + r * 104 + d4 * 4;
#pragma unroll
    for (int cc = 0; cc < 4; ++cc) Vt[(d4 * 4 + cc) * 72 + r] = srcp[cc];
  }
  int wv = tid >> 6, lane = tid & 63;
  int lr = lane & 15, lg = lane >> 4;
  __syncthreads();
  {
    int n = wv;
#pragma unroll
    for (int m = 0; m < 3; ++m) {
      f32x4 acc = {};
#pragma unroll
      for (int kc = 0; kc < 3; ++kc) {
        bf16x8 a = *(const bf16x8*)(Qb + (m * 16 + lr) * 104 + kc * 32 + lg * 8);
        bf16x8 bb = *(const bf16x8*)(Kb + (n * 16 + lr) * 104 + kc * 32 + lg * 8);
        acc = __builtin_amdgcn_mfma_f32_16x16x32_bf16(a, bb, acc, 0, 0, 0);
      }
#pragma unroll
      for (int j = 0; j < 4; ++j)
        sc[(m * 16 + lg * 4 + j) * 66 + n * 16 + lr] = acc[j];
    }
  }
  __syncthreads();
#pragma unroll
  for (int i = 0; i < 9; ++i) {
    int u = wv + 4 * i;
    if (u < U_TOP) {
      float s = sc[u * 66 + lane];
      float mx = s;
#pragma unroll
      for (int off = 32; off; off >>= 1) mx = fmaxf(mx, __shfl_xor(mx, off, 64));
      float pp = expf(s - mx);
      float sm = pp;
#pragma unroll
      for (int off = 32; off; off >>= 1) sm += __shfl_xor(sm, off, 64);
      Qb[u * 104 + lane] = f2bf(pp);
      if (lane == 0) {
        part_m[blk * U_TOP + u] = mx;
        part_s[blk * U_TOP + u] = sm;
      }
    }
  }
  __syncthreads();
  for (int t = wv; t < 18; t += 4) {
    int m = t / 6, n = t - (t / 6) * 6;
    f32x4 acc = {};
#pragma unroll
    for (int kc = 0; kc < 2; ++kc) {
      bf16x8 a = *(const bf16x8*)(Qb + (m * 16 + lr) * 104 + kc * 32 + lg * 8);
      bf16x8 bb = *(const bf16x8*)(Vt + (n * 16 + lr) * 72 + kc * 32 + lg * 8);
      acc = __builtin_amdgcn_mfma_f32_16x16x32_bf16(a, bb, acc, 0, 0, 0);
    }
#pragma unroll
    for (int j = 0; j < 4; ++j) {
      int u = m * 16 + lg * 4 + j;
      if (u < U_TOP)
        part_O[(size_t)blk * U_TOP * DH + u * DH + n * 16 + lr] = acc[j];
    }
  }
}

// ---------------- merge NCHUNK partials per (b,h) ----------------
__global__ __launch_bounds__(256) void attn_combine(
    const float* __restrict__ part_O, const float* __restrict__ part_m,
    const float* __restrict__ part_s, float* __restrict__ upd) {
  int bh = blockIdx.x;
  __shared__ float w[NCHUNK][U_TOP];
  __shared__ float Sinv[U_TOP];
  int tid = threadIdx.x;
  if (tid < U_TOP) {
    float m = -INFINITY;
    for (int c = 0; c < NCHUNK; ++c)
      m = fmaxf(m, part_m[(bh * NCHUNK + c) * U_TOP + tid]);
    float s = 0.f;
    for (int c = 0; c < NCHUNK; ++c) {
      float wv = expf(part_m[(bh * NCHUNK + c) * U_TOP + tid] - m);
      w[c][tid] = wv;
      s += wv * part_s[(bh * NCHUNK + c) * U_TOP + tid];
    }
    Sinv[tid] = 1.f / s;
  }
  __syncthreads();
  for (int i = tid; i < U_TOP * DH; i += 256) {
    int u = i / DH;
    float acc = 0.f;
#pragma unroll
    for (int c = 0; c < NCHUNK; ++c)
      acc += w[c][u] * part_O[((size_t)bh * NCHUNK + c) * U_TOP * DH + i];
    upd[(size_t)bh * U_TOP * DH + i] = acc * Sinv[u];
  }
}

// ---------------- attended + residual + LN1 -> normed1 (fp32 + bf16) ----------------
__global__ __launch_bounds__(256) void fuse_ln1(
    const float* __restrict__ target, const float* __restrict__ upd,
    const int* __restrict__ sel, const float* __restrict__ vmean,
    const float* __restrict__ g, const float* __restrict__ bb,
    float* __restrict__ normed1, unsigned short* __restrict__ normed1b) {
  int r = blockIdx.x;              // r = l*BATCH + b
  int l = r >> 2, b = r & 3;
  __shared__ float x[DMODEL];
  __shared__ float red[256];
  int tid = threadIdx.x;
  for (int d = tid; d < DMODEL; d += 256) {
    int h = d / DH;
    int s = sel[((size_t)(b * NH + h)) * L_SEQ + l];
    float a = (s >= 0) ? upd[((size_t)(b * NH + h) * U_TOP + s) * DH + (d - h * DH)]
                       : vmean[b * DMODEL + d];
    x[d] = target[(size_t)r * DMODEL + d] + a;
  }
  __syncthreads();
  float partial = 0.f;
  for (int d = tid; d < DMODEL; d += 256) partial += x[d];
  red[tid] = partial; __syncthreads();
  for (int s = 128; s; s >>= 1) { if (tid < s) red[tid] += red[tid + s]; __syncthreads(); }
  float mu = red[0] * (1.f / DMODEL);
  __syncthreads();
  partial = 0.f;
  for (int d = tid; d < DMODEL; d += 256) { float t = x[d] - mu; partial += t * t; }
  red[tid] = partial; __syncthreads();
  for (int s = 128; s; s >>= 1) { if (tid < s) red[tid] += red[tid + s]; __syncthreads(); }
  float rstd = 1.0f / sqrtf(red[0] * (1.f / DMODEL) + 1e-5f);
  for (int d = tid; d < DMODEL; d += 256) {
    float v = (x[d] - mu) * rstd * g[d] + bb[d];
    normed1[(size_t)r * DMODEL + d] = v;
    normed1b[(size_t)r * DMODEL + d] = f2bf(v);
  }
}

// ---------------- fp32 -> bf16 convert (for W1, W2) ----------------
__global__ __launch_bounds__(256) void convert_bf16(const float* __restrict__ in,
                                                    unsigned short* __restrict__ outp, int n4) {
  int i = blockIdx.x * 256 + threadIdx.x;
  int stride = gridDim.x * 256;
  for (; i < n4; i += stride) {
    float4 v = ((const float4*)in)[i];
    unsigned long long pk = (unsigned long long)f2bf(v.x)
                          | ((unsigned long long)f2bf(v.y) << 16)
                          | ((unsigned long long)f2bf(v.z) << 32)
                          | ((unsigned long long)f2bf(v.w) << 48);
    ((unsigned long long*)outp)[i] = pk;
  }
}

// ---------------- bf16 MFMA GEMM, 64x64 tile (occupancy-oriented) ----------------
// 4 waves 2x2, each 32x32 (acc[2][2]); BK=64; same staging/swizzle idiom as the
// verified 128x128 kernel (slot=(lane&7)^(trow&7), phys=(c*4+lg)^(row&7)).
template <bool RELU, bool BF16OUT>
__global__ __launch_bounds__(256) void gemm_mfma64(
    const unsigned short* __restrict__ A, const unsigned short* __restrict__ B,
    const float* __restrict__ bias, void* __restrict__ Cout,
    int Ndim, int Kdim) {
  __shared__ short As[64 * 64];
  __shared__ short Bs[64 * 64];
  int tid = threadIdx.x;
  int lane = tid & 63;
  int wid = tid >> 6;
  int wm = wid >> 1, wn = wid & 1;       // 2x2 waves, each 32x32
  int bm = blockIdx.y * 64, bn = blockIdx.x * 64;

  f32x4 acc[2][2] = {};

  for (int k0 = 0; k0 < Kdim; k0 += 64) {
#pragma unroll
    for (int i = 0; i < 2; ++i) {
      int trow = wid * 16 + i * 8 + (lane >> 3);
      int slot = (lane & 7) ^ (trow & 7);          // pre-swizzled global source
      const unsigned short* ga = A + (size_t)(bm + trow) * Kdim + k0 + slot * 8;
      const unsigned short* gb = B + (size_t)(bn + trow) * Kdim + k0 + slot * 8;
      __builtin_amdgcn_global_load_lds(
          (const __attribute__((address_space(1))) void*)ga,
          (__attribute__((address_space(3))) void*)(As + (wid * 16 + i * 8) * 64),
          16, 0, 0);
      __builtin_amdgcn_global_load_lds(
          (const __attribute__((address_space(1))) void*)gb,
          (__attribute__((address_space(3))) void*)(Bs + (wid * 16 + i * 8) * 64),
          16, 0, 0);
    }
    __syncthreads();
#pragma unroll
    for (int c = 0; c < 2; ++c) {
      bf16x8 af[2], bf[2];
#pragma unroll
      for (int mi = 0; mi < 2; ++mi) {
        int row = wm * 32 + mi * 16 + (lane & 15);
        int phys = (c * 4 + (lane >> 4)) ^ (row & 7);
        af[mi] = *(const bf16x8*)(As + row * 64 + phys * 8);
      }
#pragma unroll
      for (int ni = 0; ni < 2; ++ni) {
        int row = wn * 32 + ni * 16 + (lane & 15);
        int phys = (c * 4 + (lane >> 4)) ^ (row & 7);
        bf[ni] = *(const bf16x8*)(Bs + row * 64 + phys * 8);
      }
#pragma unroll
      for (int mi = 0; mi < 2; ++mi)
#pragma unroll
        for (int ni = 0; ni < 2; ++ni)
          acc[mi][ni] = __builtin_amdgcn_mfma_f32_16x16x32_bf16(af[mi], bf[ni], acc[mi][ni], 0, 0, 0);
    }
    __syncthreads();
  }

#pragma unroll
  for (int mi = 0; mi < 2; ++mi)
#pragma unroll
    for (int ni = 0; ni < 2; ++ni) {
      int col = bn + wn * 32 + ni * 16 + (lane & 15);
      float bv = bias[col];
#pragma unroll
      for (int j = 0; j < 4; ++j) {
        int row = bm + wm * 32 + mi * 16 + (lane >> 4) * 4 + j;
        float v = acc[mi][ni][j] + bv;
        if (RELU) v = fmaxf(v, 0.f);
        if (BF16OUT)
          ((unsigned short*)Cout)[(size_t)row * Ndim + col] = f2bf(v);
        else
          ((float*)Cout)[(size_t)row * Ndim + col] = v;
      }
    }
}

// ---------------- normed1 + proj -> LN2 -> out (float4, single pass) ----------------
__global__ __launch_bounds__(192) void ln2_out(
    const float* __restrict__ normed1, const float* __restrict__ proj,
    const float* __restrict__ g, const float* __restrict__ bb,
    float* __restrict__ out) {
  int r = blockIdx.x;
  int tid = threadIdx.x;           // 192 threads x float4 = 768
  __shared__ float red[6];
  float4 a = ((const float4*)(normed1 + (size_t)r * DMODEL))[tid];
  float4 p = ((const float4*)(proj + (size_t)r * DMODEL))[tid];
  float4 x = {a.x + p.x, a.y + p.y, a.z + p.z, a.w + p.w};
  float s1 = x.x + x.y + x.z + x.w;
  float s2 = x.x * x.x + x.y * x.y + x.z * x.z + x.w * x.w;
#pragma unroll
  for (int off = 32; off; off >>= 1) {
    s1 += __shfl_xor(s1, off, 64);
    s2 += __shfl_xor(s2, off, 64);
  }
  int w = tid >> 6;
  if ((tid & 63) == 0) { red[w] = s1; red[3 + w] = s2; }
  __syncthreads();
  float S1 = red[0] + red[1] + red[2];
  float S2 = red[3] + red[4] + red[5];
  float mu = S1 * (1.f / DMODEL);
  float var = S2 * (1.f / DMODEL) - mu * mu;
  float rstd = 1.0f / sqrtf(var + 1e-5f);
  float4 gv = ((const float4*)g)[tid];
  float4 bv = ((const float4*)bb)[tid];
  float4 o = {(x.x - mu) * rstd * gv.x + bv.x, (x.y - mu) * rstd * gv.y + bv.y,
              (x.z - mu) * rstd * gv.z + bv.z, (x.w - mu) * rstd * gv.w + bv.w};
  ((float4*)(out + (size_t)r * DMODEL))[tid] = o;
}

extern "C" void kernel_launch(void* const* d_in, const int* in_sizes, int n_in,
                              void* d_out, int out_size, void* d_ws, size_t ws_size,
                              hipStream_t stream) {
  const float* target = (const float*)d_in[0];
  const float* source = (const float*)d_in[1];
  const float* W1 = (const float*)d_in[2];
  const float* b1 = (const float*)d_in[3];
  const float* W2 = (const float*)d_in[4];
  const float* b2 = (const float*)d_in[5];
  const float* ln1_g = (const float*)d_in[6];
  const float* ln1_b = (const float*)d_in[7];
  const float* ln2_g = (const float*)d_in[8];
  const float* ln2_b = (const float*)d_in[9];
  float* out = (float*)d_out;

  char* ws = (char*)d_ws;
  int*            idx      = (int*)           (ws + 0x0000000);  // 140 KB
  float*          M        = (float*)         (ws + 0x0040000);  // 128 KB
  int*            top      = (int*)           (ws + 0x0080000);  // 4.4 KB
  int*            sel      = (int*)           (ws + 0x0090000);  // 128 KB
  float*          upd      = (float*)         (ws + 0x00C0000);  // 420 KB
  float*          vmean    = (float*)         (ws + 0x0130000);  // 12 KB
  float*          part_m   = (float*)         (ws + 0x0140000);  // 72 KB
  float*          part_s   = (float*)         (ws + 0x0160000);  // 72 KB
  unsigned short* w1b      = (unsigned short*)(ws + 0x0180000);  // 3 MB
  unsigned short* w2b      = (unsigned short*)(ws + 0x0480000);  // 3 MB
  unsigned short* normed1b = (unsigned short*)(ws + 0x0780000);  // 6 MB
  float*          normed1  = (float*)         (ws + 0x0D80000);  // 12 MB
  unsigned short* h1b      = (unsigned short*)(ws + 0x1980000);  // 16 MB region
  float*          part_O   = (float*)         (ws + 0x1980000);  // 6.9 MB, aliases h1b (dead before gemm1)
  float*          vpart    = (float*)         (ws + 0x2200000);  // 786 KB, aliases h1b (dead before gemm1)
  float*          proj     = (float*)         (ws + 0x2980000);  // 12 MB -> ends 0x3580000 (56 MB)

  gen_idx<<<(IDX_CNT + 255) / 256, 256, 0, stream>>>(idx);
  sample_scores<<<BATCH * L_SEQ, 256, 0, stream>>>(target, source, idx, M);
  topk_sel<<<NBH, 256, 0, stream>>>(M, top, sel);
  vmean_part<<<BATCH * VCH, 768, 0, stream>>>(source, vpart);
  vmean_comb<<<BATCH, 768, 0, stream>>>(vpart, vmean);
  attn_flash<<<NBH * NCHUNK, 256, 0, stream>>>(target, source, top, part_O, part_m, part_s);
  attn_combine<<<NBH, 256, 0, stream>>>(part_O, part_m, part_s, upd);
  convert_bf16<<<1024, 256, 0, stream>>>(W1, w1b, DFF * DMODEL / 4);
  convert_bf16<<<1024, 256, 0, stream>>>(W2, w2b, DFF * DMODEL / 4);
  fuse_ln1<<<NROWS, 256, 0, stream>>>(target, upd, sel, vmean, ln1_g, ln1_b, normed1, normed1b);
  {
    dim3 grid(DFF / 64, NROWS / 64);     // 32 x 64 = 2048 blocks
    gemm_mfma64<true, true><<<grid, 256, 0, stream>>>(normed1b, w1b, b1, h1b, DFF, DMODEL);
  }
  {
    dim3 grid(DMODEL / 64, NROWS / 64);  // 12 x 64 = 768 blocks
    gemm_mfma64<false, false><<<grid, 256, 0, stream>>>(h1b, w2b, b2, proj, DMODEL, DFF);
  }
  ln2_out<<<NROWS, 192, 0, stream>>>(normed1, proj, ln2_g, ln2_b, out);
}

// Round 18
// 161.789 us; speedup vs baseline: 6.1562x; 1.0830x over previous
//
#include <hip/hip_runtime.h>
#include <hip/hip_bf16.h>
#include <math.h>

#define L_SEQ 1024
#define BATCH 4
#define DMODEL 768
#define NH 8
#define DH 96
#define DFF 2048
#define U_TOP 35
#define NROWS (L_SEQ * BATCH)
#define NBH (BATCH * NH)
#define CHUNK 64
#define NCHUNK (L_SEQ / CHUNK)    // 16
#define VCH 64                    // vmean chunks per batch

typedef __attribute__((ext_vector_type(8))) short bf16x8;
typedef __attribute__((ext_vector_type(4))) float f32x4;

__device__ inline unsigned short f2bf(float f) {
  unsigned u = __float_as_uint(f);
  u += 0x7FFFu + ((u >> 16) & 1u);   // RNE
  return (unsigned short)(u >> 16);
}

// ---------------- Threefry-2x32 (exact JAX reproduction) ----------------
__device__ inline unsigned rotl32(unsigned v, int d) { return (v << d) | (v >> (32 - d)); }

__device__ inline void tf2x32(unsigned k0, unsigned k1, unsigned x0, unsigned x1,
                              unsigned& o0, unsigned& o1) {
  unsigned ks0 = k0, ks1 = k1, ks2 = k0 ^ k1 ^ 0x1BD11BDAu;
  x0 += ks0; x1 += ks1;
#define TFR(r) { x0 += x1; x1 = rotl32(x1, r); x1 ^= x0; }
  TFR(13) TFR(15) TFR(26) TFR(6)
  x0 += ks1; x1 += ks2 + 1u;
  TFR(17) TFR(29) TFR(16) TFR(24)
  x0 += ks2; x1 += ks0 + 2u;
  TFR(13) TFR(15) TFR(26) TFR(6)
  x0 += ks0; x1 += ks1 + 3u;
  TFR(17) TFR(29) TFR(16) TFR(24)
  x0 += ks1; x1 += ks2 + 4u;
  TFR(13) TFR(15) TFR(26) TFR(6)
  x0 += ks2; x1 += ks0 + 5u;
#undef TFR
  o0 = x0; o1 = x1;
}

// idx[j] = (w0^w1 of E(k2,(0,j))) & 1023, k2 = foldlike split(key(42))[1]
__device__ inline int jax_randint1024(int j) {
  unsigned k2a, k2b, o0, o1;
  tf2x32(0u, 42u, 0u, 1u, k2a, k2b);
  tf2x32(k2a, k2b, 0u, (unsigned)j, o0, o1);
  return (int)((o0 ^ o1) & 1023u);
}

// ---------------- M[b,h,l]: register-direct L2 gather; idx inlined ----------------
__global__ __launch_bounds__(256) void sample_scores(
    const float* __restrict__ target, const float* __restrict__ source,
    float* __restrict__ M) {
  int orig = blockIdx.x;
  int blk = (orig & 7) * (BATCH * L_SEQ / 8) + (orig >> 3);   // bijective (4096 % 8 == 0)
  int l = blk & (L_SEQ - 1);
  int b = blk >> 10;
  __shared__ float qkbuf[NH][40];
  __shared__ int sidx[40];
  int tid = threadIdx.x;
  if (tid < 40) sidx[tid] = (tid < U_TOP) ? jax_randint1024(l * U_TOP + tid) : 0;
  int h = (tid >> 2) & 7, p = tid & 3;
  int s8 = tid >> 5;
  float4 qreg[6];
  {
    const float4* qg = (const float4*)(target + ((size_t)l * BATCH + b) * DMODEL + h * DH + p * 24);
#pragma unroll
    for (int j = 0; j < 6; ++j) qreg[j] = qg[j];
  }
  __syncthreads();
#pragma unroll
  for (int c = 0; c < 5; ++c) {
    int s = c * 8 + s8;
    if (s < U_TOP) {
      int kl = sidx[s];
      const float4* kg = (const float4*)(source + ((size_t)kl * BATCH + b) * DMODEL + h * DH + p * 24);
      float a = 0.f;
#pragma unroll
      for (int j = 0; j < 6; ++j) {
        float4 kv = kg[j];
        float4 qv = qreg[j];
        a += qv.x * kv.x + qv.y * kv.y + qv.z * kv.z + qv.w * kv.w;
      }
      a += __shfl_xor(a, 1, 64);
      a += __shfl_xor(a, 2, 64);
      if (p == 0) qkbuf[h][s] = a;
    }
  }
  __syncthreads();
  int w = tid >> 6, lane = tid & 63;
#pragma unroll
  for (int hi = 0; hi < 2; ++hi) {
    int hh = w * 2 + hi;
    float v = (lane < U_TOP) ? qkbuf[hh][lane] : -INFINITY;
    float sm = (lane < U_TOP) ? v : 0.f;
    float mx = v;
#pragma unroll
    for (int off = 32; off; off >>= 1) {
      mx = fmaxf(mx, __shfl_xor(mx, off, 64));
      sm += __shfl_xor(sm, off, 64);
    }
    if (lane == 0)
      M[(size_t)(b * NH + hh) * L_SEQ + l] = mx - sm * (1.f / U_TOP);
  }
}

// ---------------- top-35 per (b,h): register-resident, shuffle-reduce ----------------
__global__ __launch_bounds__(256) void topk_sel(const float* __restrict__ M,
                                                int* __restrict__ top, int* __restrict__ sel) {
  int bh = blockIdx.x;
  int tid = threadIdx.x;
  int lane = tid & 63, w = tid >> 6;
  __shared__ float wval[4];
  __shared__ int widx[4];
  __shared__ int bidx_sh;
  float v[4]; int ir[4];
#pragma unroll
  for (int i = 0; i < 4; ++i) {
    int ii = tid + i * 256;
    v[i] = M[(size_t)bh * L_SEQ + ii];
    ir[i] = ii;
    sel[(size_t)bh * L_SEQ + ii] = -1;
  }
  for (int it = 0; it < U_TOP; ++it) {
    float bv = v[0]; int bi = ir[0];
#pragma unroll
    for (int i = 1; i < 4; ++i)
      if (v[i] > bv || (v[i] == bv && ir[i] < bi)) { bv = v[i]; bi = ir[i]; }
#pragma unroll
    for (int off = 32; off; off >>= 1) {
      float ov = __shfl_xor(bv, off, 64);
      int oi = __shfl_xor(bi, off, 64);
      if (ov > bv || (ov == bv && oi < bi)) { bv = ov; bi = oi; }
    }
    if (lane == 0) { wval[w] = bv; widx[w] = bi; }
    __syncthreads();
    if (tid == 0) {
      float fv = wval[0]; int fi = widx[0];
#pragma unroll
      for (int k = 1; k < 4; ++k)
        if (wval[k] > fv || (wval[k] == fv && widx[k] < fi)) { fv = wval[k]; fi = widx[k]; }
      top[bh * U_TOP + it] = fi;
      sel[(size_t)bh * L_SEQ + fi] = it;
      bidx_sh = fi;
    }
    __syncthreads();
    int rb = bidx_sh;
    if ((rb & 255) == tid) v[rb >> 8] = -INFINITY;
  }
}

// ---------------- V.mean: two-phase ----------------
__global__ __launch_bounds__(768) void vmean_part(const float* __restrict__ source,
                                                  float* __restrict__ part) {
  int blk = blockIdx.x;            // b*VCH + c
  int b = blk >> 6, c = blk & (VCH - 1);
  int d = threadIdx.x;
  float s = 0.f;
  int l0 = c * (L_SEQ / VCH);
#pragma unroll
  for (int l = l0; l < l0 + L_SEQ / VCH; ++l)
    s += source[((size_t)l * BATCH + b) * DMODEL + d];
  part[(size_t)blk * DMODEL + d] = s;
}

__global__ __launch_bounds__(768) void vmean_comb(const float* __restrict__ part,
                                                  float* __restrict__ vmean) {
  int b = blockIdx.x;
  int d = threadIdx.x;
  float s = 0.f;
  for (int c = 0; c < VCH; ++c) s += part[((size_t)(b * VCH + c)) * DMODEL + d];
  vmean[b * DMODEL + d] = s * (1.f / L_SEQ);
}

// ---------------- flash attention chunk via MFMA (verified R15) ----------------
__global__ __launch_bounds__(256) void attn_flash(
    const float* __restrict__ target, const float* __restrict__ source,
    const int* __restrict__ top,
    float* __restrict__ part_O,   // [NBH*NCHUNK][35][96]
    float* __restrict__ part_m,   // [NBH*NCHUNK][35]
    float* __restrict__ part_s) {
  int blk = blockIdx.x;
  int chunk = blk & (NCHUNK - 1);
  int bh = blk >> 4;
  int h = bh & (NH - 1), b = bh >> 3;
  __shared__ short Qb[48 * 104];     // Q (scaled), later P
  __shared__ short Kb[CHUNK * 104];
  __shared__ short Vt[96 * 72];
  __shared__ float sc[48 * 66];
  int tid = threadIdx.x;
  const float scale = 0.1020620726f;   // 1/sqrt(96)
  for (int i = tid; i < 13 * 104; i += 256) Qb[35 * 104 + i] = 0;
  for (int i = tid; i < U_TOP * 24; i += 256) {
    int u = i / 24, d4 = i - u * 24;
    int qpos = top[bh * U_TOP + u];
    float4 v = *(const float4*)(target + ((size_t)qpos * BATCH + b) * DMODEL + h * DH + d4 * 4);
    short* dst = Qb + u * 104 + d4 * 4;
    dst[0] = f2bf(v.x * scale); dst[1] = f2bf(v.y * scale);
    dst[2] = f2bf(v.z * scale); dst[3] = f2bf(v.w * scale);
  }
  int l0 = chunk * CHUNK;
  for (int i = tid; i < CHUNK * 24; i += 256) {
    int r = i / 24, d4 = i - r * 24;
    float4 v = *(const float4*)(source + ((size_t)(l0 + r) * BATCH + b) * DMODEL + h * DH + d4 * 4);
    short* dst = Kb + r * 104 + d4 * 4;
    dst[0] = f2bf(v.x); dst[1] = f2bf(v.y); dst[2] = f2bf(v.z); dst[3] = f2bf(v.w);
  }
  __syncthreads();
  for (int i = tid; i < CHUNK * 24; i += 256) {
    int r = i & (CHUNK - 1), d4 = i >> 6;
    const short* srcp = Kb + r * 104 + d4 * 4;
#pragma unroll
    for (int cc = 0; cc < 4; ++cc) Vt[(d4 * 4 + cc) * 72 + r] = srcp[cc];
  }
  int wv = tid >> 6, lane = tid & 63;
  int lr = lane & 15, lg = lane >> 4;
  __syncthreads();
  {
    int n = wv;
#pragma unroll
    for (int m = 0; m < 3; ++m) {
      f32x4 acc = {};
#pragma unroll
      for (int kc = 0; kc < 3; ++kc) {
        bf16x8 a = *(const bf16x8*)(Qb + (m * 16 + lr) * 104 + kc * 32 + lg * 8);
        bf16x8 bb = *(const bf16x8*)(Kb + (n * 16 + lr) * 104 + kc * 32 + lg * 8);
        acc = __builtin_amdgcn_mfma_f32_16x16x32_bf16(a, bb, acc, 0, 0, 0);
      }
#pragma unroll
      for (int j = 0; j < 4; ++j)
        sc[(m * 16 + lg * 4 + j) * 66 + n * 16 + lr] = acc[j];
    }
  }
  __syncthreads();
#pragma unroll
  for (int i = 0; i < 9; ++i) {
    int u = wv + 4 * i;
    if (u < U_TOP) {
      float s = sc[u * 66 + lane];
      float mx = s;
#pragma unroll
      for (int off = 32; off; off >>= 1) mx = fmaxf(mx, __shfl_xor(mx, off, 64));
      float pp = expf(s - mx);
      float sm = pp;
#pragma unroll
      for (int off = 32; off; off >>= 1) sm += __shfl_xor(sm, off, 64);
      Qb[u * 104 + lane] = f2bf(pp);
      if (lane == 0) {
        part_m[blk * U_TOP + u] = mx;
        part_s[blk * U_TOP + u] = sm;
      }
    }
  }
  __syncthreads();
  for (int t = wv; t < 18; t += 4) {
    int m = t / 6, n = t - (t / 6) * 6;
    f32x4 acc = {};
#pragma unroll
    for (int kc = 0; kc < 2; ++kc) {
      bf16x8 a = *(const bf16x8*)(Qb + (m * 16 + lr) * 104 + kc * 32 + lg * 8);
      bf16x8 bb = *(const bf16x8*)(Vt + (n * 16 + lr) * 72 + kc * 32 + lg * 8);
      acc = __builtin_amdgcn_mfma_f32_16x16x32_bf16(a, bb, acc, 0, 0, 0);
    }
#pragma unroll
    for (int j = 0; j < 4; ++j) {
      int u = m * 16 + lg * 4 + j;
      if (u < U_TOP)
        part_O[(size_t)blk * U_TOP * DH + u * DH + n * 16 + lr] = acc[j];
    }
  }
}

// ---------------- combine + residual + LN1 -> normed1 (fp32 + bf16) ----------------
// attn_combine fused in: each selected (bh,u) occurs at exactly one row (l,b),
// so chunk weights (16-lane shfl subgroup reduce) + 16-chunk part_O merge happen here.
__global__ __launch_bounds__(256) void fuse_ln1(
    const float* __restrict__ target, const float* __restrict__ part_O,
    const float* __restrict__ part_m, const float* __restrict__ part_s,
    const int* __restrict__ sel, const float* __restrict__ vmean,
    const float* __restrict__ g, const float* __restrict__ bb,
    float* __restrict__ normed1, unsigned short* __restrict__ normed1b) {
  int r = blockIdx.x;              // r = l*BATCH + b
  int l = r >> 2, b = r & 3;
  __shared__ float wgt[NH][NCHUNK];
  __shared__ float sinv[NH];
  __shared__ int uarr[NH];
  __shared__ float x[DMODEL];
  __shared__ float red[256];
  int tid = threadIdx.x;
  if (tid < NH) uarr[tid] = sel[((size_t)(b * NH + tid)) * L_SEQ + l];
  __syncthreads();
  if (tid < NH * NCHUNK) {           // threads 0..127: (h = tid>>4, c = tid&15)
    int h = tid >> 4, c = tid & 15;
    int u = uarr[h];
    if (u >= 0) {
      int bh = b * NH + h;
      float pm = part_m[(bh * NCHUNK + c) * U_TOP + u];
      float mx = pm;
#pragma unroll
      for (int off = 1; off < 16; off <<= 1) mx = fmaxf(mx, __shfl_xor(mx, off, 64));
      float wv = expf(pm - mx);
      float sv = wv * part_s[(bh * NCHUNK + c) * U_TOP + u];
#pragma unroll
      for (int off = 1; off < 16; off <<= 1) sv += __shfl_xor(sv, off, 64);
      wgt[h][c] = wv;
      if (c == 0) sinv[h] = 1.f / sv;
    }
  }
  __syncthreads();
  for (int d = tid; d < DMODEL; d += 256) {
    int h = d / DH;
    int u = uarr[h];
    float a;
    if (u >= 0) {
      int bh = b * NH + h;
      int dd = d - h * DH;
      float acc = 0.f;
#pragma unroll
      for (int c = 0; c < NCHUNK; ++c)
        acc += wgt[h][c] * part_O[((size_t)(bh * NCHUNK + c) * U_TOP + u) * DH + dd];
      a = acc * sinv[h];
    } else {
      a = vmean[b * DMODEL + d];
    }
    x[d] = target[(size_t)r * DMODEL + d] + a;
  }
  __syncthreads();
  float partial = 0.f;
  for (int d = tid; d < DMODEL; d += 256) partial += x[d];
  red[tid] = partial; __syncthreads();
  for (int s = 128; s; s >>= 1) { if (tid < s) red[tid] += red[tid + s]; __syncthreads(); }
  float mu = red[0] * (1.f / DMODEL);
  __syncthreads();
  partial = 0.f;
  for (int d = tid; d < DMODEL; d += 256) { float t = x[d] - mu; partial += t * t; }
  red[tid] = partial; __syncthreads();
  for (int s = 128; s; s >>= 1) { if (tid < s) red[tid] += red[tid + s]; __syncthreads(); }
  float rstd = 1.0f / sqrtf(red[0] * (1.f / DMODEL) + 1e-5f);
  for (int d = tid; d < DMODEL; d += 256) {
    float v = (x[d] - mu) * rstd * g[d] + bb[d];
    normed1[(size_t)r * DMODEL + d] = v;
    normed1b[(size_t)r * DMODEL + d] = f2bf(v);
  }
}

// ---------------- fp32 -> bf16 convert, W1 and W2 in one launch ----------------
__global__ __launch_bounds__(256) void convert_bf16_2(
    const float* __restrict__ inA, const float* __restrict__ inB,
    unsigned short* __restrict__ outA, unsigned short* __restrict__ outB, int n4each) {
  int i = blockIdx.x * 256 + threadIdx.x;
  int stride = gridDim.x * 256;
  for (; i < 2 * n4each; i += stride) {
    const float* in = (i < n4each) ? inA : inB;
    unsigned short* outp = (i < n4each) ? outA : outB;
    int k = (i < n4each) ? i : i - n4each;
    float4 v = ((const float4*)in)[k];
    unsigned long long pk = (unsigned long long)f2bf(v.x)
                          | ((unsigned long long)f2bf(v.y) << 16)
                          | ((unsigned long long)f2bf(v.z) << 32)
                          | ((unsigned long long)f2bf(v.w) << 48);
    ((unsigned long long*)outp)[k] = pk;
  }
}

// ---------------- bf16 MFMA GEMM, 64x64 tile (verified R17) ----------------
template <bool RELU, bool BF16OUT>
__global__ __launch_bounds__(256) void gemm_mfma64(
    const unsigned short* __restrict__ A, const unsigned short* __restrict__ B,
    const float* __restrict__ bias, void* __restrict__ Cout,
    int Ndim, int Kdim) {
  __shared__ short As[64 * 64];
  __shared__ short Bs[64 * 64];
  int tid = threadIdx.x;
  int lane = tid & 63;
  int wid = tid >> 6;
  int wm = wid >> 1, wn = wid & 1;       // 2x2 waves, each 32x32
  int bm = blockIdx.y * 64, bn = blockIdx.x * 64;

  f32x4 acc[2][2] = {};

  for (int k0 = 0; k0 < Kdim; k0 += 64) {
#pragma unroll
    for (int i = 0; i < 2; ++i) {
      int trow = wid * 16 + i * 8 + (lane >> 3);
      int slot = (lane & 7) ^ (trow & 7);          // pre-swizzled global source
      const unsigned short* ga = A + (size_t)(bm + trow) * Kdim + k0 + slot * 8;
      const unsigned short* gb = B + (size_t)(bn + trow) * Kdim + k0 + slot * 8;
      __builtin_amdgcn_global_load_lds(
          (const __attribute__((address_space(1))) void*)ga,
          (__attribute__((address_space(3))) void*)(As + (wid * 16 + i * 8) * 64),
          16, 0, 0);
      __builtin_amdgcn_global_load_lds(
          (const __attribute__((address_space(1))) void*)gb,
          (__attribute__((address_space(3))) void*)(Bs + (wid * 16 + i * 8) * 64),
          16, 0, 0);
    }
    __syncthreads();
#pragma unroll
    for (int c = 0; c < 2; ++c) {
      bf16x8 af[2], bf[2];
#pragma unroll
      for (int mi = 0; mi < 2; ++mi) {
        int row = wm * 32 + mi * 16 + (lane & 15);
        int phys = (c * 4 + (lane >> 4)) ^ (row & 7);
        af[mi] = *(const bf16x8*)(As + row * 64 + phys * 8);
      }
#pragma unroll
      for (int ni = 0; ni < 2; ++ni) {
        int row = wn * 32 + ni * 16 + (lane & 15);
        int phys = (c * 4 + (lane >> 4)) ^ (row & 7);
        bf[ni] = *(const bf16x8*)(Bs + row * 64 + phys * 8);
      }
#pragma unroll
      for (int mi = 0; mi < 2; ++mi)
#pragma unroll
        for (int ni = 0; ni < 2; ++ni)
          acc[mi][ni] = __builtin_amdgcn_mfma_f32_16x16x32_bf16(af[mi], bf[ni], acc[mi][ni], 0, 0, 0);
    }
    __syncthreads();
  }

#pragma unroll
  for (int mi = 0; mi < 2; ++mi)
#pragma unroll
    for (int ni = 0; ni < 2; ++ni) {
      int col = bn + wn * 32 + ni * 16 + (lane & 15);
      float bv = bias[col];
#pragma unroll
      for (int j = 0; j < 4; ++j) {
        int row = bm + wm * 32 + mi * 16 + (lane >> 4) * 4 + j;
        float v = acc[mi][ni][j] + bv;
        if (RELU) v = fmaxf(v, 0.f);
        if (BF16OUT)
          ((unsigned short*)Cout)[(size_t)row * Ndim + col] = f2bf(v);
        else
          ((float*)Cout)[(size_t)row * Ndim + col] = v;
      }
    }
}

// ---------------- normed1 + proj -> LN2 -> out (float4, single pass) ----------------
__global__ __launch_bounds__(192) void ln2_out(
    const float* __restrict__ normed1, const float* __restrict__ proj,
    const float* __restrict__ g, const float* __restrict__ bb,
    float* __restrict__ out) {
  int r = blockIdx.x;
  int tid = threadIdx.x;           // 192 threads x float4 = 768
  __shared__ float red[6];
  float4 a = ((const float4*)(normed1 + (size_t)r * DMODEL))[tid];
  float4 p = ((const float4*)(proj + (size_t)r * DMODEL))[tid];
  float4 x = {a.x + p.x, a.y + p.y, a.z + p.z, a.w + p.w};
  float s1 = x.x + x.y + x.z + x.w;
  float s2 = x.x * x.x + x.y * x.y + x.z * x.z + x.w * x.w;
#pragma unroll
  for (int off = 32; off; off >>= 1) {
    s1 += __shfl_xor(s1, off, 64);
    s2 += __shfl_xor(s2, off, 64);
  }
  int w = tid >> 6;
  if ((tid & 63) == 0) { red[w] = s1; red[3 + w] = s2; }
  __syncthreads();
  float S1 = red[0] + red[1] + red[2];
  float S2 = red[3] + red[4] + red[5];
  float mu = S1 * (1.f / DMODEL);
  float var = S2 * (1.f / DMODEL) - mu * mu;
  float rstd = 1.0f / sqrtf(var + 1e-5f);
  float4 gv = ((const float4*)g)[tid];
  float4 bv = ((const float4*)bb)[tid];
  float4 o = {(x.x - mu) * rstd * gv.x + bv.x, (x.y - mu) * rstd * gv.y + bv.y,
              (x.z - mu) * rstd * gv.z + bv.z, (x.w - mu) * rstd * gv.w + bv.w};
  ((float4*)(out + (size_t)r * DMODEL))[tid] = o;
}

extern "C" void kernel_launch(void* const* d_in, const int* in_sizes, int n_in,
                              void* d_out, int out_size, void* d_ws, size_t ws_size,
                              hipStream_t stream) {
  const float* target = (const float*)d_in[0];
  const float* source = (const float*)d_in[1];
  const float* W1 = (const float*)d_in[2];
  const float* b1 = (const float*)d_in[3];
  const float* W2 = (const float*)d_in[4];
  const float* b2 = (const float*)d_in[5];
  const float* ln1_g = (const float*)d_in[6];
  const float* ln1_b = (const float*)d_in[7];
  const float* ln2_g = (const float*)d_in[8];
  const float* ln2_b = (const float*)d_in[9];
  float* out = (float*)d_out;

  char* ws = (char*)d_ws;
  float*          M        = (float*)         (ws + 0x0040000);  // 128 KB
  int*            top      = (int*)           (ws + 0x0080000);  // 4.4 KB
  int*            sel      = (int*)           (ws + 0x0090000);  // 128 KB
  float*          vmean    = (float*)         (ws + 0x0130000);  // 12 KB
  float*          part_m   = (float*)         (ws + 0x0140000);  // 72 KB
  float*          part_s   = (float*)         (ws + 0x0160000);  // 72 KB
  unsigned short* w1b      = (unsigned short*)(ws + 0x0180000);  // 3 MB
  unsigned short* w2b      = (unsigned short*)(ws + 0x0480000);  // 3 MB
  unsigned short* normed1b = (unsigned short*)(ws + 0x0780000);  // 6 MB
  float*          normed1  = (float*)         (ws + 0x0D80000);  // 12 MB
  unsigned short* h1b      = (unsigned short*)(ws + 0x1980000);  // 16 MB region
  float*          part_O   = (float*)         (ws + 0x1980000);  // 6.9 MB, aliases h1b (dead before gemm1)
  float*          vpart    = (float*)         (ws + 0x2200000);  // 786 KB, aliases h1b (dead before gemm1)
  float*          proj     = (float*)         (ws + 0x2980000);  // 12 MB -> ends 0x3580000 (56 MB)

  sample_scores<<<BATCH * L_SEQ, 256, 0, stream>>>(target, source, M);
  topk_sel<<<NBH, 256, 0, stream>>>(M, top, sel);
  vmean_part<<<BATCH * VCH, 768, 0, stream>>>(source, vpart);
  vmean_comb<<<BATCH, 768, 0, stream>>>(vpart, vmean);
  attn_flash<<<NBH * NCHUNK, 256, 0, stream>>>(target, source, top, part_O, part_m, part_s);
  convert_bf16_2<<<1024, 256, 0, stream>>>(W1, W2, w1b, w2b, DFF * DMODEL / 4);
  fuse_ln1<<<NROWS, 256, 0, stream>>>(target, part_O, part_m, part_s, sel, vmean,
                                      ln1_g, ln1_b, normed1, normed1b);
  {
    dim3 grid(DFF / 64, NROWS / 64);     // 32 x 64 = 2048 blocks
    gemm_mfma64<true, true><<<grid, 256, 0, stream>>>(normed1b, w1b, b1, h1b, DFF, DMODEL);
  }
  {
    dim3 grid(DMODEL / 64, NROWS / 64);  // 12 x 64 = 768 blocks
    gemm_mfma64<false, false><<<grid, 256, 0, stream>>>(h1b, w2b, b2, proj, DMODEL, DFF);
  }
  ln2_out<<<NROWS, 192, 0, stream>>>(normed1, proj, ln2_g, ln2_b, out);
}

// Round 19
// 148.858 us; speedup vs baseline: 6.6910x; 1.0869x over previous
//
#include <hip/hip_runtime.h>
#include <hip/hip_bf16.h>
#include <math.h>

#define L_SEQ 1024
#define BATCH 4
#define DMODEL 768
#define NH 8
#define DH 96
#define DFF 2048
#define U_TOP 35
#define NROWS (L_SEQ * BATCH)
#define NBH (BATCH * NH)
#define CHUNK 64
#define NCHUNK (L_SEQ / CHUNK)    // 16
#define VCH 64                    // vmean chunks per batch

typedef __attribute__((ext_vector_type(8))) short bf16x8;
typedef __attribute__((ext_vector_type(4))) float f32x4;

__device__ inline unsigned short f2bf(float f) {
  unsigned u = __float_as_uint(f);
  u += 0x7FFFu + ((u >> 16) & 1u);   // RNE
  return (unsigned short)(u >> 16);
}

// ---------------- Threefry-2x32 (exact JAX reproduction) ----------------
__device__ inline unsigned rotl32(unsigned v, int d) { return (v << d) | (v >> (32 - d)); }

__device__ inline void tf2x32(unsigned k0, unsigned k1, unsigned x0, unsigned x1,
                              unsigned& o0, unsigned& o1) {
  unsigned ks0 = k0, ks1 = k1, ks2 = k0 ^ k1 ^ 0x1BD11BDAu;
  x0 += ks0; x1 += ks1;
#define TFR(r) { x0 += x1; x1 = rotl32(x1, r); x1 ^= x0; }
  TFR(13) TFR(15) TFR(26) TFR(6)
  x0 += ks1; x1 += ks2 + 1u;
  TFR(17) TFR(29) TFR(16) TFR(24)
  x0 += ks2; x1 += ks0 + 2u;
  TFR(13) TFR(15) TFR(26) TFR(6)
  x0 += ks0; x1 += ks1 + 3u;
  TFR(17) TFR(29) TFR(16) TFR(24)
  x0 += ks1; x1 += ks2 + 4u;
  TFR(13) TFR(15) TFR(26) TFR(6)
  x0 += ks2; x1 += ks0 + 5u;
#undef TFR
  o0 = x0; o1 = x1;
}

// idx[j] = (w0^w1 of E(k2,(0,j))) & 1023, k2 = foldlike split(key(42))[1]
__device__ inline int jax_randint1024(int j) {
  unsigned k2a, k2b, o0, o1;
  tf2x32(0u, 42u, 0u, 1u, k2a, k2b);
  tf2x32(k2a, k2b, 0u, (unsigned)j, o0, o1);
  return (int)((o0 ^ o1) & 1023u);
}

// ---------------- PACK A: sample_scores (4096 blocks) + vmean_part (256 blocks) ----------------
__global__ __launch_bounds__(256) void sample_vmean(
    const float* __restrict__ target, const float* __restrict__ source,
    float* __restrict__ M, float* __restrict__ vpart) {
  int tid = threadIdx.x;
  if (blockIdx.x >= BATCH * L_SEQ) {
    // ---- vmean_part: blk in [0,256): b = blk>>6, c = blk&63; 16 rows each ----
    int blk = blockIdx.x - BATCH * L_SEQ;
    int b = blk >> 6, c = blk & (VCH - 1);
    int l0 = c * (L_SEQ / VCH);
#pragma unroll
    for (int k = 0; k < 3; ++k) {
      int d = tid + k * 256;
      float s = 0.f;
#pragma unroll
      for (int l = l0; l < l0 + L_SEQ / VCH; ++l)
        s += source[((size_t)l * BATCH + b) * DMODEL + d];
      vpart[(size_t)blk * DMODEL + d] = s;
    }
    return;
  }
  // ---- sample_scores (verified R14/R18) ----
  int orig = blockIdx.x;
  int blk = (orig & 7) * (BATCH * L_SEQ / 8) + (orig >> 3);   // bijective (4096 % 8 == 0)
  int l = blk & (L_SEQ - 1);
  int b = blk >> 10;
  __shared__ float qkbuf[NH][40];
  __shared__ int sidx[40];
  if (tid < 40) sidx[tid] = (tid < U_TOP) ? jax_randint1024(l * U_TOP + tid) : 0;
  int h = (tid >> 2) & 7, p = tid & 3;
  int s8 = tid >> 5;
  float4 qreg[6];
  {
    const float4* qg = (const float4*)(target + ((size_t)l * BATCH + b) * DMODEL + h * DH + p * 24);
#pragma unroll
    for (int j = 0; j < 6; ++j) qreg[j] = qg[j];
  }
  __syncthreads();
#pragma unroll
  for (int c = 0; c < 5; ++c) {
    int s = c * 8 + s8;
    if (s < U_TOP) {
      int kl = sidx[s];
      const float4* kg = (const float4*)(source + ((size_t)kl * BATCH + b) * DMODEL + h * DH + p * 24);
      float a = 0.f;
#pragma unroll
      for (int j = 0; j < 6; ++j) {
        float4 kv = kg[j];
        float4 qv = qreg[j];
        a += qv.x * kv.x + qv.y * kv.y + qv.z * kv.z + qv.w * kv.w;
      }
      a += __shfl_xor(a, 1, 64);
      a += __shfl_xor(a, 2, 64);
      if (p == 0) qkbuf[h][s] = a;
    }
  }
  __syncthreads();
  int w = tid >> 6, lane = tid & 63;
#pragma unroll
  for (int hi = 0; hi < 2; ++hi) {
    int hh = w * 2 + hi;
    float v = (lane < U_TOP) ? qkbuf[hh][lane] : -INFINITY;
    float sm = (lane < U_TOP) ? v : 0.f;
    float mx = v;
#pragma unroll
    for (int off = 32; off; off >>= 1) {
      mx = fmaxf(mx, __shfl_xor(mx, off, 64));
      sm += __shfl_xor(sm, off, 64);
    }
    if (lane == 0)
      M[(size_t)(b * NH + hh) * L_SEQ + l] = mx - sm * (1.f / U_TOP);
  }
}

// ---------------- PACK B: topk_sel (32 blocks) + vmean_comb (4 blocks) ----------------
__global__ __launch_bounds__(256) void topk_vmean(
    const float* __restrict__ M, int* __restrict__ top, int* __restrict__ sel,
    const float* __restrict__ vpart, float* __restrict__ vmean) {
  int tid = threadIdx.x;
  if (blockIdx.x >= NBH) {
    // ---- vmean_comb for b = blockIdx.x - NBH ----
    int b = blockIdx.x - NBH;
#pragma unroll
    for (int k = 0; k < 3; ++k) {
      int d = tid + k * 256;
      float s = 0.f;
      for (int c = 0; c < VCH; ++c) s += vpart[((size_t)(b * VCH + c)) * DMODEL + d];
      vmean[b * DMODEL + d] = s * (1.f / L_SEQ);
    }
    return;
  }
  // ---- topk_sel (verified R10) ----
  int bh = blockIdx.x;
  int lane = tid & 63, w = tid >> 6;
  __shared__ float wval[4];
  __shared__ int widx[4];
  __shared__ int bidx_sh;
  float v[4]; int ir[4];
#pragma unroll
  for (int i = 0; i < 4; ++i) {
    int ii = tid + i * 256;
    v[i] = M[(size_t)bh * L_SEQ + ii];
    ir[i] = ii;
    sel[(size_t)bh * L_SEQ + ii] = -1;
  }
  for (int it = 0; it < U_TOP; ++it) {
    float bv = v[0]; int bi = ir[0];
#pragma unroll
    for (int i = 1; i < 4; ++i)
      if (v[i] > bv || (v[i] == bv && ir[i] < bi)) { bv = v[i]; bi = ir[i]; }
#pragma unroll
    for (int off = 32; off; off >>= 1) {
      float ov = __shfl_xor(bv, off, 64);
      int oi = __shfl_xor(bi, off, 64);
      if (ov > bv || (ov == bv && oi < bi)) { bv = ov; bi = oi; }
    }
    if (lane == 0) { wval[w] = bv; widx[w] = bi; }
    __syncthreads();
    if (tid == 0) {
      float fv = wval[0]; int fi = widx[0];
#pragma unroll
      for (int k = 1; k < 4; ++k)
        if (wval[k] > fv || (wval[k] == fv && widx[k] < fi)) { fv = wval[k]; fi = widx[k]; }
      top[bh * U_TOP + it] = fi;
      sel[(size_t)bh * L_SEQ + fi] = it;
      bidx_sh = fi;
    }
    __syncthreads();
    int rb = bidx_sh;
    if ((rb & 255) == tid) v[rb >> 8] = -INFINITY;
  }
}

// ---------------- PACK C: attn_flash (512 blocks) + convert W1/W2 (1024 blocks) ----------------
__global__ __launch_bounds__(256) void attn_conv(
    const float* __restrict__ target, const float* __restrict__ source,
    const int* __restrict__ top,
    float* __restrict__ part_O, float* __restrict__ part_m, float* __restrict__ part_s,
    const float* __restrict__ W1, const float* __restrict__ W2,
    unsigned short* __restrict__ w1b, unsigned short* __restrict__ w2b) {
  __shared__ short Qb[48 * 104];     // Q (scaled), later P
  __shared__ short Kb[CHUNK * 104];
  __shared__ short Vt[96 * 72];
  __shared__ float sc[48 * 66];
  int tid = threadIdx.x;
  if (blockIdx.x >= NBH * NCHUNK) {
    // ---- convert: 1024 blocks grid-stride over both weight mats ----
    const int n4each = DFF * DMODEL / 4;
    int i = (blockIdx.x - NBH * NCHUNK) * 256 + tid;
    int stride = 1024 * 256;
    for (; i < 2 * n4each; i += stride) {
      const float* in = (i < n4each) ? W1 : W2;
      unsigned short* outp = (i < n4each) ? w1b : w2b;
      int k = (i < n4each) ? i : i - n4each;
      float4 v = ((const float4*)in)[k];
      unsigned long long pk = (unsigned long long)f2bf(v.x)
                            | ((unsigned long long)f2bf(v.y) << 16)
                            | ((unsigned long long)f2bf(v.z) << 32)
                            | ((unsigned long long)f2bf(v.w) << 48);
      ((unsigned long long*)outp)[k] = pk;
    }
    return;
  }
  // ---- attn_flash (verified R15) ----
  int blk = blockIdx.x;
  int chunk = blk & (NCHUNK - 1);
  int bh = blk >> 4;
  int h = bh & (NH - 1), b = bh >> 3;
  const float scale = 0.1020620726f;   // 1/sqrt(96)
  for (int i = tid; i < 13 * 104; i += 256) Qb[35 * 104 + i] = 0;
  for (int i = tid; i < U_TOP * 24; i += 256) {
    int u = i / 24, d4 = i - u * 24;
    int qpos = top[bh * U_TOP + u];
    float4 v = *(const float4*)(target + ((size_t)qpos * BATCH + b) * DMODEL + h * DH + d4 * 4);
    short* dst = Qb + u * 104 + d4 * 4;
    dst[0] = f2bf(v.x * scale); dst[1] = f2bf(v.y * scale);
    dst[2] = f2bf(v.z * scale); dst[3] = f2bf(v.w * scale);
  }
  int l0 = chunk * CHUNK;
  for (int i = tid; i < CHUNK * 24; i += 256) {
    int r = i / 24, d4 = i - r * 24;
    float4 v = *(const float4*)(source + ((size_t)(l0 + r) * BATCH + b) * DMODEL + h * DH + d4 * 4);
    short* dst = Kb + r * 104 + d4 * 4;
    dst[0] = f2bf(v.x); dst[1] = f2bf(v.y); dst[2] = f2bf(v.z); dst[3] = f2bf(v.w);
  }
  __syncthreads();
  for (int i = tid; i < CHUNK * 24; i += 256) {
    int r = i & (CHUNK - 1), d4 = i >> 6;
    const short* srcp = Kb + r * 104 + d4 * 4;
#pragma unroll
    for (int cc = 0; cc < 4; ++cc) Vt[(d4 * 4 + cc) * 72 + r] = srcp[cc];
  }
  int wv = tid >> 6, lane = tid & 63;
  int lr = lane & 15, lg = lane >> 4;
  __syncthreads();
  {
    int n = wv;
#pragma unroll
    for (int m = 0; m < 3; ++m) {
      f32x4 acc = {};
#pragma unroll
      for (int kc = 0; kc < 3; ++kc) {
        bf16x8 a = *(const bf16x8*)(Qb + (m * 16 + lr) * 104 + kc * 32 + lg * 8);
        bf16x8 bb = *(const bf16x8*)(Kb + (n * 16 + lr) * 104 + kc * 32 + lg * 8);
        acc = __builtin_amdgcn_mfma_f32_16x16x32_bf16(a, bb, acc, 0, 0, 0);
      }
#pragma unroll
      for (int j = 0; j < 4; ++j)
        sc[(m * 16 + lg * 4 + j) * 66 + n * 16 + lr] = acc[j];
    }
  }
  __syncthreads();
#pragma unroll
  for (int i = 0; i < 9; ++i) {
    int u = wv + 4 * i;
    if (u < U_TOP) {
      float s = sc[u * 66 + lane];
      float mx = s;
#pragma unroll
      for (int off = 32; off; off >>= 1) mx = fmaxf(mx, __shfl_xor(mx, off, 64));
      float pp = expf(s - mx);
      float sm = pp;
#pragma unroll
      for (int off = 32; off; off >>= 1) sm += __shfl_xor(sm, off, 64);
      Qb[u * 104 + lane] = f2bf(pp);
      if (lane == 0) {
        part_m[blk * U_TOP + u] = mx;
        part_s[blk * U_TOP + u] = sm;
      }
    }
  }
  __syncthreads();
  for (int t = wv; t < 18; t += 4) {
    int m = t / 6, n = t - (t / 6) * 6;
    f32x4 acc = {};
#pragma unroll
    for (int kc = 0; kc < 2; ++kc) {
      bf16x8 a = *(const bf16x8*)(Qb + (m * 16 + lr) * 104 + kc * 32 + lg * 8);
      bf16x8 bb = *(const bf16x8*)(Vt + (n * 16 + lr) * 72 + kc * 32 + lg * 8);
      acc = __builtin_amdgcn_mfma_f32_16x16x32_bf16(a, bb, acc, 0, 0, 0);
    }
#pragma unroll
    for (int j = 0; j < 4; ++j) {
      int u = m * 16 + lg * 4 + j;
      if (u < U_TOP)
        part_O[(size_t)blk * U_TOP * DH + u * DH + n * 16 + lr] = acc[j];
    }
  }
}

// ---------------- combine + residual + LN1 -> normed1 (verified R18) ----------------
__global__ __launch_bounds__(256) void fuse_ln1(
    const float* __restrict__ target, const float* __restrict__ part_O,
    const float* __restrict__ part_m, const float* __restrict__ part_s,
    const int* __restrict__ sel, const float* __restrict__ vmean,
    const float* __restrict__ g, const float* __restrict__ bb,
    float* __restrict__ normed1, unsigned short* __restrict__ normed1b) {
  int r = blockIdx.x;              // r = l*BATCH + b
  int l = r >> 2, b = r & 3;
  __shared__ float wgt[NH][NCHUNK];
  __shared__ float sinv[NH];
  __shared__ int uarr[NH];
  __shared__ float x[DMODEL];
  __shared__ float red[256];
  int tid = threadIdx.x;
  if (tid < NH) uarr[tid] = sel[((size_t)(b * NH + tid)) * L_SEQ + l];
  __syncthreads();
  if (tid < NH * NCHUNK) {           // threads 0..127: (h = tid>>4, c = tid&15)
    int h = tid >> 4, c = tid & 15;
    int u = uarr[h];
    if (u >= 0) {
      int bh = b * NH + h;
      float pm = part_m[(bh * NCHUNK + c) * U_TOP + u];
      float mx = pm;
#pragma unroll
      for (int off = 1; off < 16; off <<= 1) mx = fmaxf(mx, __shfl_xor(mx, off, 64));
      float wv = expf(pm - mx);
      float sv = wv * part_s[(bh * NCHUNK + c) * U_TOP + u];
#pragma unroll
      for (int off = 1; off < 16; off <<= 1) sv += __shfl_xor(sv, off, 64);
      wgt[h][c] = wv;
      if (c == 0) sinv[h] = 1.f / sv;
    }
  }
  __syncthreads();
  for (int d = tid; d < DMODEL; d += 256) {
    int h = d / DH;
    int u = uarr[h];
    float a;
    if (u >= 0) {
      int bh = b * NH + h;
      int dd = d - h * DH;
      float acc = 0.f;
#pragma unroll
      for (int c = 0; c < NCHUNK; ++c)
        acc += wgt[h][c] * part_O[((size_t)(bh * NCHUNK + c) * U_TOP + u) * DH + dd];
      a = acc * sinv[h];
    } else {
      a = vmean[b * DMODEL + d];
    }
    x[d] = target[(size_t)r * DMODEL + d] + a;
  }
  __syncthreads();
  float partial = 0.f;
  for (int d = tid; d < DMODEL; d += 256) partial += x[d];
  red[tid] = partial; __syncthreads();
  for (int s = 128; s; s >>= 1) { if (tid < s) red[tid] += red[tid + s]; __syncthreads(); }
  float mu = red[0] * (1.f / DMODEL);
  __syncthreads();
  partial = 0.f;
  for (int d = tid; d < DMODEL; d += 256) { float t = x[d] - mu; partial += t * t; }
  red[tid] = partial; __syncthreads();
  for (int s = 128; s; s >>= 1) { if (tid < s) red[tid] += red[tid + s]; __syncthreads(); }
  float rstd = 1.0f / sqrtf(red[0] * (1.f / DMODEL) + 1e-5f);
  for (int d = tid; d < DMODEL; d += 256) {
    float v = (x[d] - mu) * rstd * g[d] + bb[d];
    normed1[(size_t)r * DMODEL + d] = v;
    normed1b[(size_t)r * DMODEL + d] = f2bf(v);
  }
}

// ---------------- bf16 MFMA GEMM, 64x64 tile + XCD-chunked swizzle (1D grid) ----------------
template <bool RELU, bool BF16OUT>
__global__ __launch_bounds__(256) void gemm_mfma64(
    const unsigned short* __restrict__ A, const unsigned short* __restrict__ B,
    const float* __restrict__ bias, void* __restrict__ Cout,
    int Ndim, int Kdim, int GX) {
  __shared__ short As[64 * 64];
  __shared__ short Bs[64 * 64];
  int tid = threadIdx.x;
  int lane = tid & 63;
  int wid = tid >> 6;
  int wm = wid >> 1, wn = wid & 1;       // 2x2 waves, each 32x32
  // XCD-chunked bijective swizzle (nwg % 8 == 0): each XCD gets a contiguous
  // flat range -> contiguous row panels -> A panel L2-resident per XCD.
  int nwg = gridDim.x;
  int flat = (blockIdx.x & 7) * (nwg >> 3) + (blockIdx.x >> 3);
  int bx = flat % GX, by = flat / GX;
  int bm = by * 64, bn = bx * 64;

  f32x4 acc[2][2] = {};

  for (int k0 = 0; k0 < Kdim; k0 += 64) {
#pragma unroll
    for (int i = 0; i < 2; ++i) {
      int trow = wid * 16 + i * 8 + (lane >> 3);
      int slot = (lane & 7) ^ (trow & 7);          // pre-swizzled global source
      const unsigned short* ga = A + (size_t)(bm + trow) * Kdim + k0 + slot * 8;
      const unsigned short* gb = B + (size_t)(bn + trow) * Kdim + k0 + slot * 8;
      __builtin_amdgcn_global_load_lds(
          (const __attribute__((address_space(1))) void*)ga,
          (__attribute__((address_space(3))) void*)(As + (wid * 16 + i * 8) * 64),
          16, 0, 0);
      __builtin_amdgcn_global_load_lds(
          (const __attribute__((address_space(1))) void*)gb,
          (__attribute__((address_space(3))) void*)(Bs + (wid * 16 + i * 8) * 64),
          16, 0, 0);
    }
    __syncthreads();
#pragma unroll
    for (int c = 0; c < 2; ++c) {
      bf16x8 af[2], bf[2];
#pragma unroll
      for (int mi = 0; mi < 2; ++mi) {
        int row = wm * 32 + mi * 16 + (lane & 15);
        int phys = (c * 4 + (lane >> 4)) ^ (row & 7);
        af[mi] = *(const bf16x8*)(As + row * 64 + phys * 8);
      }
#pragma unroll
      for (int ni = 0; ni < 2; ++ni) {
        int row = wn * 32 + ni * 16 + (lane & 15);
        int phys = (c * 4 + (lane >> 4)) ^ (row & 7);
        bf[ni] = *(const bf16x8*)(Bs + row * 64 + phys * 8);
      }
#pragma unroll
      for (int mi = 0; mi < 2; ++mi)
#pragma unroll
        for (int ni = 0; ni < 2; ++ni)
          acc[mi][ni] = __builtin_amdgcn_mfma_f32_16x16x32_bf16(af[mi], bf[ni], acc[mi][ni], 0, 0, 0);
    }
    __syncthreads();
  }

#pragma unroll
  for (int mi = 0; mi < 2; ++mi)
#pragma unroll
    for (int ni = 0; ni < 2; ++ni) {
      int col = bn + wn * 32 + ni * 16 + (lane & 15);
      float bv = bias[col];
#pragma unroll
      for (int j = 0; j < 4; ++j) {
        int row = bm + wm * 32 + mi * 16 + (lane >> 4) * 4 + j;
        float v = acc[mi][ni][j] + bv;
        if (RELU) v = fmaxf(v, 0.f);
        if (BF16OUT)
          ((unsigned short*)Cout)[(size_t)row * Ndim + col] = f2bf(v);
        else
          ((float*)Cout)[(size_t)row * Ndim + col] = v;
      }
    }
}

// ---------------- normed1 + proj -> LN2 -> out (verified R9) ----------------
__global__ __launch_bounds__(192) void ln2_out(
    const float* __restrict__ normed1, const float* __restrict__ proj,
    const float* __restrict__ g, const float* __restrict__ bb,
    float* __restrict__ out) {
  int r = blockIdx.x;
  int tid = threadIdx.x;           // 192 threads x float4 = 768
  __shared__ float red[6];
  float4 a = ((const float4*)(normed1 + (size_t)r * DMODEL))[tid];
  float4 p = ((const float4*)(proj + (size_t)r * DMODEL))[tid];
  float4 x = {a.x + p.x, a.y + p.y, a.z + p.z, a.w + p.w};
  float s1 = x.x + x.y + x.z + x.w;
  float s2 = x.x * x.x + x.y * x.y + x.z * x.z + x.w * x.w;
#pragma unroll
  for (int off = 32; off; off >>= 1) {
    s1 += __shfl_xor(s1, off, 64);
    s2 += __shfl_xor(s2, off, 64);
  }
  int w = tid >> 6;
  if ((tid & 63) == 0) { red[w] = s1; red[3 + w] = s2; }
  __syncthreads();
  float S1 = red[0] + red[1] + red[2];
  float S2 = red[3] + red[4] + red[5];
  float mu = S1 * (1.f / DMODEL);
  float var = S2 * (1.f / DMODEL) - mu * mu;
  float rstd = 1.0f / sqrtf(var + 1e-5f);
  float4 gv = ((const float4*)g)[tid];
  float4 bv = ((const float4*)bb)[tid];
  float4 o = {(x.x - mu) * rstd * gv.x + bv.x, (x.y - mu) * rstd * gv.y + bv.y,
              (x.z - mu) * rstd * gv.z + bv.z, (x.w - mu) * rstd * gv.w + bv.w};
  ((float4*)(out + (size_t)r * DMODEL))[tid] = o;
}

extern "C" void kernel_launch(void* const* d_in, const int* in_sizes, int n_in,
                              void* d_out, int out_size, void* d_ws, size_t ws_size,
                              hipStream_t stream) {
  const float* target = (const float*)d_in[0];
  const float* source = (const float*)d_in[1];
  const float* W1 = (const float*)d_in[2];
  const float* b1 = (const float*)d_in[3];
  const float* W2 = (const float*)d_in[4];
  const float* b2 = (const float*)d_in[5];
  const float* ln1_g = (const float*)d_in[6];
  const float* ln1_b = (const float*)d_in[7];
  const float* ln2_g = (const float*)d_in[8];
  const float* ln2_b = (const float*)d_in[9];
  float* out = (float*)d_out;

  char* ws = (char*)d_ws;
  float*          M        = (float*)         (ws + 0x0040000);  // 128 KB
  int*            top      = (int*)           (ws + 0x0080000);  // 4.4 KB
  int*            sel      = (int*)           (ws + 0x0090000);  // 128 KB
  float*          vmean    = (float*)         (ws + 0x0130000);  // 12 KB
  float*          part_m   = (float*)         (ws + 0x0140000);  // 72 KB
  float*          part_s   = (float*)         (ws + 0x0160000);  // 72 KB
  unsigned short* w1b      = (unsigned short*)(ws + 0x0180000);  // 3 MB
  unsigned short* w2b      = (unsigned short*)(ws + 0x0480000);  // 3 MB
  unsigned short* normed1b = (unsigned short*)(ws + 0x0780000);  // 6 MB
  float*          normed1  = (float*)         (ws + 0x0D80000);  // 12 MB
  unsigned short* h1b      = (unsigned short*)(ws + 0x1980000);  // 16 MB region
  float*          part_O   = (float*)         (ws + 0x1980000);  // 6.9 MB, aliases h1b (dead before gemm1)
  float*          vpart    = (float*)         (ws + 0x2200000);  // 786 KB, aliases h1b (dead before gemm1)
  float*          proj     = (float*)         (ws + 0x2980000);  // 12 MB -> ends 0x3580000 (56 MB)

  sample_vmean<<<BATCH * L_SEQ + BATCH * VCH, 256, 0, stream>>>(target, source, M, vpart);
  topk_vmean<<<NBH + BATCH, 256, 0, stream>>>(M, top, sel, vpart, vmean);
  attn_conv<<<NBH * NCHUNK + 1024, 256, 0, stream>>>(target, source, top,
                                                     part_O, part_m, part_s,
                                                     W1, W2, w1b, w2b);
  fuse_ln1<<<NROWS, 256, 0, stream>>>(target, part_O, part_m, part_s, sel, vmean,
                                      ln1_g, ln1_b, normed1, normed1b);
  gemm_mfma64<true, true><<<(DFF / 64) * (NROWS / 64), 256, 0, stream>>>(
      normed1b, w1b, b1, h1b, DFF, DMODEL, DFF / 64);        // 2048 blocks
  gemm_mfma64<false, false><<<(DMODEL / 64) * (NROWS / 64), 256, 0, stream>>>(
      h1b, w2b, b2, proj, DMODEL, DFF, DMODEL / 64);         // 768 blocks
  ln2_out<<<NROWS, 192, 0, stream>>>(normed1, proj, ln2_g, ln2_b, out);
}

// Round 21
// 146.299 us; speedup vs baseline: 6.8080x; 1.0175x over previous
//
#include <hip/hip_runtime.h>
#include <hip/hip_bf16.h>
#include <math.h>

#define L_SEQ 1024
#define BATCH 4
#define DMODEL 768
#define NH 8
#define DH 96
#define DFF 2048
#define U_TOP 35
#define NROWS (L_SEQ * BATCH)
#define NBH (BATCH * NH)
#define CHUNK 64
#define NCHUNK (L_SEQ / CHUNK)    // 16
#define VCH 64                    // vmean chunks per batch

typedef __attribute__((ext_vector_type(8))) short bf16x8;
typedef __attribute__((ext_vector_type(4))) float f32x4;

__device__ inline unsigned short f2bf(float f) {
  unsigned u = __float_as_uint(f);
  u += 0x7FFFu + ((u >> 16) & 1u);   // RNE
  return (unsigned short)(u >> 16);
}
__device__ inline float bf2f(unsigned short v) {
  return __uint_as_float((unsigned)v << 16);
}

// ---------------- Threefry-2x32 (exact JAX reproduction) ----------------
__device__ inline unsigned rotl32(unsigned v, int d) { return (v << d) | (v >> (32 - d)); }

__device__ inline void tf2x32(unsigned k0, unsigned k1, unsigned x0, unsigned x1,
                              unsigned& o0, unsigned& o1) {
  unsigned ks0 = k0, ks1 = k1, ks2 = k0 ^ k1 ^ 0x1BD11BDAu;
  x0 += ks0; x1 += ks1;
#define TFR(r) { x0 += x1; x1 = rotl32(x1, r); x1 ^= x0; }
  TFR(13) TFR(15) TFR(26) TFR(6)
  x0 += ks1; x1 += ks2 + 1u;
  TFR(17) TFR(29) TFR(16) TFR(24)
  x0 += ks2; x1 += ks0 + 2u;
  TFR(13) TFR(15) TFR(26) TFR(6)
  x0 += ks0; x1 += ks1 + 3u;
  TFR(17) TFR(29) TFR(16) TFR(24)
  x0 += ks1; x1 += ks2 + 4u;
  TFR(13) TFR(15) TFR(26) TFR(6)
  x0 += ks2; x1 += ks0 + 5u;
#undef TFR
  o0 = x0; o1 = x1;
}

// idx[j] = (w0^w1 of E(k2,(0,j))) & 1023, k2 = foldlike split(key(42))[1]
__device__ inline int jax_randint1024(int j) {
  unsigned k2a, k2b, o0, o1;
  tf2x32(0u, 42u, 0u, 1u, k2a, k2b);
  tf2x32(k2a, k2b, 0u, (unsigned)j, o0, o1);
  return (int)((o0 ^ o1) & 1023u);
}

// ---------------- PACK A: sample_scores (4096 blocks) + vmean_part (256 blocks) ----------------
__global__ __launch_bounds__(256) void sample_vmean(
    const float* __restrict__ target, const float* __restrict__ source,
    float* __restrict__ M, float* __restrict__ vpart) {
  int tid = threadIdx.x;
  if (blockIdx.x >= BATCH * L_SEQ) {
    int blk = blockIdx.x - BATCH * L_SEQ;
    int b = blk >> 6, c = blk & (VCH - 1);
    int l0 = c * (L_SEQ / VCH);
#pragma unroll
    for (int k = 0; k < 3; ++k) {
      int d = tid + k * 256;
      float s = 0.f;
#pragma unroll
      for (int l = l0; l < l0 + L_SEQ / VCH; ++l)
        s += source[((size_t)l * BATCH + b) * DMODEL + d];
      vpart[(size_t)blk * DMODEL + d] = s;
    }
    return;
  }
  int orig = blockIdx.x;
  int blk = (orig & 7) * (BATCH * L_SEQ / 8) + (orig >> 3);   // bijective (4096 % 8 == 0)
  int l = blk & (L_SEQ - 1);
  int b = blk >> 10;
  __shared__ float qkbuf[NH][40];
  __shared__ int sidx[40];
  if (tid < 40) sidx[tid] = (tid < U_TOP) ? jax_randint1024(l * U_TOP + tid) : 0;
  int h = (tid >> 2) & 7, p = tid & 3;
  int s8 = tid >> 5;
  float4 qreg[6];
  {
    const float4* qg = (const float4*)(target + ((size_t)l * BATCH + b) * DMODEL + h * DH + p * 24);
#pragma unroll
    for (int j = 0; j < 6; ++j) qreg[j] = qg[j];
  }
  __syncthreads();
#pragma unroll
  for (int c = 0; c < 5; ++c) {
    int s = c * 8 + s8;
    if (s < U_TOP) {
      int kl = sidx[s];
      const float4* kg = (const float4*)(source + ((size_t)kl * BATCH + b) * DMODEL + h * DH + p * 24);
      float a = 0.f;
#pragma unroll
      for (int j = 0; j < 6; ++j) {
        float4 kv = kg[j];
        float4 qv = qreg[j];
        a += qv.x * kv.x + qv.y * kv.y + qv.z * kv.z + qv.w * kv.w;
      }
      a += __shfl_xor(a, 1, 64);
      a += __shfl_xor(a, 2, 64);
      if (p == 0) qkbuf[h][s] = a;
    }
  }
  __syncthreads();
  int w = tid >> 6, lane = tid & 63;
#pragma unroll
  for (int hi = 0; hi < 2; ++hi) {
    int hh = w * 2 + hi;
    float v = (lane < U_TOP) ? qkbuf[hh][lane] : -INFINITY;
    float sm = (lane < U_TOP) ? v : 0.f;
    float mx = v;
#pragma unroll
    for (int off = 32; off; off >>= 1) {
      mx = fmaxf(mx, __shfl_xor(mx, off, 64));
      sm += __shfl_xor(sm, off, 64);
    }
    if (lane == 0)
      M[(size_t)(b * NH + hh) * L_SEQ + l] = mx - sm * (1.f / U_TOP);
  }
}

// ---------------- PACK B: topk_sel (32 blocks) + vmean_comb (4 blocks) ----------------
__global__ __launch_bounds__(256) void topk_vmean(
    const float* __restrict__ M, int* __restrict__ top, int* __restrict__ sel,
    const float* __restrict__ vpart, float* __restrict__ vmean) {
  int tid = threadIdx.x;
  if (blockIdx.x >= NBH) {
    int b = blockIdx.x - NBH;
#pragma unroll
    for (int k = 0; k < 3; ++k) {
      int d = tid + k * 256;
      float s = 0.f;
      for (int c = 0; c < VCH; ++c) s += vpart[((size_t)(b * VCH + c)) * DMODEL + d];
      vmean[b * DMODEL + d] = s * (1.f / L_SEQ);
    }
    return;
  }
  int bh = blockIdx.x;
  int lane = tid & 63, w = tid >> 6;
  __shared__ float wval[4];
  __shared__ int widx[4];
  __shared__ int bidx_sh;
  float v[4]; int ir[4];
#pragma unroll
  for (int i = 0; i < 4; ++i) {
    int ii = tid + i * 256;
    v[i] = M[(size_t)bh * L_SEQ + ii];
    ir[i] = ii;
    sel[(size_t)bh * L_SEQ + ii] = -1;
  }
  for (int it = 0; it < U_TOP; ++it) {
    float bv = v[0]; int bi = ir[0];
#pragma unroll
    for (int i = 1; i < 4; ++i)
      if (v[i] > bv || (v[i] == bv && ir[i] < bi)) { bv = v[i]; bi = ir[i]; }
#pragma unroll
    for (int off = 32; off; off >>= 1) {
      float ov = __shfl_xor(bv, off, 64);
      int oi = __shfl_xor(bi, off, 64);
      if (ov > bv || (ov == bv && oi < bi)) { bv = ov; bi = oi; }
    }
    if (lane == 0) { wval[w] = bv; widx[w] = bi; }
    __syncthreads();
    if (tid == 0) {
      float fv = wval[0]; int fi = widx[0];
#pragma unroll
      for (int k = 1; k < 4; ++k)
        if (wval[k] > fv || (wval[k] == fv && widx[k] < fi)) { fv = wval[k]; fi = widx[k]; }
      top[bh * U_TOP + it] = fi;
      sel[(size_t)bh * L_SEQ + fi] = it;
      bidx_sh = fi;
    }
    __syncthreads();
    int rb = bidx_sh;
    if ((rb & 255) == tid) v[rb >> 8] = -INFINITY;
  }
}

// ---------------- PACK C: attn_flash (512 blocks) + convert W1/W2 (1024 blocks) ----------------
__global__ __launch_bounds__(256) void attn_conv(
    const float* __restrict__ target, const float* __restrict__ source,
    const int* __restrict__ top,
    float* __restrict__ part_O, float* __restrict__ part_m, float* __restrict__ part_s,
    const float* __restrict__ W1, const float* __restrict__ W2,
    unsigned short* __restrict__ w1b, unsigned short* __restrict__ w2b) {
  __shared__ short Qb[48 * 104];     // Q (scaled), later P
  __shared__ short Kb[CHUNK * 104];
  __shared__ short Vt[96 * 72];
  __shared__ float sc[48 * 66];
  int tid = threadIdx.x;
  if (blockIdx.x >= NBH * NCHUNK) {
    const int n4each = DFF * DMODEL / 4;
    int i = (blockIdx.x - NBH * NCHUNK) * 256 + tid;
    int stride = 1024 * 256;
    for (; i < 2 * n4each; i += stride) {
      const float* in = (i < n4each) ? W1 : W2;
      unsigned short* outp = (i < n4each) ? w1b : w2b;
      int k = (i < n4each) ? i : i - n4each;
      float4 v = ((const float4*)in)[k];
      unsigned long long pk = (unsigned long long)f2bf(v.x)
                            | ((unsigned long long)f2bf(v.y) << 16)
                            | ((unsigned long long)f2bf(v.z) << 32)
                            | ((unsigned long long)f2bf(v.w) << 48);
      ((unsigned long long*)outp)[k] = pk;
    }
    return;
  }
  int blk = blockIdx.x;
  int chunk = blk & (NCHUNK - 1);
  int bh = blk >> 4;
  int h = bh & (NH - 1), b = bh >> 3;
  const float scale = 0.1020620726f;   // 1/sqrt(96)
  for (int i = tid; i < 13 * 104; i += 256) Qb[35 * 104 + i] = 0;
  for (int i = tid; i < U_TOP * 24; i += 256) {
    int u = i / 24, d4 = i - u * 24;
    int qpos = top[bh * U_TOP + u];
    float4 v = *(const float4*)(target + ((size_t)qpos * BATCH + b) * DMODEL + h * DH + d4 * 4);
    short* dst = Qb + u * 104 + d4 * 4;
    dst[0] = f2bf(v.x * scale); dst[1] = f2bf(v.y * scale);
    dst[2] = f2bf(v.z * scale); dst[3] = f2bf(v.w * scale);
  }
  int l0 = chunk * CHUNK;
  for (int i = tid; i < CHUNK * 24; i += 256) {
    int r = i / 24, d4 = i - r * 24;
    float4 v = *(const float4*)(source + ((size_t)(l0 + r) * BATCH + b) * DMODEL + h * DH + d4 * 4);
    short* dst = Kb + r * 104 + d4 * 4;
    dst[0] = f2bf(v.x); dst[1] = f2bf(v.y); dst[2] = f2bf(v.z); dst[3] = f2bf(v.w);
  }
  __syncthreads();
  for (int i = tid; i < CHUNK * 24; i += 256) {
    int r = i & (CHUNK - 1), d4 = i >> 6;
    const short* srcp = Kb + r * 104 + d4 * 4;
#pragma unroll
    for (int cc = 0; cc < 4; ++cc) Vt[(d4 * 4 + cc) * 72 + r] = srcp[cc];
  }
  int wv = tid >> 6, lane = tid & 63;
  int lr = lane & 15, lg = lane >> 4;
  __syncthreads();
  {
    int n = wv;
#pragma unroll
    for (int m = 0; m < 3; ++m) {
      f32x4 acc = {};
#pragma unroll
      for (int kc = 0; kc < 3; ++kc) {
        bf16x8 a = *(const bf16x8*)(Qb + (m * 16 + lr) * 104 + kc * 32 + lg * 8);
        bf16x8 bb = *(const bf16x8*)(Kb + (n * 16 + lr) * 104 + kc * 32 + lg * 8);
        acc = __builtin_amdgcn_mfma_f32_16x16x32_bf16(a, bb, acc, 0, 0, 0);
      }
#pragma unroll
      for (int j = 0; j < 4; ++j)
        sc[(m * 16 + lg * 4 + j) * 66 + n * 16 + lr] = acc[j];
    }
  }
  __syncthreads();
#pragma unroll
  for (int i = 0; i < 9; ++i) {
    int u = wv + 4 * i;
    if (u < U_TOP) {
      float s = sc[u * 66 + lane];
      float mx = s;
#pragma unroll
      for (int off = 32; off; off >>= 1) mx = fmaxf(mx, __shfl_xor(mx, off, 64));
      float pp = expf(s - mx);
      float sm = pp;
#pragma unroll
      for (int off = 32; off; off >>= 1) sm += __shfl_xor(sm, off, 64);
      Qb[u * 104 + lane] = f2bf(pp);
      if (lane == 0) {
        part_m[blk * U_TOP + u] = mx;
        part_s[blk * U_TOP + u] = sm;
      }
    }
  }
  __syncthreads();
  for (int t = wv; t < 18; t += 4) {
    int m = t / 6, n = t - (t / 6) * 6;
    f32x4 acc = {};
#pragma unroll
    for (int kc = 0; kc < 2; ++kc) {
      bf16x8 a = *(const bf16x8*)(Qb + (m * 16 + lr) * 104 + kc * 32 + lg * 8);
      bf16x8 bb = *(const bf16x8*)(Vt + (n * 16 + lr) * 72 + kc * 32 + lg * 8);
      acc = __builtin_amdgcn_mfma_f32_16x16x32_bf16(a, bb, acc, 0, 0, 0);
    }
#pragma unroll
    for (int j = 0; j < 4; ++j) {
      int u = m * 16 + lg * 4 + j;
      if (u < U_TOP)
        part_O[(size_t)blk * U_TOP * DH + u * DH + n * 16 + lr] = acc[j];
    }
  }
}

// ---------------- combine + residual + LN1 -> normed1b (bf16 only) ----------------
__global__ __launch_bounds__(256) void fuse_ln1(
    const float* __restrict__ target, const float* __restrict__ part_O,
    const float* __restrict__ part_m, const float* __restrict__ part_s,
    const int* __restrict__ sel, const float* __restrict__ vmean,
    const float* __restrict__ g, const float* __restrict__ bb,
    unsigned short* __restrict__ normed1b) {
  int r = blockIdx.x;              // r = l*BATCH + b
  int l = r >> 2, b = r & 3;
  __shared__ float wgt[NH][NCHUNK];
  __shared__ float sinv[NH];
  __shared__ int uarr[NH];
  __shared__ float x[DMODEL];
  __shared__ float red[256];
  int tid = threadIdx.x;
  if (tid < NH) uarr[tid] = sel[((size_t)(b * NH + tid)) * L_SEQ + l];
  __syncthreads();
  if (tid < NH * NCHUNK) {           // threads 0..127: (h = tid>>4, c = tid&15)
    int h = tid >> 4, c = tid & 15;
    int u = uarr[h];
    if (u >= 0) {
      int bh = b * NH + h;
      float pm = part_m[(bh * NCHUNK + c) * U_TOP + u];
      float mx = pm;
#pragma unroll
      for (int off = 1; off < 16; off <<= 1) mx = fmaxf(mx, __shfl_xor(mx, off, 64));
      float wv = expf(pm - mx);
      float sv = wv * part_s[(bh * NCHUNK + c) * U_TOP + u];
#pragma unroll
      for (int off = 1; off < 16; off <<= 1) sv += __shfl_xor(sv, off, 64);
      wgt[h][c] = wv;
      if (c == 0) sinv[h] = 1.f / sv;
    }
  }
  __syncthreads();
  for (int d = tid; d < DMODEL; d += 256) {
    int h = d / DH;
    int u = uarr[h];
    float a;
    if (u >= 0) {
      int bh = b * NH + h;
      int dd = d - h * DH;
      float acc = 0.f;
#pragma unroll
      for (int c = 0; c < NCHUNK; ++c)
        acc += wgt[h][c] * part_O[((size_t)(bh * NCHUNK + c) * U_TOP + u) * DH + dd];
      a = acc * sinv[h];
    } else {
      a = vmean[b * DMODEL + d];
    }
    x[d] = target[(size_t)r * DMODEL + d] + a;
  }
  __syncthreads();
  float partial = 0.f;
  for (int d = tid; d < DMODEL; d += 256) partial += x[d];
  red[tid] = partial; __syncthreads();
  for (int s = 128; s; s >>= 1) { if (tid < s) red[tid] += red[tid + s]; __syncthreads(); }
  float mu = red[0] * (1.f / DMODEL);
  __syncthreads();
  partial = 0.f;
  for (int d = tid; d < DMODEL; d += 256) { float t = x[d] - mu; partial += t * t; }
  red[tid] = partial; __syncthreads();
  for (int s = 128; s; s >>= 1) { if (tid < s) red[tid] += red[tid + s]; __syncthreads(); }
  float rstd = 1.0f / sqrtf(red[0] * (1.f / DMODEL) + 1e-5f);
  for (int d = tid; d < DMODEL; d += 256) {
    float v = (x[d] - mu) * rstd * g[d] + bb[d];
    normed1b[(size_t)r * DMODEL + d] = f2bf(v);
  }
}

// ---------------- bf16 MFMA GEMM, 64x64 tile + XCD-chunked swizzle (verified R19) ----------------
template <bool RELU, bool BF16OUT>
__global__ __launch_bounds__(256) void gemm_mfma64(
    const unsigned short* __restrict__ A, const unsigned short* __restrict__ B,
    const float* __restrict__ bias, void* __restrict__ Cout,
    int Ndim, int Kdim, int GX) {
  __shared__ short As[64 * 64];
  __shared__ short Bs[64 * 64];
  int tid = threadIdx.x;
  int lane = tid & 63;
  int wid = tid >> 6;
  int wm = wid >> 1, wn = wid & 1;       // 2x2 waves, each 32x32
  int nwg = gridDim.x;
  int flat = (blockIdx.x & 7) * (nwg >> 3) + (blockIdx.x >> 3);
  int bx = flat % GX, by = flat / GX;
  int bm = by * 64, bn = bx * 64;

  f32x4 acc[2][2] = {};

  for (int k0 = 0; k0 < Kdim; k0 += 64) {
#pragma unroll
    for (int i = 0; i < 2; ++i) {
      int trow = wid * 16 + i * 8 + (lane >> 3);
      int slot = (lane & 7) ^ (trow & 7);          // pre-swizzled global source
      const unsigned short* ga = A + (size_t)(bm + trow) * Kdim + k0 + slot * 8;
      const unsigned short* gb = B + (size_t)(bn + trow) * Kdim + k0 + slot * 8;
      __builtin_amdgcn_global_load_lds(
          (const __attribute__((address_space(1))) void*)ga,
          (__attribute__((address_space(3))) void*)(As + (wid * 16 + i * 8) * 64),
          16, 0, 0);
      __builtin_amdgcn_global_load_lds(
          (const __attribute__((address_space(1))) void*)gb,
          (__attribute__((address_space(3))) void*)(Bs + (wid * 16 + i * 8) * 64),
          16, 0, 0);
    }
    __syncthreads();
#pragma unroll
    for (int c = 0; c < 2; ++c) {
      bf16x8 af[2], bf[2];
#pragma unroll
      for (int mi = 0; mi < 2; ++mi) {
        int row = wm * 32 + mi * 16 + (lane & 15);
        int phys = (c * 4 + (lane >> 4)) ^ (row & 7);
        af[mi] = *(const bf16x8*)(As + row * 64 + phys * 8);
      }
#pragma unroll
      for (int ni = 0; ni < 2; ++ni) {
        int row = wn * 32 + ni * 16 + (lane & 15);
        int phys = (c * 4 + (lane >> 4)) ^ (row & 7);
        bf[ni] = *(const bf16x8*)(Bs + row * 64 + phys * 8);
      }
#pragma unroll
      for (int mi = 0; mi < 2; ++mi)
#pragma unroll
        for (int ni = 0; ni < 2; ++ni)
          acc[mi][ni] = __builtin_amdgcn_mfma_f32_16x16x32_bf16(af[mi], bf[ni], acc[mi][ni], 0, 0, 0);
    }
    __syncthreads();
  }

#pragma unroll
  for (int mi = 0; mi < 2; ++mi)
#pragma unroll
    for (int ni = 0; ni < 2; ++ni) {
      int col = bn + wn * 32 + ni * 16 + (lane & 15);
      float bv = bias[col];
#pragma unroll
      for (int j = 0; j < 4; ++j) {
        int row = bm + wm * 32 + mi * 16 + (lane >> 4) * 4 + j;
        float v = acc[mi][ni][j] + bv;
        if (RELU) v = fmaxf(v, 0.f);
        if (BF16OUT)
          ((unsigned short*)Cout)[(size_t)row * Ndim + col] = f2bf(v);
        else
          ((float*)Cout)[(size_t)row * Ndim + col] = v;
      }
    }
}

// ---------------- normed1b + projb (bf16) -> LN2 -> out (fp32) ----------------
__global__ __launch_bounds__(192) void ln2_out(
    const unsigned short* __restrict__ normed1b, const unsigned short* __restrict__ projb,
    const float* __restrict__ g, const float* __restrict__ bb,
    float* __restrict__ out) {
  int r = blockIdx.x;
  int tid = threadIdx.x;           // 192 threads x 4 elems = 768
  __shared__ float red[6];
  ushort4 av = ((const ushort4*)(normed1b + (size_t)r * DMODEL))[tid];
  ushort4 pv = ((const ushort4*)(projb + (size_t)r * DMODEL))[tid];
  float4 x = {bf2f(av.x) + bf2f(pv.x), bf2f(av.y) + bf2f(pv.y),
              bf2f(av.z) + bf2f(pv.z), bf2f(av.w) + bf2f(pv.w)};
  float s1 = x.x + x.y + x.z + x.w;
  float s2 = x.x * x.x + x.y * x.y + x.z * x.z + x.w * x.w;
#pragma unroll
  for (int off = 32; off; off >>= 1) {
    s1 += __shfl_xor(s1, off, 64);
    s2 += __shfl_xor(s2, off, 64);
  }
  int w = tid >> 6;
  if ((tid & 63) == 0) { red[w] = s1; red[3 + w] = s2; }
  __syncthreads();
  float S1 = red[0] + red[1] + red[2];
  float S2 = red[3] + red[4] + red[5];
  float mu = S1 * (1.f / DMODEL);
  float var = S2 * (1.f / DMODEL) - mu * mu;
  float rstd = 1.0f / sqrtf(var + 1e-5f);
  float4 gv = ((const float4*)g)[tid];
  float4 bv = ((const float4*)bb)[tid];
  float4 o = {(x.x - mu) * rstd * gv.x + bv.x, (x.y - mu) * rstd * gv.y + bv.y,
              (x.z - mu) * rstd * gv.z + bv.z, (x.w - mu) * rstd * gv.w + bv.w};
  ((float4*)(out + (size_t)r * DMODEL))[tid] = o;
}

extern "C" void kernel_launch(void* const* d_in, const int* in_sizes, int n_in,
                              void* d_out, int out_size, void* d_ws, size_t ws_size,
                              hipStream_t stream) {
  const float* target = (const float*)d_in[0];
  const float* source = (const float*)d_in[1];
  const float* W1 = (const float*)d_in[2];
  const float* b1 = (const float*)d_in[3];
  const float* W2 = (const float*)d_in[4];
  const float* b2 = (const float*)d_in[5];
  const float* ln1_g = (const float*)d_in[6];
  const float* ln1_b = (const float*)d_in[7];
  const float* ln2_g = (const float*)d_in[8];
  const float* ln2_b = (const float*)d_in[9];
  float* out = (float*)d_out;

  char* ws = (char*)d_ws;
  float*          M        = (float*)         (ws + 0x0040000);  // 128 KB
  int*            top      = (int*)           (ws + 0x0080000);  // 4.4 KB
  int*            sel      = (int*)           (ws + 0x0090000);  // 128 KB
  float*          vmean    = (float*)         (ws + 0x0130000);  // 12 KB
  float*          part_m   = (float*)         (ws + 0x0140000);  // 72 KB
  float*          part_s   = (float*)         (ws + 0x0160000);  // 72 KB
  unsigned short* w1b      = (unsigned short*)(ws + 0x0180000);  // 3 MB
  unsigned short* w2b      = (unsigned short*)(ws + 0x0480000);  // 3 MB
  unsigned short* normed1b = (unsigned short*)(ws + 0x0780000);  // 6 MB
  unsigned short* projb    = (unsigned short*)(ws + 0x0D80000);  // 6 MB
  unsigned short* h1b      = (unsigned short*)(ws + 0x1980000);  // 16 MB region
  float*          part_O   = (float*)         (ws + 0x1980000);  // 6.9 MB, aliases h1b (dead before gemm1)
  float*          vpart    = (float*)         (ws + 0x2200000);  // 786 KB, aliases h1b (dead before gemm1)

  sample_vmean<<<BATCH * L_SEQ + BATCH * VCH, 256, 0, stream>>>(target, source, M, vpart);
  topk_vmean<<<NBH + BATCH, 256, 0, stream>>>(M, top, sel, vpart, vmean);
  attn_conv<<<NBH * NCHUNK + 1024, 256, 0, stream>>>(target, source, top,
                                                     part_O, part_m, part_s,
                                                     W1, W2, w1b, w2b);
  fuse_ln1<<<NROWS, 256, 0, stream>>>(target, part_O, part_m, part_s, sel, vmean,
                                      ln1_g, ln1_b, normed1b);
  gemm_mfma64<true, true><<<(DFF / 64) * (NROWS / 64), 256, 0, stream>>>(
      normed1b, w1b, b1, h1b, DFF, DMODEL, DFF / 64);        // 2048 blocks
  gemm_mfma64<false, true><<<(DMODEL / 64) * (NROWS / 64), 256, 0, stream>>>(
      h1b, w2b, b2, projb, DMODEL, DFF, DMODEL / 64);        // 768 blocks
  ln2_out<<<NROWS, 192, 0, stream>>>(normed1b, projb, ln2_g, ln2_b, out);
}